// Round 1
// baseline (5496.985 us; speedup 1.0000x reference)
//
#include <hip/hip_runtime.h>
#include <math.h>

#define R_ROWS 1048576
#define F_IN   64
#define H1     256
#define D      128
#define NN     100000
#define NE     1600000
#define NB     4096
#define A1     256
#define NT     16
#define N_GIN  4

// ---------------------------------------------------------------------------
// FE: h = relu(relu(bulk@W1+b1)@W2+b2), then segment-sum into sums/counts.
// Block = 256 threads, 32 rows per block. bulk rows read with block-uniform
// addresses (scalarizes to s_load); W columns held in VGPRs.
// ---------------------------------------------------------------------------
__global__ __launch_bounds__(256) void fe_kernel(
    const float* __restrict__ bulk, const int* __restrict__ seg_ids,
    const float* __restrict__ W1, const float* __restrict__ b1,
    const float* __restrict__ W2, const float* __restrict__ b2,
    float* __restrict__ sums, float* __restrict__ counts)
{
    __shared__ float h1s[32][H1];   // 32 KB
    const int t = threadIdx.x;
    const long r0 = (long)blockIdx.x * 32;

    // ---- layer 1: thread t owns output column t (0..255) ----
    float w[F_IN];
    #pragma unroll
    for (int k = 0; k < F_IN; ++k) w[k] = W1[k * H1 + t];
    float acc[32];
    const float bias1 = b1[t];
    #pragma unroll
    for (int r = 0; r < 32; ++r) acc[r] = bias1;

    for (int k0 = 0; k0 < F_IN; k0 += 4) {
        #pragma unroll
        for (int r = 0; r < 32; ++r) {
            const float4 bv = *reinterpret_cast<const float4*>(&bulk[(r0 + r) * F_IN + k0]);
            acc[r] = fmaf(bv.x, w[k0 + 0], acc[r]);
            acc[r] = fmaf(bv.y, w[k0 + 1], acc[r]);
            acc[r] = fmaf(bv.z, w[k0 + 2], acc[r]);
            acc[r] = fmaf(bv.w, w[k0 + 3], acc[r]);
        }
    }
    #pragma unroll
    for (int r = 0; r < 32; ++r) h1s[r][t] = fmaxf(acc[r], 0.f);
    __syncthreads();

    // ---- layer 2: thread -> (column c, row-group rg) ----
    const int c  = t & (D - 1);
    const int rg = t >> 7;          // 0 or 1 -> rows rg*16 .. rg*16+15
    float acc2[16];
    const float bias2 = b2[c];
    #pragma unroll
    for (int r = 0; r < 16; ++r) acc2[r] = bias2;

    for (int k0 = 0; k0 < H1; k0 += 64) {
        float w2[64];
        #pragma unroll
        for (int k = 0; k < 64; ++k) w2[k] = W2[(k0 + k) * D + c];
        #pragma unroll
        for (int r = 0; r < 16; ++r) {
            const int rr = rg * 16 + r;
            #pragma unroll
            for (int k4 = 0; k4 < 64; k4 += 4) {
                const float4 hv = *reinterpret_cast<const float4*>(&h1s[rr][k0 + k4]);
                acc2[r] = fmaf(hv.x, w2[k4 + 0], acc2[r]);
                acc2[r] = fmaf(hv.y, w2[k4 + 1], acc2[r]);
                acc2[r] = fmaf(hv.z, w2[k4 + 2], acc2[r]);
                acc2[r] = fmaf(hv.w, w2[k4 + 3], acc2[r]);
            }
        }
    }

    // ---- segment accumulation (seg_ids sorted -> run compression) ----
    const int base_r = rg * 16;
    int cur = seg_ids[r0 + base_r];
    float run = 0.f;
    #pragma unroll
    for (int r = 0; r < 16; ++r) {
        const int s = seg_ids[r0 + base_r + r];
        if (s != cur) {
            atomicAdd(&sums[(long)cur * D + c], run);
            cur = s; run = 0.f;
        }
        run += fmaxf(acc2[r], 0.f);
    }
    atomicAdd(&sums[(long)cur * D + c], run);

    if (c == 0) {   // threads t==0 and t==128 handle counts for their rows
        int cur2 = seg_ids[r0 + base_r];
        float rl = 0.f;
        #pragma unroll
        for (int r = 0; r < 16; ++r) {
            const int s = seg_ids[r0 + base_r + r];
            if (s != cur2) { atomicAdd(&counts[cur2], rl); cur2 = s; rl = 0.f; }
            rl += 1.f;
        }
        atomicAdd(&counts[cur2], rl);
    }
}

// node_h = sums / max(counts,1) (in place OK: elementwise)
__global__ __launch_bounds__(256) void divide_kernel(
    const float* __restrict__ sums, const float* __restrict__ counts,
    float* __restrict__ nodeh)
{
    const long i = (long)blockIdx.x * 256 + threadIdx.x;
    if (i < (long)NN * D) {
        const float cnt = counts[i >> 7];
        nodeh[i] = sums[i] / fmaxf(cnt, 1.f);
    }
}

// ---------------------------------------------------------------------------
// CSR build over edge_dst
// ---------------------------------------------------------------------------
__global__ __launch_bounds__(256) void hist_kernel(const int* __restrict__ edst,
                                                   int* __restrict__ deg)
{
    const int e = blockIdx.x * 256 + threadIdx.x;
    if (e < NE) atomicAdd(&deg[edst[e]], 1);
}

#define SCHUNK 2048
__global__ __launch_bounds__(256) void scan_reduce(const int* __restrict__ deg,
                                                   int* __restrict__ partials, int n)
{
    __shared__ int sdata[256];
    const int b = blockIdx.x, t = threadIdx.x;
    const int base = b * SCHUNK;
    int sum = 0;
    for (int i = t; i < SCHUNK; i += 256) {
        const int idx = base + i;
        sum += (idx < n) ? deg[idx] : 0;
    }
    sdata[t] = sum; __syncthreads();
    for (int s = 128; s > 0; s >>= 1) {
        if (t < s) sdata[t] += sdata[t + s];
        __syncthreads();
    }
    if (t == 0) partials[b] = sdata[0];
}

__global__ void scan_partials(int* partials, int nb)
{
    if (threadIdx.x == 0) {
        int acc = 0;
        for (int i = 0; i < nb; ++i) { const int v = partials[i]; partials[i] = acc; acc += v; }
    }
}

__global__ __launch_bounds__(256) void scan_write(const int* __restrict__ deg,
                                                  const int* __restrict__ partials,
                                                  int* __restrict__ offsets, int n)
{
    __shared__ int sdata[256];
    const int b = blockIdx.x, t = threadIdx.x;
    const int base = b * SCHUNK;
    int loc[8]; int s = 0;
    #pragma unroll
    for (int j = 0; j < 8; ++j) {
        const int idx = base + t * 8 + j;
        const int v = (idx < n) ? deg[idx] : 0;
        loc[j] = s; s += v;
    }
    sdata[t] = s; __syncthreads();
    for (int d = 1; d < 256; d <<= 1) {
        const int v = (t >= d) ? sdata[t - d] : 0;
        __syncthreads();
        sdata[t] += v;
        __syncthreads();
    }
    const int excl = (t == 0) ? 0 : sdata[t - 1];
    const int tbase = partials[b] + excl;
    #pragma unroll
    for (int j = 0; j < 8; ++j) {
        const int idx = base + t * 8 + j;
        if (idx < n) offsets[idx] = tbase + loc[j];
    }
}

__global__ __launch_bounds__(256) void scatter_edges(const int* __restrict__ esrc,
                                                     const int* __restrict__ edst,
                                                     int* __restrict__ cursor,
                                                     int* __restrict__ csr_src)
{
    const int e = blockIdx.x * 256 + threadIdx.x;
    if (e < NE) {
        const int d = edst[e];
        const int p = atomicAdd(&cursor[d], 1);
        csr_src[p] = esrc[e];
    }
}

// ---------------------------------------------------------------------------
// GIN layer: y = (1+eps)*h + sum_{in-edges} h[src]  (pull via CSR, 1 wave/node)
// ---------------------------------------------------------------------------
__global__ __launch_bounds__(256) void gin_agg(
    const float* __restrict__ h, const int* __restrict__ offsets,
    const int* __restrict__ deg, const int* __restrict__ csr_src,
    float* __restrict__ y)
{
    const int wave = threadIdx.x >> 6;
    const int lane = threadIdx.x & 63;
    const int n = blockIdx.x * 4 + wave;
    if (n >= NN) return;
    const int off = offsets[n];
    const int dg  = deg[n];
    float2 acc = *reinterpret_cast<const float2*>(&h[(long)n * D + lane * 2]);
    acc.x *= 2.1f; acc.y *= 2.1f;     // 1 + eps, eps = 1.1
    for (int j = 0; j < dg; ++j) {
        const int s = csr_src[off + j];
        const float2 v = *reinterpret_cast<const float2*>(&h[(long)s * D + lane * 2]);
        acc.x += v.x; acc.y += v.y;
    }
    *reinterpret_cast<float2*>(&y[(long)n * D + lane * 2]) = acc;
}

// h_out = relu(y @ W + b); 32 rows per block
__global__ __launch_bounds__(256) void gin_gemm(
    const float* __restrict__ y, const float* __restrict__ W,
    const float* __restrict__ bvec, float* __restrict__ hout)
{
    __shared__ float yt[32][D];     // 16 KB
    const int t = threadIdx.x;
    const long r0 = (long)blockIdx.x * 32;
    for (int i = t * 4; i < 32 * D; i += 1024)
        *reinterpret_cast<float4*>(&yt[0][0] + i) =
            *reinterpret_cast<const float4*>(&y[r0 * D + i]);
    __syncthreads();

    const int c  = t & (D - 1);
    const int rg = t >> 7;
    float acc[16];
    const float bb = bvec[c];
    #pragma unroll
    for (int r = 0; r < 16; ++r) acc[r] = bb;

    for (int k0 = 0; k0 < D; k0 += 64) {
        float w[64];
        #pragma unroll
        for (int k = 0; k < 64; ++k) w[k] = W[(k0 + k) * D + c];
        #pragma unroll
        for (int r = 0; r < 16; ++r) {
            const int rr = rg * 16 + r;
            #pragma unroll
            for (int k4 = 0; k4 < 64; k4 += 4) {
                const float4 hv = *reinterpret_cast<const float4*>(&yt[rr][k0 + k4]);
                acc[r] = fmaf(hv.x, w[k4 + 0], acc[r]);
                acc[r] = fmaf(hv.y, w[k4 + 1], acc[r]);
                acc[r] = fmaf(hv.z, w[k4 + 2], acc[r]);
                acc[r] = fmaf(hv.w, w[k4 + 3], acc[r]);
            }
        }
    }
    #pragma unroll
    for (int r = 0; r < 16; ++r) {
        const int rr = rg * 16 + r;
        hout[(r0 + rr) * D + c] = fmaxf(acc[r], 0.f);
    }
}

// ---------------------------------------------------------------------------
// Heads: one block per root
// ---------------------------------------------------------------------------
__global__ __launch_bounds__(256) void head_kernel(
    const float* __restrict__ h, const int* __restrict__ root,
    const float* __restrict__ Wa1, const float* __restrict__ ba1,
    const float* __restrict__ Wa2, const float* __restrict__ ba2,
    const float* __restrict__ Wc1, const float* __restrict__ bc1,
    const float* __restrict__ Wc2, const float* __restrict__ bc2,
    float* __restrict__ out_act, float* __restrict__ out_crit)
{
    __shared__ float X[D];
    __shared__ float a1[A1];
    __shared__ float red[256];
    __shared__ float logits[NT];
    const int t = threadIdx.x;
    const int bi = blockIdx.x;
    const int n = root[bi];
    if (t < 32)
        *reinterpret_cast<float4*>(&X[t * 4]) =
            *reinterpret_cast<const float4*>(&h[(long)n * D + t * 4]);
    __syncthreads();

    // actor layer 1: a1[t] = relu(X . Wa1[:,t] + ba1[t])
    float acc = ba1[t];
    #pragma unroll
    for (int k = 0; k < D; k += 4) {
        const float4 xv = *reinterpret_cast<const float4*>(&X[k]);
        acc = fmaf(xv.x, Wa1[(k + 0) * A1 + t], acc);
        acc = fmaf(xv.y, Wa1[(k + 1) * A1 + t], acc);
        acc = fmaf(xv.z, Wa1[(k + 2) * A1 + t], acc);
        acc = fmaf(xv.w, Wa1[(k + 3) * A1 + t], acc);
    }
    a1[t] = fmaxf(acc, 0.f);
    __syncthreads();

    // logits: 16 outputs x 16 partial groups
    const int j = t & 15, p = t >> 4;
    float pa = 0.f;
    #pragma unroll
    for (int k = 0; k < 16; ++k) {
        const int kk = p * 16 + k;
        pa = fmaf(a1[kk], Wa2[kk * NT + j], pa);
    }
    red[j * 16 + p] = pa;
    __syncthreads();
    if (t < NT) {
        float s = 0.f;
        #pragma unroll
        for (int p2 = 0; p2 < 16; ++p2) s += red[t * 16 + p2];
        logits[t] = fmaxf(s + ba2[t], 0.f);
    }
    __syncthreads();
    if (t < NT) {
        float mx = -1e30f;
        #pragma unroll
        for (int i = 0; i < NT; ++i) mx = fmaxf(mx, logits[i]);
        red[t] = expf(logits[t] - mx);
    }
    __syncthreads();
    if (t < NT) {
        float s = 0.f;
        #pragma unroll
        for (int i = 0; i < NT; ++i) s += red[i];
        out_act[(long)bi * NT + t] = red[t] / s;
    }
    __syncthreads();

    // critic
    float accc = bc1[t];
    #pragma unroll
    for (int k = 0; k < D; k += 4) {
        const float4 xv = *reinterpret_cast<const float4*>(&X[k]);
        accc = fmaf(xv.x, Wc1[(k + 0) * A1 + t], accc);
        accc = fmaf(xv.y, Wc1[(k + 1) * A1 + t], accc);
        accc = fmaf(xv.z, Wc1[(k + 2) * A1 + t], accc);
        accc = fmaf(xv.w, Wc1[(k + 3) * A1 + t], accc);
    }
    red[t] = fmaxf(accc, 0.f) * Wc2[t];
    __syncthreads();
    for (int s = 128; s > 0; s >>= 1) {
        if (t < s) red[t] += red[t + s];
        __syncthreads();
    }
    if (t == 0) out_crit[bi] = red[0] + bc2[0];
}

// ---------------------------------------------------------------------------
extern "C" void kernel_launch(void* const* d_in, const int* in_sizes, int n_in,
                              void* d_out, int out_size, void* d_ws, size_t ws_size,
                              hipStream_t stream)
{
    const float* bulk = (const float*)d_in[0];
    const int*   seg  = (const int*)d_in[1];
    const int*   esrc = (const int*)d_in[2];
    const int*   edst = (const int*)d_in[3];
    const int*   root = (const int*)d_in[4];
    const float* W1   = (const float*)d_in[6];
    const float* b1   = (const float*)d_in[7];
    const float* W2   = (const float*)d_in[8];
    const float* b2   = (const float*)d_in[9];
    const float* ginW = (const float*)d_in[10];
    const float* ginb = (const float*)d_in[11];
    const float* Wa1  = (const float*)d_in[12];
    const float* ba1  = (const float*)d_in[13];
    const float* Wa2  = (const float*)d_in[14];
    const float* ba2  = (const float*)d_in[15];
    const float* Wc1  = (const float*)d_in[16];
    const float* bc1  = (const float*)d_in[17];
    const float* Wc2  = (const float*)d_in[18];
    const float* bc2  = (const float*)d_in[19];

    char* ws = (char*)d_ws;
    float* sums    = (float*)ws;                       // N*D, doubles as node_h A
    float* nodeB   = sums + (long)NN * D;              // N*D
    float* counts  = nodeB + (long)NN * D;             // N
    int*   deg     = (int*)(counts + NN);              // N
    int*   offsets = deg + NN;                         // N
    int*   cursor  = offsets + NN;                     // N
    int*   partials= cursor + NN;                      // 256
    int*   csr     = partials + 256;                   // E

    hipMemsetAsync(sums,   0, (long)NN * D * sizeof(float), stream);
    hipMemsetAsync(counts, 0, NN * sizeof(float), stream);
    hipMemsetAsync(deg,    0, NN * sizeof(int), stream);

    fe_kernel<<<R_ROWS / 32, 256, 0, stream>>>(bulk, seg, W1, b1, W2, b2, sums, counts);
    divide_kernel<<<((long)NN * D + 255) / 256, 256, 0, stream>>>(sums, counts, sums);

    hist_kernel<<<(NE + 255) / 256, 256, 0, stream>>>(edst, deg);
    const int nchunks = (NN + SCHUNK - 1) / SCHUNK;
    scan_reduce<<<nchunks, 256, 0, stream>>>(deg, partials, NN);
    scan_partials<<<1, 64, 0, stream>>>(partials, nchunks);
    scan_write<<<nchunks, 256, 0, stream>>>(deg, partials, offsets, NN);
    hipMemcpyAsync(cursor, offsets, NN * sizeof(int), hipMemcpyDeviceToDevice, stream);
    scatter_edges<<<(NE + 255) / 256, 256, 0, stream>>>(esrc, edst, cursor, csr);

    float* hA = sums;
    float* hB = nodeB;
    for (int l = 0; l < N_GIN; ++l) {
        gin_agg<<<(NN + 3) / 4, 256, 0, stream>>>(hA, offsets, deg, csr, hB);
        gin_gemm<<<(NN + 31) / 32, 256, 0, stream>>>(hB, ginW + (long)l * D * D, ginb + (long)l * D, hA);
    }

    head_kernel<<<NB, 256, 0, stream>>>(hA, root, Wa1, ba1, Wa2, ba2,
                                        Wc1, bc1, Wc2, bc2,
                                        (float*)d_out, (float*)d_out + (long)NB * NT);
}

// Round 2
// 1545.681 us; speedup vs baseline: 3.5564x; 3.5564x over previous
//
#include <hip/hip_runtime.h>
#include <math.h>

#define R_ROWS 1048576
#define F_IN   64
#define H1     256
#define D      128
#define NN     100000
#define NE     1600000
#define NB     4096
#define A1     256
#define NTOK   16
#define N_GIN  4
#define FE_ROWS 64

typedef short short8 __attribute__((ext_vector_type(8)));
typedef float f32x4  __attribute__((ext_vector_type(4)));
typedef unsigned int uintx4 __attribute__((ext_vector_type(4)));

__device__ __forceinline__ ushort f2bf(float x) {
    uint u = __builtin_bit_cast(uint, x);
    u += 0x7FFFu + ((u >> 16) & 1u);
    return (ushort)(u >> 16);
}
__device__ __forceinline__ float bf2f(ushort h) {
    uint u = ((uint)h) << 16;
    return __builtin_bit_cast(float, u);
}
// one dword per element: low16 = hi-plane bf16, high16 = lo-plane bf16
__device__ __forceinline__ uint packsplit(float x) {
    const ushort hi = f2bf(x);
    const ushort lo = f2bf(x - bf2f(hi));
    return (uint)hi | ((uint)lo << 16);
}
__device__ __forceinline__ f32x4 mm(short8 a, short8 b, f32x4 c) {
    return __builtin_amdgcn_mfma_f32_16x16x32_bf16(a, b, c, 0, 0, 0);
}
__device__ __forceinline__ void unpack_pair(const uintx4 q0, const uintx4 q1,
                                            short8& hi, short8& lo) {
    uintx4 H, L;
    H[0] = (q0[0] & 0xFFFFu) | (q0[1] << 16);
    H[1] = (q0[2] & 0xFFFFu) | (q0[3] << 16);
    H[2] = (q1[0] & 0xFFFFu) | (q1[1] << 16);
    H[3] = (q1[2] & 0xFFFFu) | (q1[3] << 16);
    L[0] = (q0[0] >> 16) | (q0[1] & 0xFFFF0000u);
    L[1] = (q0[2] >> 16) | (q0[3] & 0xFFFF0000u);
    L[2] = (q1[0] >> 16) | (q1[1] & 0xFFFF0000u);
    L[3] = (q1[2] >> 16) | (q1[3] & 0xFFFF0000u);
    hi = __builtin_bit_cast(short8, H);
    lo = __builtin_bit_cast(short8, L);
}

// ---------------------------------------------------------------------------
// Pack a [K][N] f32 weight into MFMA-fragment order, bf16 hi/lo planes.
// frag f = kt*(N/16) + nt; lane holds 8 consecutive k at k0 = kt*32+(lane>>4)*8,
// col n = nt*16+(lane&15). Consumer loads one dwordx4 per (frag, plane).
// ---------------------------------------------------------------------------
__global__ __launch_bounds__(256) void pack_weights(
    const float* __restrict__ W, int Ndim, int nfrag, ushort* __restrict__ out)
{
    const int id = blockIdx.x * 256 + threadIdx.x;
    const int f = id >> 6, lane = id & 63;
    if (f >= nfrag) return;
    const int NTn = Ndim >> 4;
    const int kt = f / NTn, nt = f - kt * NTn;
    const int k0 = kt * 32 + (lane >> 4) * 8;
    const int n = nt * 16 + (lane & 15);
    uintx4 Hv, Lv;
    #pragma unroll
    for (int jj = 0; jj < 4; ++jj) {
        const float x0 = W[(k0 + 2 * jj) * Ndim + n];
        const float x1 = W[(k0 + 2 * jj + 1) * Ndim + n];
        const ushort h0 = f2bf(x0), l0 = f2bf(x0 - bf2f(h0));
        const ushort h1u = f2bf(x1), l1 = f2bf(x1 - bf2f(h1u));
        Hv[jj] = (uint)h0 | ((uint)h1u << 16);
        Lv[jj] = (uint)l0 | ((uint)l1 << 16);
    }
    *reinterpret_cast<uintx4*>(&out[((f * 2 + 0) * 64 + lane) * 8]) = Hv;
    *reinterpret_cast<uintx4*>(&out[((f * 2 + 1) * 64 + lane) * 8]) = Lv;
}

// ---------------------------------------------------------------------------
// Fused feature extractor: relu(relu(bulk@W1+b1)@W2+b2) + segment sum.
// 64 rows/block, 4 waves, 3xbf16-split MFMA. 64KB LDS.
// ---------------------------------------------------------------------------
__global__ __launch_bounds__(256, 2) void fe_mfma(
    const float* __restrict__ bulk, const int* __restrict__ seg,
    const ushort* __restrict__ W1p, const float* __restrict__ b1,
    const ushort* __restrict__ W2p, const float* __restrict__ b2,
    float* __restrict__ sums, float* __restrict__ counts)
{
    __shared__ __align__(16) uint smem_u[FE_ROWS * 256];   // exactly 64 KB
    ushort* Ah = (ushort*)smem_u;            // [64][72] bf16 hi plane
    ushort* Al = Ah + FE_ROWS * 72;          // [64][72] bf16 lo plane
    float* h2  = (float*)smem_u;             // [64][132] f32 overlay (after L2)

    const int t = threadIdx.x;
    const int lane = t & 63;
    const int w = t >> 6;
    const long r0 = (long)blockIdx.x * FE_ROWS;

    // ---- stage A (bulk rows) as bf16 hi/lo planes ----
    #pragma unroll
    for (int i = 0; i < 4; ++i) {
        const int fid = t + i * 256;          // 64 rows x 16 float4
        const int row = fid >> 4;
        const int c4 = (fid & 15) * 4;
        const float4 v = *reinterpret_cast<const float4*>(&bulk[(r0 + row) * F_IN + c4]);
        const float xs[4] = {v.x, v.y, v.z, v.w};
        ushort hs[4], ls[4];
        #pragma unroll
        for (int e = 0; e < 4; ++e) { hs[e] = f2bf(xs[e]); ls[e] = f2bf(xs[e] - bf2f(hs[e])); }
        *reinterpret_cast<ushort4*>(&Ah[row * 72 + c4]) = make_ushort4(hs[0], hs[1], hs[2], hs[3]);
        *reinterpret_cast<ushort4*>(&Al[row * 72 + c4]) = make_ushort4(ls[0], ls[1], ls[2], ls[3]);
    }

    // ---- W1 fragments + biases (global, L2-hot) ----
    short8 bw1[4][2][2];
    #pragma unroll
    for (int ntl = 0; ntl < 4; ++ntl)
        #pragma unroll
        for (int kt = 0; kt < 2; ++kt)
            #pragma unroll
            for (int p = 0; p < 2; ++p) {
                const int f = kt * 16 + (w * 4 + ntl);
                bw1[ntl][kt][p] = *reinterpret_cast<const short8*>(&W1p[((f * 2 + p) * 64 + lane) * 8]);
            }
    float b1v[4], b2v[2];
    #pragma unroll
    for (int ntl = 0; ntl < 4; ++ntl) b1v[ntl] = b1[w * 64 + ntl * 16 + (lane & 15)];
    #pragma unroll
    for (int ntl = 0; ntl < 2; ++ntl) b2v[ntl] = b2[w * 32 + ntl * 16 + (lane & 15)];

    __syncthreads();

    // ---- A fragments: lane -> A[row = mt*16+(l&15)][k = kt*32+(l>>4)*8 ..+7] ----
    short8 a1[4][2][2];
    #pragma unroll
    for (int mt = 0; mt < 4; ++mt)
        #pragma unroll
        for (int kt = 0; kt < 2; ++kt) {
            const int row = mt * 16 + (lane & 15);
            const int kb = kt * 32 + (lane >> 4) * 8;
            a1[mt][kt][0] = *reinterpret_cast<const short8*>(&Ah[row * 72 + kb]);
            a1[mt][kt][1] = *reinterpret_cast<const short8*>(&Al[row * 72 + kb]);
        }
    __syncthreads();

    // ---- layer 1 MFMA (3xbf16 split) ----
    const f32x4 zz = {0.f, 0.f, 0.f, 0.f};
    f32x4 acc1[4][4];
    #pragma unroll
    for (int mt = 0; mt < 4; ++mt)
        #pragma unroll
        for (int ntl = 0; ntl < 4; ++ntl) {
            f32x4 a = zz;
            #pragma unroll
            for (int kt = 0; kt < 2; ++kt) {
                a = mm(a1[mt][kt][0], bw1[ntl][kt][0], a);
                a = mm(a1[mt][kt][0], bw1[ntl][kt][1], a);
                a = mm(a1[mt][kt][1], bw1[ntl][kt][0], a);
            }
            acc1[mt][ntl] = a;
        }

    // ---- relu+bias, write h1 as packed (hi,lo) dwords, XOR-swizzled groups ----
    // dword addr: row*256 + (((col>>2) ^ (row&7))<<2) | (col&3)
    #pragma unroll
    for (int mt = 0; mt < 4; ++mt)
        #pragma unroll
        for (int ntl = 0; ntl < 4; ++ntl)
            #pragma unroll
            for (int r = 0; r < 4; ++r) {
                const int row = mt * 16 + (lane >> 4) * 4 + r;
                const int col = w * 64 + ntl * 16 + (lane & 15);
                const float x = fmaxf(acc1[mt][ntl][r] + b1v[ntl], 0.f);
                const int addr = row * 256 + ((((col >> 2) ^ (row & 7)) << 2) | (col & 3));
                smem_u[addr] = packsplit(x);
            }
    __syncthreads();

    // ---- layer 2: K=256 streamed, W2 frags from global (L2-hot) ----
    f32x4 acc2[4][2];
    #pragma unroll
    for (int mt = 0; mt < 4; ++mt) { acc2[mt][0] = zz; acc2[mt][1] = zz; }

    #pragma unroll
    for (int kt = 0; kt < 8; ++kt) {
        short8 bw2[2][2];
        #pragma unroll
        for (int ntl = 0; ntl < 2; ++ntl)
            #pragma unroll
            for (int p = 0; p < 2; ++p) {
                const int f = kt * 8 + (w * 2 + ntl);
                bw2[ntl][p] = *reinterpret_cast<const short8*>(&W2p[((f * 2 + p) * 64 + lane) * 8]);
            }
        #pragma unroll
        for (int mt = 0; mt < 4; ++mt) {
            const int row = mt * 16 + (lane & 15);
            const int g0 = (kt * 32 + (lane >> 4) * 8) >> 2;   // even group idx
            const int swz = lane & 7;                          // == row & 7
            const uintx4 q0 = *reinterpret_cast<const uintx4*>(&smem_u[row * 256 + ((g0 ^ swz) << 2)]);
            const uintx4 q1 = *reinterpret_cast<const uintx4*>(&smem_u[row * 256 + (((g0 + 1) ^ swz) << 2)]);
            short8 ah, al;
            unpack_pair(q0, q1, ah, al);
            #pragma unroll
            for (int ntl = 0; ntl < 2; ++ntl) {
                acc2[mt][ntl] = mm(ah, bw2[ntl][0], acc2[mt][ntl]);
                acc2[mt][ntl] = mm(ah, bw2[ntl][1], acc2[mt][ntl]);
                acc2[mt][ntl] = mm(al, bw2[ntl][0], acc2[mt][ntl]);
            }
        }
    }
    __syncthreads();   // all h1 reads done before h2 overlays the same LDS

    // ---- write h2 (relu+bias) ----
    #pragma unroll
    for (int mt = 0; mt < 4; ++mt)
        #pragma unroll
        for (int ntl = 0; ntl < 2; ++ntl)
            #pragma unroll
            for (int r = 0; r < 4; ++r) {
                const int row = mt * 16 + (lane >> 4) * 4 + r;
                const int col = w * 32 + ntl * 16 + (lane & 15);
                h2[row * 132 + col] = fmaxf(acc2[mt][ntl][r] + b2v[ntl], 0.f);
            }
    __syncthreads();

    // ---- segment reduction: interior segments -> plain store, boundary -> atomic
    if (t <= 128) {
        const bool docnt = (t == 128);
        const int c = docnt ? 0 : t;
        const int prev = (r0 == 0) ? -1 : seg[r0 - 1];
        const int nxt = (r0 + FE_ROWS >= R_ROWS) ? -1 : seg[r0 + FE_ROWS];
        int cur = seg[r0];
        float run = 0.f;
        int runstart = 0;
        #pragma unroll 1
        for (int r = 0; r < FE_ROWS; ++r) {
            const int s = seg[r0 + r];
            if (s != cur) {
                const bool interior = !(runstart == 0 && cur == prev);
                if (docnt) { if (interior) counts[cur] = run; else atomicAdd(&counts[cur], run); }
                else { if (interior) sums[(long)cur * D + c] = run; else atomicAdd(&sums[(long)cur * D + c], run); }
                cur = s; run = 0.f; runstart = r;
            }
            run += docnt ? 1.f : h2[r * 132 + c];
        }
        const bool interior = (!(runstart == 0 && cur == prev)) && (cur != nxt);
        if (docnt) { if (interior) counts[cur] = run; else atomicAdd(&counts[cur], run); }
        else { if (interior) sums[(long)cur * D + c] = run; else atomicAdd(&sums[(long)cur * D + c], run); }
    }
}

// node_h = sums / max(counts,1)
__global__ __launch_bounds__(256) void divide_kernel(
    const float* __restrict__ sums, const float* __restrict__ counts,
    float* __restrict__ nodeh)
{
    const long i = (long)blockIdx.x * 256 + threadIdx.x;
    if (i < (long)NN * D) {
        const float cnt = counts[i >> 7];
        nodeh[i] = sums[i] / fmaxf(cnt, 1.f);
    }
}

// ---------------------------------------------------------------------------
// CSR build over edge_dst
// ---------------------------------------------------------------------------
__global__ __launch_bounds__(256) void hist_kernel(const int* __restrict__ edst,
                                                   int* __restrict__ deg)
{
    const int e = blockIdx.x * 256 + threadIdx.x;
    if (e < NE) atomicAdd(&deg[edst[e]], 1);
}

#define SCHUNK 2048
__global__ __launch_bounds__(256) void scan_reduce(const int* __restrict__ deg,
                                                   int* __restrict__ partials, int n)
{
    __shared__ int sdata[256];
    const int b = blockIdx.x, t = threadIdx.x;
    const int base = b * SCHUNK;
    int sum = 0;
    for (int i = t; i < SCHUNK; i += 256) {
        const int idx = base + i;
        sum += (idx < n) ? deg[idx] : 0;
    }
    sdata[t] = sum; __syncthreads();
    for (int s = 128; s > 0; s >>= 1) {
        if (t < s) sdata[t] += sdata[t + s];
        __syncthreads();
    }
    if (t == 0) partials[b] = sdata[0];
}

__global__ void scan_partials(int* partials, int nb)
{
    if (threadIdx.x == 0) {
        int acc = 0;
        for (int i = 0; i < nb; ++i) { const int v = partials[i]; partials[i] = acc; acc += v; }
    }
}

__global__ __launch_bounds__(256) void scan_write(const int* __restrict__ deg,
                                                  const int* __restrict__ partials,
                                                  int* __restrict__ offsets, int n)
{
    __shared__ int sdata[256];
    const int b = blockIdx.x, t = threadIdx.x;
    const int base = b * SCHUNK;
    int loc[8]; int s = 0;
    #pragma unroll
    for (int j = 0; j < 8; ++j) {
        const int idx = base + t * 8 + j;
        const int v = (idx < n) ? deg[idx] : 0;
        loc[j] = s; s += v;
    }
    sdata[t] = s; __syncthreads();
    for (int d = 1; d < 256; d <<= 1) {
        const int v = (t >= d) ? sdata[t - d] : 0;
        __syncthreads();
        sdata[t] += v;
        __syncthreads();
    }
    const int excl = (t == 0) ? 0 : sdata[t - 1];
    const int tbase = partials[b] + excl;
    #pragma unroll
    for (int j = 0; j < 8; ++j) {
        const int idx = base + t * 8 + j;
        if (idx < n) offsets[idx] = tbase + loc[j];
    }
}

__global__ __launch_bounds__(256) void scatter_edges(const int* __restrict__ esrc,
                                                     const int* __restrict__ edst,
                                                     int* __restrict__ cursor,
                                                     int* __restrict__ csr_src)
{
    const int e = blockIdx.x * 256 + threadIdx.x;
    if (e < NE) {
        const int d = edst[e];
        const int p = atomicAdd(&cursor[d], 1);
        csr_src[p] = esrc[e];
    }
}

// ---------------------------------------------------------------------------
// GIN aggregate: y = (1+eps)*h + sum_in h[src]  (pull via CSR, 1 wave/node)
// ---------------------------------------------------------------------------
__global__ __launch_bounds__(256) void gin_agg(
    const float* __restrict__ h, const int* __restrict__ offsets,
    const int* __restrict__ deg, const int* __restrict__ csr_src,
    float* __restrict__ y)
{
    const int wave = threadIdx.x >> 6;
    const int lane = threadIdx.x & 63;
    const int n = blockIdx.x * 4 + wave;
    if (n >= NN) return;
    const int off = offsets[n];
    const int dg  = deg[n];
    float2 acc = *reinterpret_cast<const float2*>(&h[(long)n * D + lane * 2]);
    acc.x *= 2.1f; acc.y *= 2.1f;
    for (int j = 0; j < dg; ++j) {
        const int s = csr_src[off + j];
        const float2 v = *reinterpret_cast<const float2*>(&h[(long)s * D + lane * 2]);
        acc.x += v.x; acc.y += v.y;
    }
    *reinterpret_cast<float2*>(&y[(long)n * D + lane * 2]) = acc;
}

// ---------------------------------------------------------------------------
// GIN GEMM: h = relu(y @ W + b), MFMA 3xbf16, 32 rows/block
// ---------------------------------------------------------------------------
__global__ __launch_bounds__(256) void gin_gemm_mfma(
    const float* __restrict__ y, const ushort* __restrict__ Wp,
    const float* __restrict__ bvec, float* __restrict__ hout)
{
    __shared__ __align__(16) uint ypk[32 * 140];
    const int t = threadIdx.x, lane = t & 63, w = t >> 6;
    const long r0 = (long)blockIdx.x * 32;

    #pragma unroll
    for (int i = 0; i < 4; ++i) {
        const int fid = t + i * 256;
        const int row = fid >> 5;
        const int c4 = (fid & 31) * 4;
        const float4 v = *reinterpret_cast<const float4*>(&y[(r0 + row) * D + c4]);
        uintx4 pk;
        pk[0] = packsplit(v.x); pk[1] = packsplit(v.y);
        pk[2] = packsplit(v.z); pk[3] = packsplit(v.w);
        *reinterpret_cast<uintx4*>(&ypk[row * 140 + c4]) = pk;
    }

    short8 bw[2][4][2];
    #pragma unroll
    for (int ntl = 0; ntl < 2; ++ntl)
        #pragma unroll
        for (int kt = 0; kt < 4; ++kt)
            #pragma unroll
            for (int p = 0; p < 2; ++p) {
                const int f = kt * 8 + (w * 2 + ntl);
                bw[ntl][kt][p] = *reinterpret_cast<const short8*>(&Wp[((f * 2 + p) * 64 + lane) * 8]);
            }
    float bv[2];
    bv[0] = bvec[w * 32 + (lane & 15)];
    bv[1] = bvec[w * 32 + 16 + (lane & 15)];
    __syncthreads();

    const f32x4 zz = {0.f, 0.f, 0.f, 0.f};
    f32x4 acc[2][2] = {{zz, zz}, {zz, zz}};
    #pragma unroll
    for (int kt = 0; kt < 4; ++kt)
        #pragma unroll
        for (int mt = 0; mt < 2; ++mt) {
            const int row = mt * 16 + (lane & 15);
            const int kb = kt * 32 + (lane >> 4) * 8;
            const uintx4 q0 = *reinterpret_cast<const uintx4*>(&ypk[row * 140 + kb]);
            const uintx4 q1 = *reinterpret_cast<const uintx4*>(&ypk[row * 140 + kb + 4]);
            short8 ah, al;
            unpack_pair(q0, q1, ah, al);
            #pragma unroll
            for (int ntl = 0; ntl < 2; ++ntl) {
                acc[mt][ntl] = mm(ah, bw[ntl][kt][0], acc[mt][ntl]);
                acc[mt][ntl] = mm(ah, bw[ntl][kt][1], acc[mt][ntl]);
                acc[mt][ntl] = mm(al, bw[ntl][kt][0], acc[mt][ntl]);
            }
        }

    #pragma unroll
    for (int mt = 0; mt < 2; ++mt)
        #pragma unroll
        for (int ntl = 0; ntl < 2; ++ntl)
            #pragma unroll
            for (int r = 0; r < 4; ++r) {
                const int row = mt * 16 + (lane >> 4) * 4 + r;
                const int col = w * 32 + ntl * 16 + (lane & 15);
                hout[(r0 + row) * D + col] = fmaxf(acc[mt][ntl][r] + bv[ntl], 0.f);
            }
}

// ---------------------------------------------------------------------------
// Heads: one block per root
// ---------------------------------------------------------------------------
__global__ __launch_bounds__(256) void head_kernel(
    const float* __restrict__ h, const int* __restrict__ root,
    const float* __restrict__ Wa1, const float* __restrict__ ba1,
    const float* __restrict__ Wa2, const float* __restrict__ ba2,
    const float* __restrict__ Wc1, const float* __restrict__ bc1,
    const float* __restrict__ Wc2, const float* __restrict__ bc2,
    float* __restrict__ out_act, float* __restrict__ out_crit)
{
    __shared__ float X[D];
    __shared__ float a1[A1];
    __shared__ float red[256];
    __shared__ float logits[NTOK];
    const int t = threadIdx.x;
    const int bi = blockIdx.x;
    const int n = root[bi];
    if (t < 32)
        *reinterpret_cast<float4*>(&X[t * 4]) =
            *reinterpret_cast<const float4*>(&h[(long)n * D + t * 4]);
    __syncthreads();

    float acc = ba1[t];
    #pragma unroll
    for (int k = 0; k < D; k += 4) {
        const float4 xv = *reinterpret_cast<const float4*>(&X[k]);
        acc = fmaf(xv.x, Wa1[(k + 0) * A1 + t], acc);
        acc = fmaf(xv.y, Wa1[(k + 1) * A1 + t], acc);
        acc = fmaf(xv.z, Wa1[(k + 2) * A1 + t], acc);
        acc = fmaf(xv.w, Wa1[(k + 3) * A1 + t], acc);
    }
    a1[t] = fmaxf(acc, 0.f);
    __syncthreads();

    const int j = t & 15, p = t >> 4;
    float pa = 0.f;
    #pragma unroll
    for (int k = 0; k < 16; ++k) {
        const int kk = p * 16 + k;
        pa = fmaf(a1[kk], Wa2[kk * NTOK + j], pa);
    }
    red[j * 16 + p] = pa;
    __syncthreads();
    if (t < NTOK) {
        float s = 0.f;
        #pragma unroll
        for (int p2 = 0; p2 < 16; ++p2) s += red[t * 16 + p2];
        logits[t] = fmaxf(s + ba2[t], 0.f);
    }
    __syncthreads();
    if (t < NTOK) {
        float mx = -1e30f;
        #pragma unroll
        for (int i = 0; i < NTOK; ++i) mx = fmaxf(mx, logits[i]);
        red[t] = expf(logits[t] - mx);
    }
    __syncthreads();
    if (t < NTOK) {
        float s = 0.f;
        #pragma unroll
        for (int i = 0; i < NTOK; ++i) s += red[i];
        out_act[(long)bi * NTOK + t] = red[t] / s;
    }
    __syncthreads();

    float accc = bc1[t];
    #pragma unroll
    for (int k = 0; k < D; k += 4) {
        const float4 xv = *reinterpret_cast<const float4*>(&X[k]);
        accc = fmaf(xv.x, Wc1[(k + 0) * A1 + t], accc);
        accc = fmaf(xv.y, Wc1[(k + 1) * A1 + t], accc);
        accc = fmaf(xv.z, Wc1[(k + 2) * A1 + t], accc);
        accc = fmaf(xv.w, Wc1[(k + 3) * A1 + t], accc);
    }
    red[t] = fmaxf(accc, 0.f) * Wc2[t];
    __syncthreads();
    for (int s = 128; s > 0; s >>= 1) {
        if (t < s) red[t] += red[t + s];
        __syncthreads();
    }
    if (t == 0) out_crit[bi] = red[0] + bc2[0];
}

// ---------------------------------------------------------------------------
extern "C" void kernel_launch(void* const* d_in, const int* in_sizes, int n_in,
                              void* d_out, int out_size, void* d_ws, size_t ws_size,
                              hipStream_t stream)
{
    const float* bulk = (const float*)d_in[0];
    const int*   seg  = (const int*)d_in[1];
    const int*   esrc = (const int*)d_in[2];
    const int*   edst = (const int*)d_in[3];
    const int*   root = (const int*)d_in[4];
    const float* W1   = (const float*)d_in[6];
    const float* b1   = (const float*)d_in[7];
    const float* W2   = (const float*)d_in[8];
    const float* b2   = (const float*)d_in[9];
    const float* ginW = (const float*)d_in[10];
    const float* ginb = (const float*)d_in[11];
    const float* Wa1  = (const float*)d_in[12];
    const float* ba1  = (const float*)d_in[13];
    const float* Wa2  = (const float*)d_in[14];
    const float* ba2  = (const float*)d_in[15];
    const float* Wc1  = (const float*)d_in[16];
    const float* bc1  = (const float*)d_in[17];
    const float* Wc2  = (const float*)d_in[18];
    const float* bc2  = (const float*)d_in[19];

    char* ws = (char*)d_ws;
    ushort* W1p = (ushort*)ws;                 // 32768 ush = 64 KB
    ushort* W2p = W1p + 32768;                 // 65536 ush = 128 KB
    float* sums    = (float*)(ws + 196608);    // N*D (node_h A)
    float* nodeB   = sums + (long)NN * D;      // N*D
    float* counts  = nodeB + (long)NN * D;     // N
    int*   deg     = (int*)(counts + NN);      // N
    int*   offsets = deg + NN;                 // N
    int*   cursor  = offsets + NN;             // N (dead after scatter)
    int*   partials= cursor + NN;              // 256
    int*   csr     = partials + 256;           // E
    ushort* Gp     = (ushort*)cursor;          // 4*32768 ush = 256 KB, reuses cursor

    pack_weights<<<8, 256, 0, stream>>>(W1, H1, 32, W1p);
    pack_weights<<<16, 256, 0, stream>>>(W2, D, 64, W2p);

    hipMemsetAsync(sums,   0, (long)NN * D * sizeof(float), stream);
    hipMemsetAsync(counts, 0, NN * sizeof(float), stream);
    hipMemsetAsync(deg,    0, NN * sizeof(int), stream);

    fe_mfma<<<R_ROWS / FE_ROWS, 256, 0, stream>>>(bulk, seg, W1p, b1, W2p, b2, sums, counts);
    divide_kernel<<<((long)NN * D + 255) / 256, 256, 0, stream>>>(sums, counts, sums);

    hist_kernel<<<(NE + 255) / 256, 256, 0, stream>>>(edst, deg);
    const int nchunks = (NN + SCHUNK - 1) / SCHUNK;
    scan_reduce<<<nchunks, 256, 0, stream>>>(deg, partials, NN);
    scan_partials<<<1, 64, 0, stream>>>(partials, nchunks);
    scan_write<<<nchunks, 256, 0, stream>>>(deg, partials, offsets, NN);
    hipMemcpyAsync(cursor, offsets, NN * sizeof(int), hipMemcpyDeviceToDevice, stream);
    scatter_edges<<<(NE + 255) / 256, 256, 0, stream>>>(esrc, edst, cursor, csr);

    // cursor is dead now: pack GIN weights into its space
    for (int l = 0; l < N_GIN; ++l)
        pack_weights<<<8, 256, 0, stream>>>(ginW + (long)l * D * D, D, 32, Gp + (long)l * 32768);

    float* hA = sums;
    float* hB = nodeB;
    for (int l = 0; l < N_GIN; ++l) {
        gin_agg<<<(NN + 3) / 4, 256, 0, stream>>>(hA, offsets, deg, csr, hB);
        gin_gemm_mfma<<<NN / 32, 256, 0, stream>>>(hB, Gp + (long)l * 32768, ginb + (long)l * D, hA);
    }

    head_kernel<<<NB, 256, 0, stream>>>(hA, root, Wa1, ba1, Wa2, ba2,
                                        Wc1, bc1, Wc2, bc2,
                                        (float*)d_out, (float*)d_out + (long)NB * NTOK);
}

// Round 3
// 1390.455 us; speedup vs baseline: 3.9534x; 1.1116x over previous
//
#include <hip/hip_runtime.h>
#include <math.h>

#define R_ROWS 1048576
#define F_IN   64
#define H1     256
#define D      128
#define NN     100000
#define NE     1600000
#define NB     4096
#define A1     256
#define NTOK   16
#define N_GIN  4
#define FE_ROWS 64

typedef short short8 __attribute__((ext_vector_type(8)));
typedef float f32x4  __attribute__((ext_vector_type(4)));
typedef unsigned int uintx4 __attribute__((ext_vector_type(4)));

__device__ __forceinline__ ushort f2bf(float x) {
    uint u = __builtin_bit_cast(uint, x);
    u += 0x7FFFu + ((u >> 16) & 1u);
    return (ushort)(u >> 16);
}
__device__ __forceinline__ float bf2f(ushort h) {
    uint u = ((uint)h) << 16;
    return __builtin_bit_cast(float, u);
}
// packed split: low16 = bf16(x) (hi plane), high16 = bf16(x - hi) (lo plane)
// v_cvt_pk_bf16_f32 with both srcs equal is operand-order-immune.
__device__ __forceinline__ uint packsplit(float x) {
    uint h;
    asm("v_cvt_pk_bf16_f32 %0, %1, %1" : "=v"(h) : "v"(x));
    const float hf = __builtin_bit_cast(float, h << 16);
    const float d = x - hf;
    uint l;
    asm("v_cvt_pk_bf16_f32 %0, %1, %1" : "=v"(l) : "v"(d));
    return __builtin_amdgcn_perm(l, h, 0x05040100u);   // [h.b0,h.b1,l.b0,l.b1]
}
__device__ __forceinline__ f32x4 mm(short8 a, short8 b, f32x4 c) {
    return __builtin_amdgcn_mfma_f32_16x16x32_bf16(a, b, c, 0, 0, 0);
}
// q0 = packed dwords for k0..k3, q1 for k4..k7 -> hi/lo short8 planes (8 v_perm)
__device__ __forceinline__ void unpack_pair(const uintx4 q0, const uintx4 q1,
                                            short8& hi, short8& lo) {
    uintx4 H, L;
    H[0] = __builtin_amdgcn_perm(q0[1], q0[0], 0x05040100u);
    H[1] = __builtin_amdgcn_perm(q0[3], q0[2], 0x05040100u);
    H[2] = __builtin_amdgcn_perm(q1[1], q1[0], 0x05040100u);
    H[3] = __builtin_amdgcn_perm(q1[3], q1[2], 0x05040100u);
    L[0] = __builtin_amdgcn_perm(q0[1], q0[0], 0x07060302u);
    L[1] = __builtin_amdgcn_perm(q0[3], q0[2], 0x07060302u);
    L[2] = __builtin_amdgcn_perm(q1[1], q1[0], 0x07060302u);
    L[3] = __builtin_amdgcn_perm(q1[3], q1[2], 0x07060302u);
    hi = __builtin_bit_cast(short8, H);
    lo = __builtin_bit_cast(short8, L);
}

// ---------------------------------------------------------------------------
// Pack a [K][N] f32 weight into MFMA-fragment order, bf16 hi/lo planes.
// ---------------------------------------------------------------------------
__global__ __launch_bounds__(256) void pack_weights(
    const float* __restrict__ W, int Ndim, int nfrag, ushort* __restrict__ out)
{
    const int id = blockIdx.x * 256 + threadIdx.x;
    const int f = id >> 6, lane = id & 63;
    if (f >= nfrag) return;
    const int NTn = Ndim >> 4;
    const int kt = f / NTn, nt = f - kt * NTn;
    const int k0 = kt * 32 + (lane >> 4) * 8;
    const int n = nt * 16 + (lane & 15);
    uintx4 Hv, Lv;
    #pragma unroll
    for (int jj = 0; jj < 4; ++jj) {
        const float x0 = W[(k0 + 2 * jj) * Ndim + n];
        const float x1 = W[(k0 + 2 * jj + 1) * Ndim + n];
        const ushort h0 = f2bf(x0), l0 = f2bf(x0 - bf2f(h0));
        const ushort h1u = f2bf(x1), l1 = f2bf(x1 - bf2f(h1u));
        Hv[jj] = (uint)h0 | ((uint)h1u << 16);
        Lv[jj] = (uint)l0 | ((uint)l1 << 16);
    }
    *reinterpret_cast<uintx4*>(&out[((f * 2 + 0) * 64 + lane) * 8]) = Hv;
    *reinterpret_cast<uintx4*>(&out[((f * 2 + 1) * 64 + lane) * 8]) = Lv;
}

// ---------------------------------------------------------------------------
// Fused feature extractor + segment sum. 64 rows/block, 4 waves.
// ---------------------------------------------------------------------------
__global__ __launch_bounds__(256, 2) void fe_mfma(
    const float* __restrict__ bulk, const int* __restrict__ seg,
    const ushort* __restrict__ W1p, const float* __restrict__ b1,
    const ushort* __restrict__ W2p, const float* __restrict__ b2,
    float* __restrict__ sums)
{
    __shared__ __align__(16) uint smem_u[FE_ROWS * 256];   // 64 KB
    float* h2 = (float*)smem_u;                             // [64][132] overlay

    const int t = threadIdx.x;
    const int lane = t & 63;
    const int w = t >> 6;
    const long r0 = (long)blockIdx.x * FE_ROWS;

    // ---- stage A packed: [64 rows][64 cols] dwords, group-XOR swizzle ----
    #pragma unroll
    for (int i = 0; i < 4; ++i) {
        const int gid = t + i * 256;          // 64 rows x 16 groups
        const int row = gid >> 4;
        const int g4 = gid & 15;
        const float4 v = *reinterpret_cast<const float4*>(&bulk[(r0 + row) * F_IN + g4 * 4]);
        uintx4 pk;
        pk[0] = packsplit(v.x); pk[1] = packsplit(v.y);
        pk[2] = packsplit(v.z); pk[3] = packsplit(v.w);
        *reinterpret_cast<uintx4*>(&smem_u[row * 64 + ((g4 ^ (row & 7)) << 2)]) = pk;
    }

    // ---- W1 fragments + biases ----
    short8 bw1[4][2][2];
    #pragma unroll
    for (int ntl = 0; ntl < 4; ++ntl)
        #pragma unroll
        for (int kt = 0; kt < 2; ++kt)
            #pragma unroll
            for (int p = 0; p < 2; ++p) {
                const int f = kt * 16 + (w * 4 + ntl);
                bw1[ntl][kt][p] = *reinterpret_cast<const short8*>(&W1p[((f * 2 + p) * 64 + lane) * 8]);
            }
    float b1v[4], b2v[2];
    #pragma unroll
    for (int ntl = 0; ntl < 4; ++ntl) b1v[ntl] = b1[w * 64 + ntl * 16 + (lane & 15)];
    #pragma unroll
    for (int ntl = 0; ntl < 2; ++ntl) b2v[ntl] = b2[w * 32 + ntl * 16 + (lane & 15)];

    __syncthreads();

    // ---- A fragments from packed LDS (perm unpack) ----
    short8 a1h[4][2], a1l[4][2];
    #pragma unroll
    for (int mt = 0; mt < 4; ++mt)
        #pragma unroll
        for (int kt = 0; kt < 2; ++kt) {
            const int row = mt * 16 + (lane & 15);
            const int g0 = kt * 8 + (lane >> 4) * 2;
            const int swz = lane & 7;
            const uintx4 q0 = *reinterpret_cast<const uintx4*>(&smem_u[row * 64 + ((g0 ^ swz) << 2)]);
            const uintx4 q1 = *reinterpret_cast<const uintx4*>(&smem_u[row * 64 + (((g0 + 1) ^ swz) << 2)]);
            unpack_pair(q0, q1, a1h[mt][kt], a1l[mt][kt]);
        }
    __syncthreads();

    // ---- layer 1 MFMA (3-term split) ----
    const f32x4 zz = {0.f, 0.f, 0.f, 0.f};
    f32x4 acc1[4][4];
    #pragma unroll
    for (int mt = 0; mt < 4; ++mt)
        #pragma unroll
        for (int ntl = 0; ntl < 4; ++ntl) {
            f32x4 a = zz;
            #pragma unroll
            for (int kt = 0; kt < 2; ++kt) {
                a = mm(a1h[mt][kt], bw1[ntl][kt][0], a);
                a = mm(a1h[mt][kt], bw1[ntl][kt][1], a);
                a = mm(a1l[mt][kt], bw1[ntl][kt][0], a);
            }
            acc1[mt][ntl] = a;
        }

    // ---- h1 packed to LDS [64][256] dwords, group-XOR swizzle ----
    #pragma unroll
    for (int mt = 0; mt < 4; ++mt)
        #pragma unroll
        for (int ntl = 0; ntl < 4; ++ntl)
            #pragma unroll
            for (int r = 0; r < 4; ++r) {
                const int row = mt * 16 + (lane >> 4) * 4 + r;
                const int col = w * 64 + ntl * 16 + (lane & 15);
                const float x = fmaxf(acc1[mt][ntl][r] + b1v[ntl], 0.f);
                const int addr = row * 256 + ((((col >> 2) ^ (row & 7)) << 2) | (col & 3));
                smem_u[addr] = packsplit(x);
            }
    __syncthreads();

    // ---- layer 2 ----
    f32x4 acc2[4][2];
    #pragma unroll
    for (int mt = 0; mt < 4; ++mt) { acc2[mt][0] = zz; acc2[mt][1] = zz; }

    #pragma unroll
    for (int kt = 0; kt < 8; ++kt) {
        short8 bw2[2][2];
        #pragma unroll
        for (int ntl = 0; ntl < 2; ++ntl)
            #pragma unroll
            for (int p = 0; p < 2; ++p) {
                const int f = kt * 8 + (w * 2 + ntl);
                bw2[ntl][p] = *reinterpret_cast<const short8*>(&W2p[((f * 2 + p) * 64 + lane) * 8]);
            }
        #pragma unroll
        for (int mt = 0; mt < 4; ++mt) {
            const int row = mt * 16 + (lane & 15);
            const int g0 = kt * 8 + (lane >> 4) * 2;
            const int swz = lane & 7;
            const uintx4 q0 = *reinterpret_cast<const uintx4*>(&smem_u[row * 256 + ((g0 ^ swz) << 2)]);
            const uintx4 q1 = *reinterpret_cast<const uintx4*>(&smem_u[row * 256 + (((g0 + 1) ^ swz) << 2)]);
            short8 ah, al;
            unpack_pair(q0, q1, ah, al);
            #pragma unroll
            for (int ntl = 0; ntl < 2; ++ntl) {
                acc2[mt][ntl] = mm(ah, bw2[ntl][0], acc2[mt][ntl]);
                acc2[mt][ntl] = mm(ah, bw2[ntl][1], acc2[mt][ntl]);
                acc2[mt][ntl] = mm(al, bw2[ntl][0], acc2[mt][ntl]);
            }
        }
    }
    __syncthreads();

    // ---- h2 (relu+bias) ----
    #pragma unroll
    for (int mt = 0; mt < 4; ++mt)
        #pragma unroll
        for (int ntl = 0; ntl < 2; ++ntl)
            #pragma unroll
            for (int r = 0; r < 4; ++r) {
                const int row = mt * 16 + (lane >> 4) * 4 + r;
                const int col = w * 32 + ntl * 16 + (lane & 15);
                h2[row * 132 + col] = fmaxf(acc2[mt][ntl][r] + b2v[ntl], 0.f);
            }
    __syncthreads();

    // ---- segment sums: 2 half-windows x 128 cols, interior runs -> store ----
    {
        const int g = t >> 7;           // half-window 0/1
        const int c = t & 127;
        const int base = g * 32;
        const long rb = r0 + base;
        const int prev = (rb == 0) ? -1 : seg[rb - 1];
        const int nxt = (rb + 32 >= R_ROWS) ? -1 : seg[rb + 32];
        int cur = seg[rb];
        float run = 0.f;
        int runstart = 0;
        #pragma unroll 1
        for (int r = 0; r < 32; ++r) {
            const int s = seg[rb + r];
            if (s != cur) {
                if (runstart != 0 || cur != prev) sums[(long)cur * D + c] = run;
                else atomicAdd(&sums[(long)cur * D + c], run);
                cur = s; run = 0.f; runstart = r;
            }
            run += h2[(base + r) * 132 + c];
        }
        if ((runstart != 0 || cur != prev) && cur != nxt) sums[(long)cur * D + c] = run;
        else atomicAdd(&sums[(long)cur * D + c], run);
    }
}

// start[n] = lower_bound(seg, n) for n in [0, NN]
__global__ __launch_bounds__(256) void start_kernel(const int* __restrict__ seg,
                                                    int* __restrict__ start)
{
    const int n = blockIdx.x * 256 + threadIdx.x;
    if (n > NN) return;
    int lo = 0, hi = R_ROWS;
    #pragma unroll 1
    while (lo < hi) {
        const int mid = (lo + hi) >> 1;
        if (seg[mid] < n) lo = mid + 1; else hi = mid;
    }
    start[n] = lo;
}

// node_h = sums / max(count,1), count from start diff
__global__ __launch_bounds__(256) void divide_kernel(
    const float* __restrict__ sums, const int* __restrict__ start,
    float* __restrict__ nodeh)
{
    const long i = (long)blockIdx.x * 256 + threadIdx.x;
    if (i < (long)NN * D) {
        const int n = (int)(i >> 7);
        const float cnt = (float)(start[n + 1] - start[n]);
        nodeh[i] = sums[i] / fmaxf(cnt, 1.f);
    }
}

// ---------------------------------------------------------------------------
// CSR build over edge_dst
// ---------------------------------------------------------------------------
__global__ __launch_bounds__(256) void hist_kernel(const int* __restrict__ edst,
                                                   int* __restrict__ deg)
{
    const int e = blockIdx.x * 256 + threadIdx.x;
    if (e < NE) atomicAdd(&deg[edst[e]], 1);
}

#define SCHUNK 2048
__global__ __launch_bounds__(256) void scan_reduce(const int* __restrict__ deg,
                                                   int* __restrict__ partials, int n)
{
    __shared__ int sdata[256];
    const int b = blockIdx.x, t = threadIdx.x;
    const int base = b * SCHUNK;
    int sum = 0;
    for (int i = t; i < SCHUNK; i += 256) {
        const int idx = base + i;
        sum += (idx < n) ? deg[idx] : 0;
    }
    sdata[t] = sum; __syncthreads();
    for (int s = 128; s > 0; s >>= 1) {
        if (t < s) sdata[t] += sdata[t + s];
        __syncthreads();
    }
    if (t == 0) partials[b] = sdata[0];
}

__global__ void scan_partials(int* partials, int nb)
{
    if (threadIdx.x == 0) {
        int acc = 0;
        for (int i = 0; i < nb; ++i) { const int v = partials[i]; partials[i] = acc; acc += v; }
    }
}

__global__ __launch_bounds__(256) void scan_write(const int* __restrict__ deg,
                                                  const int* __restrict__ partials,
                                                  int* __restrict__ offsets, int n)
{
    __shared__ int sdata[256];
    const int b = blockIdx.x, t = threadIdx.x;
    const int base = b * SCHUNK;
    int loc[8]; int s = 0;
    #pragma unroll
    for (int j = 0; j < 8; ++j) {
        const int idx = base + t * 8 + j;
        const int v = (idx < n) ? deg[idx] : 0;
        loc[j] = s; s += v;
    }
    sdata[t] = s; __syncthreads();
    for (int d = 1; d < 256; d <<= 1) {
        const int v = (t >= d) ? sdata[t - d] : 0;
        __syncthreads();
        sdata[t] += v;
        __syncthreads();
    }
    const int excl = (t == 0) ? 0 : sdata[t - 1];
    const int tbase = partials[b] + excl;
    #pragma unroll
    for (int j = 0; j < 8; ++j) {
        const int idx = base + t * 8 + j;
        if (idx < n) offsets[idx] = tbase + loc[j];
    }
}

__global__ __launch_bounds__(256) void scatter_edges(const int* __restrict__ esrc,
                                                     const int* __restrict__ edst,
                                                     int* __restrict__ cursor,
                                                     int* __restrict__ csr_src)
{
    const int e = blockIdx.x * 256 + threadIdx.x;
    if (e < NE) {
        const int d = edst[e];
        const int p = atomicAdd(&cursor[d], 1);
        csr_src[p] = esrc[e];
    }
}

// ---------------------------------------------------------------------------
// Fused GIN layer: gather-aggregate (4 waves x 16 nodes) -> LDS packed tile
// -> 64x128x128 split MFMA -> relu -> hout.
// ---------------------------------------------------------------------------
__global__ __launch_bounds__(256, 4) void gin_fused(
    const float* __restrict__ h, const int* __restrict__ offsets,
    const int* __restrict__ deg, const int* __restrict__ csr,
    const ushort* __restrict__ Wp, const float* __restrict__ bvec,
    float* __restrict__ hout)
{
    __shared__ __align__(16) uint ypk[64 * 128];   // 32 KB
    const int t = threadIdx.x, lane = t & 63, w = t >> 6;
    const int r0 = blockIdx.x * 64;

    // ---- phase 1: aggregate 16 nodes per wave ----
    #pragma unroll 1
    for (int i = 0; i < 16; ++i) {
        const int n = r0 + w * 16 + i;
        const int row = w * 16 + i;
        float ax = 0.f, ay = 0.f;
        if (n < NN) {
            const float2 self = *reinterpret_cast<const float2*>(&h[(long)n * D + lane * 2]);
            ax = 2.1f * self.x; ay = 2.1f * self.y;
            const int off = offsets[n];
            const int dg = deg[n];
            int j = 0;
            for (; j + 4 <= dg; j += 4) {
                const int s0 = csr[off + j], s1 = csr[off + j + 1];
                const int s2 = csr[off + j + 2], s3 = csr[off + j + 3];
                const float2 v0 = *reinterpret_cast<const float2*>(&h[(long)s0 * D + lane * 2]);
                const float2 v1 = *reinterpret_cast<const float2*>(&h[(long)s1 * D + lane * 2]);
                const float2 v2 = *reinterpret_cast<const float2*>(&h[(long)s2 * D + lane * 2]);
                const float2 v3 = *reinterpret_cast<const float2*>(&h[(long)s3 * D + lane * 2]);
                ax += v0.x + v1.x + v2.x + v3.x;
                ay += v0.y + v1.y + v2.y + v3.y;
            }
            for (; j < dg; ++j) {
                const int s = csr[off + j];
                const float2 v = *reinterpret_cast<const float2*>(&h[(long)s * D + lane * 2]);
                ax += v.x; ay += v.y;
            }
        }
        const int col = lane * 2;
        const int addr = row * 128 + ((((col >> 2) ^ (row & 7)) << 2) | (col & 3));
        uint2 pk;
        pk.x = packsplit(ax); pk.y = packsplit(ay);
        *reinterpret_cast<uint2*>(&ypk[addr]) = pk;
    }
    __syncthreads();

    // ---- phase 2: GEMM 64x128 @ 128x128 ----
    const f32x4 zz = {0.f, 0.f, 0.f, 0.f};
    f32x4 acc[4][2];
    #pragma unroll
    for (int mt = 0; mt < 4; ++mt) { acc[mt][0] = zz; acc[mt][1] = zz; }

    #pragma unroll
    for (int kt = 0; kt < 4; ++kt) {
        short8 bw[2][2];
        #pragma unroll
        for (int ntl = 0; ntl < 2; ++ntl)
            #pragma unroll
            for (int p = 0; p < 2; ++p) {
                const int f = kt * 8 + (w * 2 + ntl);
                bw[ntl][p] = *reinterpret_cast<const short8*>(&Wp[((f * 2 + p) * 64 + lane) * 8]);
            }
        #pragma unroll
        for (int mt = 0; mt < 4; ++mt) {
            const int row = mt * 16 + (lane & 15);
            const int g0 = kt * 8 + (lane >> 4) * 2;
            const int swz = lane & 7;
            const uintx4 q0 = *reinterpret_cast<const uintx4*>(&ypk[row * 128 + ((g0 ^ swz) << 2)]);
            const uintx4 q1 = *reinterpret_cast<const uintx4*>(&ypk[row * 128 + (((g0 + 1) ^ swz) << 2)]);
            short8 ah, al;
            unpack_pair(q0, q1, ah, al);
            #pragma unroll
            for (int ntl = 0; ntl < 2; ++ntl) {
                acc[mt][ntl] = mm(ah, bw[ntl][0], acc[mt][ntl]);
                acc[mt][ntl] = mm(ah, bw[ntl][1], acc[mt][ntl]);
                acc[mt][ntl] = mm(al, bw[ntl][0], acc[mt][ntl]);
            }
        }
    }

    const float bv0 = bvec[w * 32 + (lane & 15)];
    const float bv1 = bvec[w * 32 + 16 + (lane & 15)];
    #pragma unroll
    for (int mt = 0; mt < 4; ++mt)
        #pragma unroll
        for (int r = 0; r < 4; ++r) {
            const long grow = r0 + mt * 16 + (lane >> 4) * 4 + r;
            if (grow < NN) {
                hout[grow * D + w * 32 + (lane & 15)] = fmaxf(acc[mt][0][r] + bv0, 0.f);
                hout[grow * D + w * 32 + 16 + (lane & 15)] = fmaxf(acc[mt][1][r] + bv1, 0.f);
            }
        }
}

// ---------------------------------------------------------------------------
// Heads: one block per root
// ---------------------------------------------------------------------------
__global__ __launch_bounds__(256) void head_kernel(
    const float* __restrict__ h, const int* __restrict__ root,
    const float* __restrict__ Wa1, const float* __restrict__ ba1,
    const float* __restrict__ Wa2, const float* __restrict__ ba2,
    const float* __restrict__ Wc1, const float* __restrict__ bc1,
    const float* __restrict__ Wc2, const float* __restrict__ bc2,
    float* __restrict__ out_act, float* __restrict__ out_crit)
{
    __shared__ float X[D];
    __shared__ float a1[A1];
    __shared__ float red[256];
    __shared__ float logits[NTOK];
    const int t = threadIdx.x;
    const int bi = blockIdx.x;
    const int n = root[bi];
    if (t < 32)
        *reinterpret_cast<float4*>(&X[t * 4]) =
            *reinterpret_cast<const float4*>(&h[(long)n * D + t * 4]);
    __syncthreads();

    float acc = ba1[t];
    #pragma unroll
    for (int k = 0; k < D; k += 4) {
        const float4 xv = *reinterpret_cast<const float4*>(&X[k]);
        acc = fmaf(xv.x, Wa1[(k + 0) * A1 + t], acc);
        acc = fmaf(xv.y, Wa1[(k + 1) * A1 + t], acc);
        acc = fmaf(xv.z, Wa1[(k + 2) * A1 + t], acc);
        acc = fmaf(xv.w, Wa1[(k + 3) * A1 + t], acc);
    }
    a1[t] = fmaxf(acc, 0.f);
    __syncthreads();

    const int j = t & 15, p = t >> 4;
    float pa = 0.f;
    #pragma unroll
    for (int k = 0; k < 16; ++k) {
        const int kk = p * 16 + k;
        pa = fmaf(a1[kk], Wa2[kk * NTOK + j], pa);
    }
    red[j * 16 + p] = pa;
    __syncthreads();
    if (t < NTOK) {
        float s = 0.f;
        #pragma unroll
        for (int p2 = 0; p2 < 16; ++p2) s += red[t * 16 + p2];
        logits[t] = fmaxf(s + ba2[t], 0.f);
    }
    __syncthreads();
    if (t < NTOK) {
        float mx = -1e30f;
        #pragma unroll
        for (int i = 0; i < NTOK; ++i) mx = fmaxf(mx, logits[i]);
        red[t] = expf(logits[t] - mx);
    }
    __syncthreads();
    if (t < NTOK) {
        float s = 0.f;
        #pragma unroll
        for (int i = 0; i < NTOK; ++i) s += red[i];
        out_act[(long)bi * NTOK + t] = red[t] / s;
    }
    __syncthreads();

    float accc = bc1[t];
    #pragma unroll
    for (int k = 0; k < D; k += 4) {
        const float4 xv = *reinterpret_cast<const float4*>(&X[k]);
        accc = fmaf(xv.x, Wc1[(k + 0) * A1 + t], accc);
        accc = fmaf(xv.y, Wc1[(k + 1) * A1 + t], accc);
        accc = fmaf(xv.z, Wc1[(k + 2) * A1 + t], accc);
        accc = fmaf(xv.w, Wc1[(k + 3) * A1 + t], accc);
    }
    red[t] = fmaxf(accc, 0.f) * Wc2[t];
    __syncthreads();
    for (int s = 128; s > 0; s >>= 1) {
        if (t < s) red[t] += red[t + s];
        __syncthreads();
    }
    if (t == 0) out_crit[bi] = red[0] + bc2[0];
}

// ---------------------------------------------------------------------------
extern "C" void kernel_launch(void* const* d_in, const int* in_sizes, int n_in,
                              void* d_out, int out_size, void* d_ws, size_t ws_size,
                              hipStream_t stream)
{
    const float* bulk = (const float*)d_in[0];
    const int*   seg  = (const int*)d_in[1];
    const int*   esrc = (const int*)d_in[2];
    const int*   edst = (const int*)d_in[3];
    const int*   root = (const int*)d_in[4];
    const float* W1   = (const float*)d_in[6];
    const float* b1   = (const float*)d_in[7];
    const float* W2   = (const float*)d_in[8];
    const float* b2   = (const float*)d_in[9];
    const float* ginW = (const float*)d_in[10];
    const float* ginb = (const float*)d_in[11];
    const float* Wa1  = (const float*)d_in[12];
    const float* ba1  = (const float*)d_in[13];
    const float* Wa2  = (const float*)d_in[14];
    const float* ba2  = (const float*)d_in[15];
    const float* Wc1  = (const float*)d_in[16];
    const float* bc1  = (const float*)d_in[17];
    const float* Wc2  = (const float*)d_in[18];
    const float* bc2  = (const float*)d_in[19];

    char* ws = (char*)d_ws;
    ushort* W1p = (ushort*)ws;                 // 64 KB
    ushort* W2p = W1p + 32768;                 // 128 KB
    float* sums    = (float*)(ws + 196608);    // N*D (node_h A)
    float* nodeB   = sums + (long)NN * D;      // N*D
    int*   start   = (int*)(nodeB + (long)NN * D); // N+1
    int*   deg     = start + (NN + 1);         // N
    int*   offsets = deg + NN;                 // N
    int*   cursor  = offsets + NN;             // N (dead after scatter)
    int*   partials= cursor + NN;              // 256
    int*   csr     = partials + 256;           // E
    ushort* Gp     = (ushort*)cursor;          // 256 KB, reuses cursor

    pack_weights<<<8, 256, 0, stream>>>(W1, H1, 32, W1p);
    pack_weights<<<16, 256, 0, stream>>>(W2, D, 64, W2p);

    hipMemsetAsync(sums, 0, (long)NN * D * sizeof(float), stream);
    hipMemsetAsync(deg, 0, NN * sizeof(int), stream);

    fe_mfma<<<R_ROWS / FE_ROWS, 256, 0, stream>>>(bulk, seg, W1p, b1, W2p, b2, sums);
    start_kernel<<<(NN + 256) / 256, 256, 0, stream>>>(seg, start);
    divide_kernel<<<((long)NN * D + 255) / 256, 256, 0, stream>>>(sums, start, sums);

    hist_kernel<<<(NE + 255) / 256, 256, 0, stream>>>(edst, deg);
    const int nchunks = (NN + SCHUNK - 1) / SCHUNK;
    scan_reduce<<<nchunks, 256, 0, stream>>>(deg, partials, NN);
    scan_partials<<<1, 64, 0, stream>>>(partials, nchunks);
    scan_write<<<nchunks, 256, 0, stream>>>(deg, partials, offsets, NN);
    hipMemcpyAsync(cursor, offsets, NN * sizeof(int), hipMemcpyDeviceToDevice, stream);
    scatter_edges<<<(NE + 255) / 256, 256, 0, stream>>>(esrc, edst, cursor, csr);

    // cursor dead: pack GIN weights into its space
    for (int l = 0; l < N_GIN; ++l)
        pack_weights<<<8, 256, 0, stream>>>(ginW + (long)l * D * D, D, 32, Gp + (long)l * 32768);

    float* hA = sums;
    float* hB = nodeB;
    for (int l = 0; l < N_GIN; ++l) {
        gin_fused<<<(NN + 63) / 64, 256, 0, stream>>>(hA, offsets, deg, csr,
                                                      Gp + (long)l * 32768, ginb + (long)l * D, hB);
        float* tmp = hA; hA = hB; hB = tmp;
    }

    head_kernel<<<NB, 256, 0, stream>>>(hA, root, Wa1, ba1, Wa2, ba2,
                                        Wc1, bc1, Wc2, bc2,
                                        (float*)d_out, (float*)d_out + (long)NB * NTOK);
}

// Round 4
// 1244.362 us; speedup vs baseline: 4.4175x; 1.1174x over previous
//
#include <hip/hip_runtime.h>
#include <math.h>

#define R_ROWS 1048576
#define F_IN   64
#define H1     256
#define D      128
#define NN     100000
#define NE     1600000
#define NB     4096
#define A1     256
#define NTOK   16
#define N_GIN  4
#define FE_ROWS 64

typedef short short8 __attribute__((ext_vector_type(8)));
typedef float f32x4  __attribute__((ext_vector_type(4)));
typedef unsigned int uintx4 __attribute__((ext_vector_type(4)));

__device__ __forceinline__ ushort f2bf(float x) {
    uint u = __builtin_bit_cast(uint, x);
    u += 0x7FFFu + ((u >> 16) & 1u);
    return (ushort)(u >> 16);
}
__device__ __forceinline__ float bf2f(ushort h) {
    uint u = ((uint)h) << 16;
    return __builtin_bit_cast(float, u);
}
// dst.lo16 = bf16(lo), dst.hi16 = bf16(hi)
__device__ __forceinline__ uint cvtpk(float lo, float hi) {
    uint r;
    asm("v_cvt_pk_bf16_f32 %0, %1, %2" : "=v"(r) : "v"(lo), "v"(hi));
    return r;
}
__device__ __forceinline__ float lo16f(uint p) { return __builtin_bit_cast(float, p << 16); }
__device__ __forceinline__ float hi16f(uint p) { return __builtin_bit_cast(float, p & 0xFFFF0000u); }

// packed split (GIN path): low16 = bf16(x) hi plane, high16 = bf16 residual
__device__ __forceinline__ uint packsplit(float x) {
    uint h;
    asm("v_cvt_pk_bf16_f32 %0, %1, %1" : "=v"(h) : "v"(x));
    const float d = x - lo16f(h);
    uint l;
    asm("v_cvt_pk_bf16_f32 %0, %1, %1" : "=v"(l) : "v"(d));
    return __builtin_amdgcn_perm(l, h, 0x05040100u);
}
__device__ __forceinline__ f32x4 mm(short8 a, short8 b, f32x4 c) {
    return __builtin_amdgcn_mfma_f32_16x16x32_bf16(a, b, c, 0, 0, 0);
}
__device__ __forceinline__ void unpack_pair(const uintx4 q0, const uintx4 q1,
                                            short8& hi, short8& lo) {
    uintx4 H, L;
    H[0] = __builtin_amdgcn_perm(q0[1], q0[0], 0x05040100u);
    H[1] = __builtin_amdgcn_perm(q0[3], q0[2], 0x05040100u);
    H[2] = __builtin_amdgcn_perm(q1[1], q1[0], 0x05040100u);
    H[3] = __builtin_amdgcn_perm(q1[3], q1[2], 0x05040100u);
    L[0] = __builtin_amdgcn_perm(q0[1], q0[0], 0x07060302u);
    L[1] = __builtin_amdgcn_perm(q0[3], q0[2], 0x07060302u);
    L[2] = __builtin_amdgcn_perm(q1[1], q1[0], 0x07060302u);
    L[3] = __builtin_amdgcn_perm(q1[3], q1[2], 0x07060302u);
    hi = __builtin_bit_cast(short8, H);
    lo = __builtin_bit_cast(short8, L);
}

// ---------------------------------------------------------------------------
// Pack [K][N] f32 weight into MFMA fragment order, bf16 hi/lo planes.
// Fragment lane map is symmetric for A/B: lane holds W[k0+j][n] with
// k0 = kt*32+(lane>>4)*8, n = nt*16+(lane&15). Used as B (B[k][col]) or as
// A of the transposed product (A[row][k] = W^T[row][k] = W[k][row]).
// ---------------------------------------------------------------------------
__global__ __launch_bounds__(256) void pack_weights(
    const float* __restrict__ W, int Ndim, int nfrag, ushort* __restrict__ out)
{
    const int id = blockIdx.x * 256 + threadIdx.x;
    const int f = id >> 6, lane = id & 63;
    if (f >= nfrag) return;
    const int NTn = Ndim >> 4;
    const int kt = f / NTn, nt = f - kt * NTn;
    const int k0 = kt * 32 + (lane >> 4) * 8;
    const int n = nt * 16 + (lane & 15);
    uintx4 Hv, Lv;
    #pragma unroll
    for (int jj = 0; jj < 4; ++jj) {
        const float x0 = W[(k0 + 2 * jj) * Ndim + n];
        const float x1 = W[(k0 + 2 * jj + 1) * Ndim + n];
        const ushort h0 = f2bf(x0), l0 = f2bf(x0 - bf2f(h0));
        const ushort h1u = f2bf(x1), l1 = f2bf(x1 - bf2f(h1u));
        Hv[jj] = (uint)h0 | ((uint)h1u << 16);
        Lv[jj] = (uint)l0 | ((uint)l1 << 16);
    }
    *reinterpret_cast<uintx4*>(&out[((f * 2 + 0) * 64 + lane) * 8]) = Hv;
    *reinterpret_cast<uintx4*>(&out[((f * 2 + 1) * 64 + lane) * 8]) = Lv;
}

// ---------------------------------------------------------------------------
// Fused FE + segment sum. 64 rows/block, 4 waves, 3 blocks/CU.
// L1 computes h1^T so h1 lands in LDS as plain row-major bf16 (one plane).
// ---------------------------------------------------------------------------
__global__ __launch_bounds__(256, 3) void fe_mfma(
    const float* __restrict__ bulk, const int* __restrict__ seg,
    const ushort* __restrict__ W1p, const float* __restrict__ b1,
    const ushort* __restrict__ W2p, const float* __restrict__ b2,
    float* __restrict__ sums)
{
    __shared__ __align__(16) uint smem_u[12800];      // 51200 B
    ushort* Ahi = (ushort*)smem_u;                    // [64][72] bulk hi
    ushort* Alo = Ahi + 64 * 72;                      // [64][72] bulk lo
    char*   h1b = (char*)(Alo + 64 * 72);             // 32 KB: [64][256] bf16, XOR-swz
    float*  h2  = (float*)smem_u;                     // [64][132] overlay (post-L2)

    const int t = threadIdx.x;
    const int lane = t & 63;
    const int w = t >> 6;
    const long r0 = (long)blockIdx.x * FE_ROWS;

    // ---- stage bulk rows as two bf16 planes ----
    #pragma unroll
    for (int i = 0; i < 4; ++i) {
        const int gid = t + i * 256;
        const int row = gid >> 4;
        const int c4 = (gid & 15) * 4;
        const float4 v = *reinterpret_cast<const float4*>(&bulk[(r0 + row) * F_IN + c4]);
        const uint h01 = cvtpk(v.x, v.y), h23 = cvtpk(v.z, v.w);
        const float dx = v.x - lo16f(h01);
        const float dy = v.y - hi16f(h01);
        const float dz = v.z - lo16f(h23);
        const float dw = v.w - hi16f(h23);
        const uint l01 = cvtpk(dx, dy), l23 = cvtpk(dz, dw);
        uint2 ph; ph.x = h01; ph.y = h23;
        uint2 pl; pl.x = l01; pl.y = l23;
        *reinterpret_cast<uint2*>(&Ahi[row * 72 + c4]) = ph;
        *reinterpret_cast<uint2*>(&Alo[row * 72 + c4]) = pl;
    }
    __syncthreads();

    // ---- L1 (transposed): A = W1 frags, B = bulk planes ----
    const f32x4 zz = {0.f, 0.f, 0.f, 0.f};
    f32x4 acc1[4][4];   // [mtl = h1-col tile][ntb = row tile]
    #pragma unroll
    for (int mtl = 0; mtl < 4; ++mtl)
        #pragma unroll
        for (int ntb = 0; ntb < 4; ++ntb) acc1[mtl][ntb] = zz;

    #pragma unroll
    for (int kt = 0; kt < 2; ++kt) {
        short8 aw[4][2];
        #pragma unroll
        for (int mtl = 0; mtl < 4; ++mtl)
            #pragma unroll
            for (int p = 0; p < 2; ++p) {
                const int f = kt * 16 + (w * 4 + mtl);
                aw[mtl][p] = *reinterpret_cast<const short8*>(&W1p[((f * 2 + p) * 64 + lane) * 8]);
            }
        short8 bh[4], bl[4];
        #pragma unroll
        for (int ntb = 0; ntb < 4; ++ntb) {
            const int row = ntb * 16 + (lane & 15);
            const int k0 = kt * 32 + (lane >> 4) * 8;
            bh[ntb] = *reinterpret_cast<const short8*>(&Ahi[row * 72 + k0]);
            bl[ntb] = *reinterpret_cast<const short8*>(&Alo[row * 72 + k0]);
        }
        #pragma unroll
        for (int mtl = 0; mtl < 4; ++mtl)
            #pragma unroll
            for (int ntb = 0; ntb < 4; ++ntb) {
                acc1[mtl][ntb] = mm(aw[mtl][0], bh[ntb], acc1[mtl][ntb]);
                acc1[mtl][ntb] = mm(aw[mtl][1], bh[ntb], acc1[mtl][ntb]);
                acc1[mtl][ntb] = mm(aw[mtl][0], bl[ntb], acc1[mtl][ntb]);
            }
    }

    // ---- h1 store: single bf16 plane, row-major, 16B XOR swizzle ----
    #pragma unroll
    for (int mtl = 0; mtl < 4; ++mtl) {
        const int hcb = w * 64 + mtl * 16 + (lane >> 4) * 4;
        const float4 bv = *reinterpret_cast<const float4*>(&b1[hcb]);
        #pragma unroll
        for (int ntb = 0; ntb < 4; ++ntb) {
            const int hr = (lane & 15) + ntb * 16;
            const float v0 = fmaxf(acc1[mtl][ntb][0] + bv.x, 0.f);
            const float v1 = fmaxf(acc1[mtl][ntb][1] + bv.y, 0.f);
            const float v2 = fmaxf(acc1[mtl][ntb][2] + bv.z, 0.f);
            const float v3 = fmaxf(acc1[mtl][ntb][3] + bv.w, 0.f);
            uint2 pk; pk.x = cvtpk(v0, v1); pk.y = cvtpk(v2, v3);
            const int byteoff = (hr * 512 + hcb * 2) ^ ((hr & 7) << 4);
            *reinterpret_cast<uint2*>(h1b + byteoff) = pk;
        }
    }
    __syncthreads();

    // ---- L2: h2 = relu(h1 @ W2 + b2), A-frags are direct b128 reads ----
    float b2v[2];
    #pragma unroll
    for (int ntl = 0; ntl < 2; ++ntl) b2v[ntl] = b2[w * 32 + ntl * 16 + (lane & 15)];
    f32x4 acc2[4][2];
    #pragma unroll
    for (int mt = 0; mt < 4; ++mt) { acc2[mt][0] = zz; acc2[mt][1] = zz; }

    #pragma unroll
    for (int kt = 0; kt < 8; ++kt) {
        short8 bw2[2][2];
        #pragma unroll
        for (int ntl = 0; ntl < 2; ++ntl)
            #pragma unroll
            for (int p = 0; p < 2; ++p) {
                const int f = kt * 8 + (w * 2 + ntl);
                bw2[ntl][p] = *reinterpret_cast<const short8*>(&W2p[((f * 2 + p) * 64 + lane) * 8]);
            }
        short8 ah[4];
        #pragma unroll
        for (int mt = 0; mt < 4; ++mt) {
            const int row = mt * 16 + (lane & 15);
            const int k0 = kt * 32 + (lane >> 4) * 8;
            ah[mt] = *reinterpret_cast<const short8*>(h1b + ((row * 512 + k0 * 2) ^ ((row & 7) << 4)));
        }
        #pragma unroll
        for (int mt = 0; mt < 4; ++mt)
            #pragma unroll
            for (int ntl = 0; ntl < 2; ++ntl) {
                acc2[mt][ntl] = mm(ah[mt], bw2[ntl][0], acc2[mt][ntl]);
                acc2[mt][ntl] = mm(ah[mt], bw2[ntl][1], acc2[mt][ntl]);
            }
    }
    __syncthreads();   // all h1 reads done before h2 overlays LDS

    #pragma unroll
    for (int mt = 0; mt < 4; ++mt)
        #pragma unroll
        for (int ntl = 0; ntl < 2; ++ntl)
            #pragma unroll
            for (int r = 0; r < 4; ++r) {
                const int row = mt * 16 + (lane >> 4) * 4 + r;
                const int col = w * 32 + ntl * 16 + (lane & 15);
                h2[row * 132 + col] = fmaxf(acc2[mt][ntl][r] + b2v[ntl], 0.f);
            }
    __syncthreads();

    // ---- segment sums: 2 half-windows x 128 cols ----
    {
        const int g = t >> 7;
        const int c = t & 127;
        const int base = g * 32;
        const long rb = r0 + base;
        const int prev = (rb == 0) ? -1 : seg[rb - 1];
        const int nxt = (rb + 32 >= R_ROWS) ? -1 : seg[rb + 32];
        int cur = seg[rb];
        float run = 0.f;
        int runstart = 0;
        #pragma unroll 1
        for (int r = 0; r < 32; ++r) {
            const int s = seg[rb + r];
            if (s != cur) {
                if (runstart != 0 || cur != prev) sums[(long)cur * D + c] = run;
                else atomicAdd(&sums[(long)cur * D + c], run);
                cur = s; run = 0.f; runstart = r;
            }
            run += h2[(base + r) * 132 + c];
        }
        if ((runstart != 0 || cur != prev) && cur != nxt) sums[(long)cur * D + c] = run;
        else atomicAdd(&sums[(long)cur * D + c], run);
    }
}

// start[n] = lower_bound(seg, n)
__global__ __launch_bounds__(256) void start_kernel(const int* __restrict__ seg,
                                                    int* __restrict__ start)
{
    const int n = blockIdx.x * 256 + threadIdx.x;
    if (n > NN) return;
    int lo = 0, hi = R_ROWS;
    #pragma unroll 1
    while (lo < hi) {
        const int mid = (lo + hi) >> 1;
        if (seg[mid] < n) lo = mid + 1; else hi = mid;
    }
    start[n] = lo;
}

__global__ __launch_bounds__(256) void divide_kernel(
    const float* __restrict__ sums, const int* __restrict__ start,
    float* __restrict__ nodeh)
{
    const long i = (long)blockIdx.x * 256 + threadIdx.x;
    if (i < (long)NN * D) {
        const int n = (int)(i >> 7);
        const float cnt = (float)(start[n + 1] - start[n]);
        nodeh[i] = sums[i] / fmaxf(cnt, 1.f);
    }
}

// ---------------------------------------------------------------------------
// CSR build over edge_dst
// ---------------------------------------------------------------------------
__global__ __launch_bounds__(256) void hist_kernel(const int* __restrict__ edst,
                                                   int* __restrict__ deg)
{
    const int e = blockIdx.x * 256 + threadIdx.x;
    if (e < NE) atomicAdd(&deg[edst[e]], 1);
}

#define SCHUNK 2048
__global__ __launch_bounds__(256) void scan_reduce(const int* __restrict__ deg,
                                                   int* __restrict__ partials, int n)
{
    __shared__ int sdata[256];
    const int b = blockIdx.x, t = threadIdx.x;
    const int base = b * SCHUNK;
    int sum = 0;
    for (int i = t; i < SCHUNK; i += 256) {
        const int idx = base + i;
        sum += (idx < n) ? deg[idx] : 0;
    }
    sdata[t] = sum; __syncthreads();
    for (int s = 128; s > 0; s >>= 1) {
        if (t < s) sdata[t] += sdata[t + s];
        __syncthreads();
    }
    if (t == 0) partials[b] = sdata[0];
}

__global__ void scan_partials(int* partials, int nb)
{
    if (threadIdx.x == 0) {
        int acc = 0;
        for (int i = 0; i < nb; ++i) { const int v = partials[i]; partials[i] = acc; acc += v; }
    }
}

__global__ __launch_bounds__(256) void scan_write(const int* __restrict__ deg,
                                                  const int* __restrict__ partials,
                                                  int* __restrict__ offsets, int n)
{
    __shared__ int sdata[256];
    const int b = blockIdx.x, t = threadIdx.x;
    const int base = b * SCHUNK;
    int loc[8]; int s = 0;
    #pragma unroll
    for (int j = 0; j < 8; ++j) {
        const int idx = base + t * 8 + j;
        const int v = (idx < n) ? deg[idx] : 0;
        loc[j] = s; s += v;
    }
    sdata[t] = s; __syncthreads();
    for (int d = 1; d < 256; d <<= 1) {
        const int v = (t >= d) ? sdata[t - d] : 0;
        __syncthreads();
        sdata[t] += v;
        __syncthreads();
    }
    const int excl = (t == 0) ? 0 : sdata[t - 1];
    const int tbase = partials[b] + excl;
    #pragma unroll
    for (int j = 0; j < 8; ++j) {
        const int idx = base + t * 8 + j;
        if (idx < n) offsets[idx] = tbase + loc[j];
    }
}

__global__ __launch_bounds__(256) void scatter_edges(const int* __restrict__ esrc,
                                                     const int* __restrict__ edst,
                                                     int* __restrict__ cursor,
                                                     int* __restrict__ csr_src)
{
    const int e = blockIdx.x * 256 + threadIdx.x;
    if (e < NE) {
        const int d = edst[e];
        const int p = atomicAdd(&cursor[d], 1);
        csr_src[p] = esrc[e];
    }
}

// ---------------------------------------------------------------------------
// Fused GIN layer: 8-deep ILP gather (int4 CSR loads) -> packed LDS tile
// -> 64x128x128 split MFMA -> relu.
// ---------------------------------------------------------------------------
__global__ __launch_bounds__(256, 4) void gin_fused(
    const float* __restrict__ h, const int* __restrict__ offsets,
    const int* __restrict__ deg, const int* __restrict__ csr,
    const ushort* __restrict__ Wp, const float* __restrict__ bvec,
    float* __restrict__ hout)
{
    __shared__ __align__(16) uint ypk[64 * 128];   // 32 KB
    const int t = threadIdx.x, lane = t & 63, w = t >> 6;
    const int r0 = blockIdx.x * 64;

    #pragma unroll 1
    for (int i = 0; i < 16; ++i) {
        const int n = r0 + w * 16 + i;
        const int row = w * 16 + i;
        float ax = 0.f, ay = 0.f;
        if (n < NN) {
            const float2 self = *reinterpret_cast<const float2*>(&h[(long)n * D + lane * 2]);
            ax = 2.1f * self.x; ay = 2.1f * self.y;
            const int off = offsets[n];
            const int dg = deg[n];
            int j = 0;
            int lead = (4 - (off & 3)) & 3;
            if (lead > dg) lead = dg;
            for (; j < lead; ++j) {
                const int s = csr[off + j];
                const float2 v = *reinterpret_cast<const float2*>(&h[(long)s * D + lane * 2]);
                ax += v.x; ay += v.y;
            }
            for (; j + 8 <= dg; j += 8) {
                const int4 i0 = *reinterpret_cast<const int4*>(&csr[off + j]);
                const int4 i1 = *reinterpret_cast<const int4*>(&csr[off + j + 4]);
                const float2 v0 = *reinterpret_cast<const float2*>(&h[(long)i0.x * D + lane * 2]);
                const float2 v1 = *reinterpret_cast<const float2*>(&h[(long)i0.y * D + lane * 2]);
                const float2 v2 = *reinterpret_cast<const float2*>(&h[(long)i0.z * D + lane * 2]);
                const float2 v3 = *reinterpret_cast<const float2*>(&h[(long)i0.w * D + lane * 2]);
                const float2 v4 = *reinterpret_cast<const float2*>(&h[(long)i1.x * D + lane * 2]);
                const float2 v5 = *reinterpret_cast<const float2*>(&h[(long)i1.y * D + lane * 2]);
                const float2 v6 = *reinterpret_cast<const float2*>(&h[(long)i1.z * D + lane * 2]);
                const float2 v7 = *reinterpret_cast<const float2*>(&h[(long)i1.w * D + lane * 2]);
                ax += (v0.x + v1.x) + (v2.x + v3.x) + (v4.x + v5.x) + (v6.x + v7.x);
                ay += (v0.y + v1.y) + (v2.y + v3.y) + (v4.y + v5.y) + (v6.y + v7.y);
            }
            if (j + 4 <= dg) {
                const int4 i0 = *reinterpret_cast<const int4*>(&csr[off + j]);
                const float2 v0 = *reinterpret_cast<const float2*>(&h[(long)i0.x * D + lane * 2]);
                const float2 v1 = *reinterpret_cast<const float2*>(&h[(long)i0.y * D + lane * 2]);
                const float2 v2 = *reinterpret_cast<const float2*>(&h[(long)i0.z * D + lane * 2]);
                const float2 v3 = *reinterpret_cast<const float2*>(&h[(long)i0.w * D + lane * 2]);
                ax += (v0.x + v1.x) + (v2.x + v3.x);
                ay += (v0.y + v1.y) + (v2.y + v3.y);
                j += 4;
            }
            for (; j < dg; ++j) {
                const int s = csr[off + j];
                const float2 v = *reinterpret_cast<const float2*>(&h[(long)s * D + lane * 2]);
                ax += v.x; ay += v.y;
            }
        }
        const int col = lane * 2;
        const int addr = row * 128 + ((((col >> 2) ^ (row & 7)) << 2) | (col & 3));
        uint2 pk;
        pk.x = packsplit(ax); pk.y = packsplit(ay);
        *reinterpret_cast<uint2*>(&ypk[addr]) = pk;
    }
    __syncthreads();

    const f32x4 zz = {0.f, 0.f, 0.f, 0.f};
    f32x4 acc[4][2];
    #pragma unroll
    for (int mt = 0; mt < 4; ++mt) { acc[mt][0] = zz; acc[mt][1] = zz; }

    #pragma unroll
    for (int kt = 0; kt < 4; ++kt) {
        short8 bw[2][2];
        #pragma unroll
        for (int ntl = 0; ntl < 2; ++ntl)
            #pragma unroll
            for (int p = 0; p < 2; ++p) {
                const int f = kt * 8 + (w * 2 + ntl);
                bw[ntl][p] = *reinterpret_cast<const short8*>(&Wp[((f * 2 + p) * 64 + lane) * 8]);
            }
        #pragma unroll
        for (int mt = 0; mt < 4; ++mt) {
            const int row = mt * 16 + (lane & 15);
            const int g0 = kt * 8 + (lane >> 4) * 2;
            const int swz = lane & 7;
            const uintx4 q0 = *reinterpret_cast<const uintx4*>(&ypk[row * 128 + ((g0 ^ swz) << 2)]);
            const uintx4 q1 = *reinterpret_cast<const uintx4*>(&ypk[row * 128 + (((g0 + 1) ^ swz) << 2)]);
            short8 ah, al;
            unpack_pair(q0, q1, ah, al);
            #pragma unroll
            for (int ntl = 0; ntl < 2; ++ntl) {
                acc[mt][ntl] = mm(ah, bw[ntl][0], acc[mt][ntl]);
                acc[mt][ntl] = mm(ah, bw[ntl][1], acc[mt][ntl]);
                acc[mt][ntl] = mm(al, bw[ntl][0], acc[mt][ntl]);
            }
        }
    }

    const float bv0 = bvec[w * 32 + (lane & 15)];
    const float bv1 = bvec[w * 32 + 16 + (lane & 15)];
    #pragma unroll
    for (int mt = 0; mt < 4; ++mt)
        #pragma unroll
        for (int r = 0; r < 4; ++r) {
            const long grow = r0 + mt * 16 + (lane >> 4) * 4 + r;
            if (grow < NN) {
                hout[grow * D + w * 32 + (lane & 15)] = fmaxf(acc[mt][0][r] + bv0, 0.f);
                hout[grow * D + w * 32 + 16 + (lane & 15)] = fmaxf(acc[mt][1][r] + bv1, 0.f);
            }
        }
}

// ---------------------------------------------------------------------------
// Heads: one block per root
// ---------------------------------------------------------------------------
__global__ __launch_bounds__(256) void head_kernel(
    const float* __restrict__ h, const int* __restrict__ root,
    const float* __restrict__ Wa1, const float* __restrict__ ba1,
    const float* __restrict__ Wa2, const float* __restrict__ ba2,
    const float* __restrict__ Wc1, const float* __restrict__ bc1,
    const float* __restrict__ Wc2, const float* __restrict__ bc2,
    float* __restrict__ out_act, float* __restrict__ out_crit)
{
    __shared__ float X[D];
    __shared__ float a1[A1];
    __shared__ float red[256];
    __shared__ float logits[NTOK];
    const int t = threadIdx.x;
    const int bi = blockIdx.x;
    const int n = root[bi];
    if (t < 32)
        *reinterpret_cast<float4*>(&X[t * 4]) =
            *reinterpret_cast<const float4*>(&h[(long)n * D + t * 4]);
    __syncthreads();

    float acc = ba1[t];
    #pragma unroll
    for (int k = 0; k < D; k += 4) {
        const float4 xv = *reinterpret_cast<const float4*>(&X[k]);
        acc = fmaf(xv.x, Wa1[(k + 0) * A1 + t], acc);
        acc = fmaf(xv.y, Wa1[(k + 1) * A1 + t], acc);
        acc = fmaf(xv.z, Wa1[(k + 2) * A1 + t], acc);
        acc = fmaf(xv.w, Wa1[(k + 3) * A1 + t], acc);
    }
    a1[t] = fmaxf(acc, 0.f);
    __syncthreads();

    const int j = t & 15, p = t >> 4;
    float pa = 0.f;
    #pragma unroll
    for (int k = 0; k < 16; ++k) {
        const int kk = p * 16 + k;
        pa = fmaf(a1[kk], Wa2[kk * NTOK + j], pa);
    }
    red[j * 16 + p] = pa;
    __syncthreads();
    if (t < NTOK) {
        float s = 0.f;
        #pragma unroll
        for (int p2 = 0; p2 < 16; ++p2) s += red[t * 16 + p2];
        logits[t] = fmaxf(s + ba2[t], 0.f);
    }
    __syncthreads();
    if (t < NTOK) {
        float mx = -1e30f;
        #pragma unroll
        for (int i = 0; i < NTOK; ++i) mx = fmaxf(mx, logits[i]);
        red[t] = expf(logits[t] - mx);
    }
    __syncthreads();
    if (t < NTOK) {
        float s = 0.f;
        #pragma unroll
        for (int i = 0; i < NTOK; ++i) s += red[i];
        out_act[(long)bi * NTOK + t] = red[t] / s;
    }
    __syncthreads();

    float accc = bc1[t];
    #pragma unroll
    for (int k = 0; k < D; k += 4) {
        const float4 xv = *reinterpret_cast<const float4*>(&X[k]);
        accc = fmaf(xv.x, Wc1[(k + 0) * A1 + t], accc);
        accc = fmaf(xv.y, Wc1[(k + 1) * A1 + t], accc);
        accc = fmaf(xv.z, Wc1[(k + 2) * A1 + t], accc);
        accc = fmaf(xv.w, Wc1[(k + 3) * A1 + t], accc);
    }
    red[t] = fmaxf(accc, 0.f) * Wc2[t];
    __syncthreads();
    for (int s = 128; s > 0; s >>= 1) {
        if (t < s) red[t] += red[t + s];
        __syncthreads();
    }
    if (t == 0) out_crit[bi] = red[0] + bc2[0];
}

// ---------------------------------------------------------------------------
extern "C" void kernel_launch(void* const* d_in, const int* in_sizes, int n_in,
                              void* d_out, int out_size, void* d_ws, size_t ws_size,
                              hipStream_t stream)
{
    const float* bulk = (const float*)d_in[0];
    const int*   seg  = (const int*)d_in[1];
    const int*   esrc = (const int*)d_in[2];
    const int*   edst = (const int*)d_in[3];
    const int*   root = (const int*)d_in[4];
    const float* W1   = (const float*)d_in[6];
    const float* b1   = (const float*)d_in[7];
    const float* W2   = (const float*)d_in[8];
    const float* b2   = (const float*)d_in[9];
    const float* ginW = (const float*)d_in[10];
    const float* ginb = (const float*)d_in[11];
    const float* Wa1  = (const float*)d_in[12];
    const float* ba1  = (const float*)d_in[13];
    const float* Wa2  = (const float*)d_in[14];
    const float* ba2  = (const float*)d_in[15];
    const float* Wc1  = (const float*)d_in[16];
    const float* bc1  = (const float*)d_in[17];
    const float* Wc2  = (const float*)d_in[18];
    const float* bc2  = (const float*)d_in[19];

    char* ws = (char*)d_ws;
    ushort* W1p = (ushort*)ws;                 // 64 KB
    ushort* W2p = W1p + 32768;                 // 128 KB
    float* sums    = (float*)(ws + 196608);    // N*D (node_h A)
    float* nodeB   = sums + (long)NN * D;      // N*D
    int*   start   = (int*)(nodeB + (long)NN * D); // N+1
    int*   deg     = start + (NN + 1);         // N
    int*   offsets = deg + NN;                 // N
    int*   cursor  = offsets + NN;             // N (dead after scatter)
    int*   partials= cursor + NN;              // 256
    int*   csr     = partials + 256;           // E
    ushort* Gp     = (ushort*)cursor;          // 256 KB, reuses cursor

    pack_weights<<<8, 256, 0, stream>>>(W1, H1, 32, W1p);
    pack_weights<<<16, 256, 0, stream>>>(W2, D, 64, W2p);

    hipMemsetAsync(sums, 0, (long)NN * D * sizeof(float), stream);
    hipMemsetAsync(deg, 0, NN * sizeof(int), stream);

    fe_mfma<<<R_ROWS / FE_ROWS, 256, 0, stream>>>(bulk, seg, W1p, b1, W2p, b2, sums);
    start_kernel<<<(NN + 256) / 256, 256, 0, stream>>>(seg, start);
    divide_kernel<<<((long)NN * D + 255) / 256, 256, 0, stream>>>(sums, start, sums);

    hist_kernel<<<(NE + 255) / 256, 256, 0, stream>>>(edst, deg);
    const int nchunks = (NN + SCHUNK - 1) / SCHUNK;
    scan_reduce<<<nchunks, 256, 0, stream>>>(deg, partials, NN);
    scan_partials<<<1, 64, 0, stream>>>(partials, nchunks);
    scan_write<<<nchunks, 256, 0, stream>>>(deg, partials, offsets, NN);
    hipMemcpyAsync(cursor, offsets, NN * sizeof(int), hipMemcpyDeviceToDevice, stream);
    scatter_edges<<<(NE + 255) / 256, 256, 0, stream>>>(esrc, edst, cursor, csr);

    for (int l = 0; l < N_GIN; ++l)
        pack_weights<<<8, 256, 0, stream>>>(ginW + (long)l * D * D, D, 32, Gp + (long)l * 32768);

    float* hA = sums;
    float* hB = nodeB;
    for (int l = 0; l < N_GIN; ++l) {
        gin_fused<<<(NN + 63) / 64, 256, 0, stream>>>(hA, offsets, deg, csr,
                                                      Gp + (long)l * 32768, ginb + (long)l * D, hB);
        float* tmp = hA; hA = hB; hB = tmp;
    }

    head_kernel<<<NB, 256, 0, stream>>>(hA, root, Wa1, ba1, Wa2, ba2,
                                        Wc1, bc1, Wc2, bc2,
                                        (float*)d_out, (float*)d_out + (long)NB * NTOK);
}

// Round 5
// 1141.950 us; speedup vs baseline: 4.8137x; 1.0897x over previous
//
#include <hip/hip_runtime.h>
#include <math.h>

#define R_ROWS 1048576
#define F_IN   64
#define H1     256
#define D      128
#define NN     100000
#define NE     1600000
#define NB     4096
#define A1     256
#define NTOK   16
#define N_GIN  4
#define FE_ROWS 64

typedef short short8 __attribute__((ext_vector_type(8)));
typedef float f32x4  __attribute__((ext_vector_type(4)));
typedef unsigned int uintx4 __attribute__((ext_vector_type(4)));

__device__ __forceinline__ ushort f2bf(float x) {
    uint u = __builtin_bit_cast(uint, x);
    u += 0x7FFFu + ((u >> 16) & 1u);
    return (ushort)(u >> 16);
}
__device__ __forceinline__ float bf2f(ushort h) {
    uint u = ((uint)h) << 16;
    return __builtin_bit_cast(float, u);
}
// dst.lo16 = bf16(lo), dst.hi16 = bf16(hi)
__device__ __forceinline__ uint cvtpk(float lo, float hi) {
    uint r;
    asm("v_cvt_pk_bf16_f32 %0, %1, %2" : "=v"(r) : "v"(lo), "v"(hi));
    return r;
}
__device__ __forceinline__ float lo16f(uint p) { return __builtin_bit_cast(float, p << 16); }
__device__ __forceinline__ float hi16f(uint p) { return __builtin_bit_cast(float, p & 0xFFFF0000u); }

// packed split: low16 = bf16(x) hi plane, high16 = bf16 residual
__device__ __forceinline__ uint packsplit(float x) {
    uint h;
    asm("v_cvt_pk_bf16_f32 %0, %1, %1" : "=v"(h) : "v"(x));
    const float d = x - lo16f(h);
    uint l;
    asm("v_cvt_pk_bf16_f32 %0, %1, %1" : "=v"(l) : "v"(d));
    return __builtin_amdgcn_perm(l, h, 0x05040100u);
}
__device__ __forceinline__ f32x4 mm(short8 a, short8 b, f32x4 c) {
    return __builtin_amdgcn_mfma_f32_16x16x32_bf16(a, b, c, 0, 0, 0);
}
__device__ __forceinline__ void unpack_pair(const uintx4 q0, const uintx4 q1,
                                            short8& hi, short8& lo) {
    uintx4 H, L;
    H[0] = __builtin_amdgcn_perm(q0[1], q0[0], 0x05040100u);
    H[1] = __builtin_amdgcn_perm(q0[3], q0[2], 0x05040100u);
    H[2] = __builtin_amdgcn_perm(q1[1], q1[0], 0x05040100u);
    H[3] = __builtin_amdgcn_perm(q1[3], q1[2], 0x05040100u);
    L[0] = __builtin_amdgcn_perm(q0[1], q0[0], 0x07060302u);
    L[1] = __builtin_amdgcn_perm(q0[3], q0[2], 0x07060302u);
    L[2] = __builtin_amdgcn_perm(q1[1], q1[0], 0x07060302u);
    L[3] = __builtin_amdgcn_perm(q1[3], q1[2], 0x07060302u);
    hi = __builtin_bit_cast(short8, H);
    lo = __builtin_bit_cast(short8, L);
}

// ---------------------------------------------------------------------------
// Pack [K][N] f32 weight into MFMA fragment order, bf16 hi/lo planes.
// ---------------------------------------------------------------------------
__global__ __launch_bounds__(256) void pack_weights(
    const float* __restrict__ W, int Ndim, int nfrag, ushort* __restrict__ out)
{
    const int id = blockIdx.x * 256 + threadIdx.x;
    const int f = id >> 6, lane = id & 63;
    if (f >= nfrag) return;
    const int NTn = Ndim >> 4;
    const int kt = f / NTn, nt = f - kt * NTn;
    const int k0 = kt * 32 + (lane >> 4) * 8;
    const int n = nt * 16 + (lane & 15);
    uintx4 Hv, Lv;
    #pragma unroll
    for (int jj = 0; jj < 4; ++jj) {
        const float x0 = W[(k0 + 2 * jj) * Ndim + n];
        const float x1 = W[(k0 + 2 * jj + 1) * Ndim + n];
        const ushort h0 = f2bf(x0), l0 = f2bf(x0 - bf2f(h0));
        const ushort h1u = f2bf(x1), l1 = f2bf(x1 - bf2f(h1u));
        Hv[jj] = (uint)h0 | ((uint)h1u << 16);
        Lv[jj] = (uint)l0 | ((uint)l1 << 16);
    }
    *reinterpret_cast<uintx4*>(&out[((f * 2 + 0) * 64 + lane) * 8]) = Hv;
    *reinterpret_cast<uintx4*>(&out[((f * 2 + 1) * 64 + lane) * 8]) = Lv;
}

// ---------------------------------------------------------------------------
// Fused FE + segment sum. 64 rows/block, 4 waves, 3 blocks/CU.
// ---------------------------------------------------------------------------
__global__ __launch_bounds__(256, 3) void fe_mfma(
    const float* __restrict__ bulk, const int* __restrict__ seg,
    const ushort* __restrict__ W1p, const float* __restrict__ b1,
    const ushort* __restrict__ W2p, const float* __restrict__ b2,
    float* __restrict__ sums)
{
    __shared__ __align__(16) uint smem_u[12800];      // 51200 B
    ushort* Ahi = (ushort*)smem_u;                    // [64][72] bulk hi
    ushort* Alo = Ahi + 64 * 72;                      // [64][72] bulk lo
    char*   h1b = (char*)(Alo + 64 * 72);             // 32 KB: [64][256] bf16, XOR-swz
    float*  h2  = (float*)smem_u;                     // [64][132] overlay (post-L2)

    const int t = threadIdx.x;
    const int lane = t & 63;
    const int w = t >> 6;
    const long r0 = (long)blockIdx.x * FE_ROWS;

    // ---- stage bulk rows as two bf16 planes ----
    #pragma unroll
    for (int i = 0; i < 4; ++i) {
        const int gid = t + i * 256;
        const int row = gid >> 4;
        const int c4 = (gid & 15) * 4;
        const float4 v = *reinterpret_cast<const float4*>(&bulk[(r0 + row) * F_IN + c4]);
        const uint h01 = cvtpk(v.x, v.y), h23 = cvtpk(v.z, v.w);
        const float dx = v.x - lo16f(h01);
        const float dy = v.y - hi16f(h01);
        const float dz = v.z - lo16f(h23);
        const float dw = v.w - hi16f(h23);
        const uint l01 = cvtpk(dx, dy), l23 = cvtpk(dz, dw);
        uint2 ph; ph.x = h01; ph.y = h23;
        uint2 pl; pl.x = l01; pl.y = l23;
        *reinterpret_cast<uint2*>(&Ahi[row * 72 + c4]) = ph;
        *reinterpret_cast<uint2*>(&Alo[row * 72 + c4]) = pl;
    }
    __syncthreads();

    // ---- L1 (transposed): A = W1 frags, B = bulk planes ----
    const f32x4 zz = {0.f, 0.f, 0.f, 0.f};
    f32x4 acc1[4][4];
    #pragma unroll
    for (int mtl = 0; mtl < 4; ++mtl)
        #pragma unroll
        for (int ntb = 0; ntb < 4; ++ntb) acc1[mtl][ntb] = zz;

    #pragma unroll
    for (int kt = 0; kt < 2; ++kt) {
        short8 aw[4][2];
        #pragma unroll
        for (int mtl = 0; mtl < 4; ++mtl)
            #pragma unroll
            for (int p = 0; p < 2; ++p) {
                const int f = kt * 16 + (w * 4 + mtl);
                aw[mtl][p] = *reinterpret_cast<const short8*>(&W1p[((f * 2 + p) * 64 + lane) * 8]);
            }
        short8 bh[4], bl[4];
        #pragma unroll
        for (int ntb = 0; ntb < 4; ++ntb) {
            const int row = ntb * 16 + (lane & 15);
            const int k0 = kt * 32 + (lane >> 4) * 8;
            bh[ntb] = *reinterpret_cast<const short8*>(&Ahi[row * 72 + k0]);
            bl[ntb] = *reinterpret_cast<const short8*>(&Alo[row * 72 + k0]);
        }
        #pragma unroll
        for (int mtl = 0; mtl < 4; ++mtl)
            #pragma unroll
            for (int ntb = 0; ntb < 4; ++ntb) {
                acc1[mtl][ntb] = mm(aw[mtl][0], bh[ntb], acc1[mtl][ntb]);
                acc1[mtl][ntb] = mm(aw[mtl][1], bh[ntb], acc1[mtl][ntb]);
                acc1[mtl][ntb] = mm(aw[mtl][0], bl[ntb], acc1[mtl][ntb]);
            }
    }

    // ---- h1 store: single bf16 plane, row-major, 16B XOR swizzle ----
    #pragma unroll
    for (int mtl = 0; mtl < 4; ++mtl) {
        const int hcb = w * 64 + mtl * 16 + (lane >> 4) * 4;
        const float4 bv = *reinterpret_cast<const float4*>(&b1[hcb]);
        #pragma unroll
        for (int ntb = 0; ntb < 4; ++ntb) {
            const int hr = (lane & 15) + ntb * 16;
            const float v0 = fmaxf(acc1[mtl][ntb][0] + bv.x, 0.f);
            const float v1 = fmaxf(acc1[mtl][ntb][1] + bv.y, 0.f);
            const float v2 = fmaxf(acc1[mtl][ntb][2] + bv.z, 0.f);
            const float v3 = fmaxf(acc1[mtl][ntb][3] + bv.w, 0.f);
            uint2 pk; pk.x = cvtpk(v0, v1); pk.y = cvtpk(v2, v3);
            const int byteoff = (hr * 512 + hcb * 2) ^ ((hr & 7) << 4);
            *reinterpret_cast<uint2*>(h1b + byteoff) = pk;
        }
    }
    __syncthreads();

    // ---- L2: h2 = relu(h1 @ W2 + b2), W2 frags prefetched one kt ahead ----
    float b2v[2];
    #pragma unroll
    for (int ntl = 0; ntl < 2; ++ntl) b2v[ntl] = b2[w * 32 + ntl * 16 + (lane & 15)];
    f32x4 acc2[4][2];
    #pragma unroll
    for (int mt = 0; mt < 4; ++mt) { acc2[mt][0] = zz; acc2[mt][1] = zz; }

    short8 bw2c[2][2];
    #pragma unroll
    for (int ntl = 0; ntl < 2; ++ntl)
        #pragma unroll
        for (int p = 0; p < 2; ++p) {
            const int f = w * 2 + ntl;
            bw2c[ntl][p] = *reinterpret_cast<const short8*>(&W2p[((f * 2 + p) * 64 + lane) * 8]);
        }

    #pragma unroll
    for (int kt = 0; kt < 8; ++kt) {
        short8 bw2n[2][2];
        if (kt < 7) {
            #pragma unroll
            for (int ntl = 0; ntl < 2; ++ntl)
                #pragma unroll
                for (int p = 0; p < 2; ++p) {
                    const int f = (kt + 1) * 8 + (w * 2 + ntl);
                    bw2n[ntl][p] = *reinterpret_cast<const short8*>(&W2p[((f * 2 + p) * 64 + lane) * 8]);
                }
        }
        short8 ah[4];
        #pragma unroll
        for (int mt = 0; mt < 4; ++mt) {
            const int row = mt * 16 + (lane & 15);
            const int k0 = kt * 32 + (lane >> 4) * 8;
            ah[mt] = *reinterpret_cast<const short8*>(h1b + ((row * 512 + k0 * 2) ^ ((row & 7) << 4)));
        }
        #pragma unroll
        for (int mt = 0; mt < 4; ++mt)
            #pragma unroll
            for (int ntl = 0; ntl < 2; ++ntl) {
                acc2[mt][ntl] = mm(ah[mt], bw2c[ntl][0], acc2[mt][ntl]);
                acc2[mt][ntl] = mm(ah[mt], bw2c[ntl][1], acc2[mt][ntl]);
            }
        if (kt < 7) {
            #pragma unroll
            for (int ntl = 0; ntl < 2; ++ntl)
                #pragma unroll
                for (int p = 0; p < 2; ++p) bw2c[ntl][p] = bw2n[ntl][p];
        }
    }
    __syncthreads();   // all h1 reads done before h2 overlays LDS

    #pragma unroll
    for (int mt = 0; mt < 4; ++mt)
        #pragma unroll
        for (int ntl = 0; ntl < 2; ++ntl)
            #pragma unroll
            for (int r = 0; r < 4; ++r) {
                const int row = mt * 16 + (lane >> 4) * 4 + r;
                const int col = w * 32 + ntl * 16 + (lane & 15);
                h2[row * 132 + col] = fmaxf(acc2[mt][ntl][r] + b2v[ntl], 0.f);
            }
    __syncthreads();

    // ---- segment sums: 2 half-windows x 128 cols ----
    {
        const int g = t >> 7;
        const int c = t & 127;
        const int base = g * 32;
        const long rb = r0 + base;
        const int prev = (rb == 0) ? -1 : seg[rb - 1];
        const int nxt = (rb + 32 >= R_ROWS) ? -1 : seg[rb + 32];
        int cur = seg[rb];
        float run = 0.f;
        int runstart = 0;
        #pragma unroll 1
        for (int r = 0; r < 32; ++r) {
            const int s = seg[rb + r];
            if (s != cur) {
                if (runstart != 0 || cur != prev) sums[(long)cur * D + c] = run;
                else atomicAdd(&sums[(long)cur * D + c], run);
                cur = s; run = 0.f; runstart = r;
            }
            run += h2[(base + r) * 132 + c];
        }
        if ((runstart != 0 || cur != prev) && cur != nxt) sums[(long)cur * D + c] = run;
        else atomicAdd(&sums[(long)cur * D + c], run);
    }
}

// start[n] = lower_bound(seg, n)
__global__ __launch_bounds__(256) void start_kernel(const int* __restrict__ seg,
                                                    int* __restrict__ start)
{
    const int n = blockIdx.x * 256 + threadIdx.x;
    if (n > NN) return;
    int lo = 0, hi = R_ROWS;
    #pragma unroll 1
    while (lo < hi) {
        const int mid = (lo + hi) >> 1;
        if (seg[mid] < n) lo = mid + 1; else hi = mid;
    }
    start[n] = lo;
}

// node_h (bf16, col-pair packed): uint u of row n holds cols (cA, cA+16),
// cA = (u&15) + (u>>4)*32. lo16 = col cA, hi16 = col cA+16.
__global__ __launch_bounds__(256) void divide_bf(
    const float* __restrict__ sums, const int* __restrict__ start,
    uint* __restrict__ hbf)
{
    const long i = (long)blockIdx.x * 256 + threadIdx.x;
    if (i < (long)NN * 64) {
        const int n = (int)(i >> 6), u = (int)(i & 63);
        const int cA = (u & 15) + (u >> 4) * 32;
        const float inv = 1.f / fmaxf((float)(start[n + 1] - start[n]), 1.f);
        const float vA = sums[(long)n * D + cA] * inv;
        const float vB = sums[(long)n * D + cA + 16] * inv;
        hbf[i] = cvtpk(vA, vB);
    }
}

// ---------------------------------------------------------------------------
// CSR build over edge_dst
// ---------------------------------------------------------------------------
__global__ __launch_bounds__(256) void hist_kernel(const int* __restrict__ edst,
                                                   int* __restrict__ deg)
{
    const int e = blockIdx.x * 256 + threadIdx.x;
    if (e < NE) atomicAdd(&deg[edst[e]], 1);
}

#define SCHUNK 2048
__global__ __launch_bounds__(256) void scan_reduce(const int* __restrict__ deg,
                                                   int* __restrict__ partials, int n)
{
    __shared__ int sdata[256];
    const int b = blockIdx.x, t = threadIdx.x;
    const int base = b * SCHUNK;
    int sum = 0;
    for (int i = t; i < SCHUNK; i += 256) {
        const int idx = base + i;
        sum += (idx < n) ? deg[idx] : 0;
    }
    sdata[t] = sum; __syncthreads();
    for (int s = 128; s > 0; s >>= 1) {
        if (t < s) sdata[t] += sdata[t + s];
        __syncthreads();
    }
    if (t == 0) partials[b] = sdata[0];
}

__global__ void scan_partials(int* partials, int nb)
{
    if (threadIdx.x == 0) {
        int acc = 0;
        for (int i = 0; i < nb; ++i) { const int v = partials[i]; partials[i] = acc; acc += v; }
    }
}

__global__ __launch_bounds__(256) void scan_write(const int* __restrict__ deg,
                                                  const int* __restrict__ partials,
                                                  int* __restrict__ offsets, int n)
{
    __shared__ int sdata[256];
    const int b = blockIdx.x, t = threadIdx.x;
    const int base = b * SCHUNK;
    int loc[8]; int s = 0;
    #pragma unroll
    for (int j = 0; j < 8; ++j) {
        const int idx = base + t * 8 + j;
        const int v = (idx < n) ? deg[idx] : 0;
        loc[j] = s; s += v;
    }
    sdata[t] = s; __syncthreads();
    for (int d = 1; d < 256; d <<= 1) {
        const int v = (t >= d) ? sdata[t - d] : 0;
        __syncthreads();
        sdata[t] += v;
        __syncthreads();
    }
    const int excl = (t == 0) ? 0 : sdata[t - 1];
    const int tbase = partials[b] + excl;
    #pragma unroll
    for (int j = 0; j < 8; ++j) {
        const int idx = base + t * 8 + j;
        if (idx < n) offsets[idx] = tbase + loc[j];
    }
}

__global__ __launch_bounds__(256) void scatter_edges(const int* __restrict__ esrc,
                                                     const int* __restrict__ edst,
                                                     int* __restrict__ cursor,
                                                     int* __restrict__ csr_src)
{
    const int e = blockIdx.x * 256 + threadIdx.x;
    if (e < NE) {
        const int d = edst[e];
        const int p = atomicAdd(&cursor[d], 1);
        csr_src[p] = esrc[e];
    }
}

// ---------------------------------------------------------------------------
// Fused GIN layer, bf16 h: gather (uint/lane = 2 cols) -> packed LDS tile
// -> 64x128x128 split MFMA -> relu -> bf16 out. 5 blocks/CU.
// ---------------------------------------------------------------------------
__global__ __launch_bounds__(256, 5) void gin_fused(
    const uint* __restrict__ hbf, const int* __restrict__ offsets,
    const int* __restrict__ deg, const int* __restrict__ csr,
    const ushort* __restrict__ Wp, const float* __restrict__ bvec,
    uint* __restrict__ houtbf)
{
    __shared__ __align__(16) uint ypk[64 * 128];   // 32 KB
    const int t = threadIdx.x, lane = t & 63, w = t >> 6;
    const int r0 = blockIdx.x * 64;
    const int colA = (lane & 15) + (lane >> 4) * 32;

    #pragma unroll 1
    for (int i = 0; i < 16; ++i) {
        const int n = r0 + w * 16 + i;
        const int row = w * 16 + i;
        float ax = 0.f, ay = 0.f;
        if (n < NN) {
            const uint self = hbf[(long)n * 64 + lane];
            ax = 2.1f * lo16f(self); ay = 2.1f * hi16f(self);
            const int off = offsets[n];
            const int dg = deg[n];
            int j = 0;
            int lead = (4 - (off & 3)) & 3;
            if (lead > dg) lead = dg;
            for (; j < lead; ++j) {
                const uint p = hbf[(long)csr[off + j] * 64 + lane];
                ax += lo16f(p); ay += hi16f(p);
            }
            for (; j + 8 <= dg; j += 8) {
                const int4 i0 = *reinterpret_cast<const int4*>(&csr[off + j]);
                const int4 i1 = *reinterpret_cast<const int4*>(&csr[off + j + 4]);
                const uint p0 = hbf[(long)i0.x * 64 + lane];
                const uint p1 = hbf[(long)i0.y * 64 + lane];
                const uint p2 = hbf[(long)i0.z * 64 + lane];
                const uint p3 = hbf[(long)i0.w * 64 + lane];
                const uint p4 = hbf[(long)i1.x * 64 + lane];
                const uint p5 = hbf[(long)i1.y * 64 + lane];
                const uint p6 = hbf[(long)i1.z * 64 + lane];
                const uint p7 = hbf[(long)i1.w * 64 + lane];
                ax += (lo16f(p0) + lo16f(p1)) + (lo16f(p2) + lo16f(p3))
                    + (lo16f(p4) + lo16f(p5)) + (lo16f(p6) + lo16f(p7));
                ay += (hi16f(p0) + hi16f(p1)) + (hi16f(p2) + hi16f(p3))
                    + (hi16f(p4) + hi16f(p5)) + (hi16f(p6) + hi16f(p7));
            }
            if (j + 4 <= dg) {
                const int4 i0 = *reinterpret_cast<const int4*>(&csr[off + j]);
                const uint p0 = hbf[(long)i0.x * 64 + lane];
                const uint p1 = hbf[(long)i0.y * 64 + lane];
                const uint p2 = hbf[(long)i0.z * 64 + lane];
                const uint p3 = hbf[(long)i0.w * 64 + lane];
                ax += (lo16f(p0) + lo16f(p1)) + (lo16f(p2) + lo16f(p3));
                ay += (hi16f(p0) + hi16f(p1)) + (hi16f(p2) + hi16f(p3));
                j += 4;
            }
            for (; j < dg; ++j) {
                const uint p = hbf[(long)csr[off + j] * 64 + lane];
                ax += lo16f(p); ay += hi16f(p);
            }
        }
        const int swz = row & 7;
        const int cB = colA + 16;
        const int aA = row * 128 + ((((colA >> 2) ^ swz) << 2) | (colA & 3));
        const int aB = row * 128 + ((((cB >> 2) ^ swz) << 2) | (cB & 3));
        ypk[aA] = packsplit(ax);
        ypk[aB] = packsplit(ay);
    }
    __syncthreads();

    const f32x4 zz = {0.f, 0.f, 0.f, 0.f};
    f32x4 acc[4][2];
    #pragma unroll
    for (int mt = 0; mt < 4; ++mt) { acc[mt][0] = zz; acc[mt][1] = zz; }

    #pragma unroll
    for (int kt = 0; kt < 4; ++kt) {
        short8 bw[2][2];
        #pragma unroll
        for (int ntl = 0; ntl < 2; ++ntl)
            #pragma unroll
            for (int p = 0; p < 2; ++p) {
                const int f = kt * 8 + (w * 2 + ntl);
                bw[ntl][p] = *reinterpret_cast<const short8*>(&Wp[((f * 2 + p) * 64 + lane) * 8]);
            }
        #pragma unroll
        for (int mt = 0; mt < 4; ++mt) {
            const int row = mt * 16 + (lane & 15);
            const int g0 = kt * 8 + (lane >> 4) * 2;
            const int swz = lane & 7;
            const uintx4 q0 = *reinterpret_cast<const uintx4*>(&ypk[row * 128 + ((g0 ^ swz) << 2)]);
            const uintx4 q1 = *reinterpret_cast<const uintx4*>(&ypk[row * 128 + (((g0 + 1) ^ swz) << 2)]);
            short8 ah, al;
            unpack_pair(q0, q1, ah, al);
            #pragma unroll
            for (int ntl = 0; ntl < 2; ++ntl) {
                acc[mt][ntl] = mm(ah, bw[ntl][0], acc[mt][ntl]);
                acc[mt][ntl] = mm(ah, bw[ntl][1], acc[mt][ntl]);
                acc[mt][ntl] = mm(al, bw[ntl][0], acc[mt][ntl]);
            }
        }
    }

    const float bv0 = bvec[w * 32 + (lane & 15)];
    const float bv1 = bvec[w * 32 + 16 + (lane & 15)];
    #pragma unroll
    for (int mt = 0; mt < 4; ++mt)
        #pragma unroll
        for (int r = 0; r < 4; ++r) {
            const long grow = r0 + mt * 16 + (lane >> 4) * 4 + r;
            if (grow < NN) {
                const float v0 = fmaxf(acc[mt][0][r] + bv0, 0.f);
                const float v1 = fmaxf(acc[mt][1][r] + bv1, 0.f);
                houtbf[grow * 64 + w * 16 + (lane & 15)] = cvtpk(v0, v1);
            }
        }
}

// ---------------------------------------------------------------------------
// Heads: one block per root (bf16 h input)
// ---------------------------------------------------------------------------
__global__ __launch_bounds__(256) void head_kernel(
    const uint* __restrict__ hbf, const int* __restrict__ root,
    const float* __restrict__ Wa1, const float* __restrict__ ba1,
    const float* __restrict__ Wa2, const float* __restrict__ ba2,
    const float* __restrict__ Wc1, const float* __restrict__ bc1,
    const float* __restrict__ Wc2, const float* __restrict__ bc2,
    float* __restrict__ out_act, float* __restrict__ out_crit)
{
    __shared__ float X[D];
    __shared__ float a1[A1];
    __shared__ float red[256];
    __shared__ float logits[NTOK];
    const int t = threadIdx.x;
    const int bi = blockIdx.x;
    const int n = root[bi];
    if (t < 64) {
        const uint p = hbf[(long)n * 64 + t];
        const int cA = (t & 15) + (t >> 4) * 32;
        X[cA] = lo16f(p);
        X[cA + 16] = hi16f(p);
    }
    __syncthreads();

    float acc = ba1[t];
    #pragma unroll
    for (int k = 0; k < D; k += 4) {
        const float4 xv = *reinterpret_cast<const float4*>(&X[k]);
        acc = fmaf(xv.x, Wa1[(k + 0) * A1 + t], acc);
        acc = fmaf(xv.y, Wa1[(k + 1) * A1 + t], acc);
        acc = fmaf(xv.z, Wa1[(k + 2) * A1 + t], acc);
        acc = fmaf(xv.w, Wa1[(k + 3) * A1 + t], acc);
    }
    a1[t] = fmaxf(acc, 0.f);
    __syncthreads();

    const int j = t & 15, p = t >> 4;
    float pa = 0.f;
    #pragma unroll
    for (int k = 0; k < 16; ++k) {
        const int kk = p * 16 + k;
        pa = fmaf(a1[kk], Wa2[kk * NTOK + j], pa);
    }
    red[j * 16 + p] = pa;
    __syncthreads();
    if (t < NTOK) {
        float s = 0.f;
        #pragma unroll
        for (int p2 = 0; p2 < 16; ++p2) s += red[t * 16 + p2];
        logits[t] = fmaxf(s + ba2[t], 0.f);
    }
    __syncthreads();
    if (t < NTOK) {
        float mx = -1e30f;
        #pragma unroll
        for (int i = 0; i < NTOK; ++i) mx = fmaxf(mx, logits[i]);
        red[t] = expf(logits[t] - mx);
    }
    __syncthreads();
    if (t < NTOK) {
        float s = 0.f;
        #pragma unroll
        for (int i = 0; i < NTOK; ++i) s += red[i];
        out_act[(long)bi * NTOK + t] = red[t] / s;
    }
    __syncthreads();

    float accc = bc1[t];
    #pragma unroll
    for (int k = 0; k < D; k += 4) {
        const float4 xv = *reinterpret_cast<const float4*>(&X[k]);
        accc = fmaf(xv.x, Wc1[(k + 0) * A1 + t], accc);
        accc = fmaf(xv.y, Wc1[(k + 1) * A1 + t], accc);
        accc = fmaf(xv.z, Wc1[(k + 2) * A1 + t], accc);
        accc = fmaf(xv.w, Wc1[(k + 3) * A1 + t], accc);
    }
    red[t] = fmaxf(accc, 0.f) * Wc2[t];
    __syncthreads();
    for (int s = 128; s > 0; s >>= 1) {
        if (t < s) red[t] += red[t + s];
        __syncthreads();
    }
    if (t == 0) out_crit[bi] = red[0] + bc2[0];
}

// ---------------------------------------------------------------------------
extern "C" void kernel_launch(void* const* d_in, const int* in_sizes, int n_in,
                              void* d_out, int out_size, void* d_ws, size_t ws_size,
                              hipStream_t stream)
{
    const float* bulk = (const float*)d_in[0];
    const int*   seg  = (const int*)d_in[1];
    const int*   esrc = (const int*)d_in[2];
    const int*   edst = (const int*)d_in[3];
    const int*   root = (const int*)d_in[4];
    const float* W1   = (const float*)d_in[6];
    const float* b1   = (const float*)d_in[7];
    const float* W2   = (const float*)d_in[8];
    const float* b2   = (const float*)d_in[9];
    const float* ginW = (const float*)d_in[10];
    const float* ginb = (const float*)d_in[11];
    const float* Wa1  = (const float*)d_in[12];
    const float* ba1  = (const float*)d_in[13];
    const float* Wa2  = (const float*)d_in[14];
    const float* ba2  = (const float*)d_in[15];
    const float* Wc1  = (const float*)d_in[16];
    const float* bc1  = (const float*)d_in[17];
    const float* Wc2  = (const float*)d_in[18];
    const float* bc2  = (const float*)d_in[19];

    char* ws = (char*)d_ws;
    ushort* W1p = (ushort*)ws;                     // 64 KB
    ushort* W2p = W1p + 32768;                     // 128 KB
    float* sums    = (float*)(ws + 196608);        // N*D f32
    uint*  hbfA    = (uint*)(sums + (long)NN * D); // N*64 uints (bf16 h)
    uint*  hbfB    = hbfA + (long)NN * 64;         // N*64
    int*   start   = (int*)(hbfB + (long)NN * 64); // N+4 (padded for alignment)
    int*   deg     = start + (NN + 4);             // N
    int*   offsets = deg + NN;                     // N
    int*   cursor  = offsets + NN;                 // N (dead after scatter)
    int*   partials= cursor + NN;                  // 256
    int*   csr     = partials + 256;               // E (16B-aligned)
    ushort* Gp     = (ushort*)cursor;              // 256 KB, reuses cursor

    pack_weights<<<8, 256, 0, stream>>>(W1, H1, 32, W1p);
    pack_weights<<<16, 256, 0, stream>>>(W2, D, 64, W2p);

    hipMemsetAsync(sums, 0, (long)NN * D * sizeof(float), stream);
    hipMemsetAsync(deg, 0, NN * sizeof(int), stream);

    fe_mfma<<<R_ROWS / FE_ROWS, 256, 0, stream>>>(bulk, seg, W1p, b1, W2p, b2, sums);
    start_kernel<<<(NN + 256) / 256, 256, 0, stream>>>(seg, start);
    divide_bf<<<((long)NN * 64 + 255) / 256, 256, 0, stream>>>(sums, start, hbfA);

    hist_kernel<<<(NE + 255) / 256, 256, 0, stream>>>(edst, deg);
    const int nchunks = (NN + SCHUNK - 1) / SCHUNK;
    scan_reduce<<<nchunks, 256, 0, stream>>>(deg, partials, NN);
    scan_partials<<<1, 64, 0, stream>>>(partials, nchunks);
    scan_write<<<nchunks, 256, 0, stream>>>(deg, partials, offsets, NN);
    hipMemcpyAsync(cursor, offsets, NN * sizeof(int), hipMemcpyDeviceToDevice, stream);
    scatter_edges<<<(NE + 255) / 256, 256, 0, stream>>>(esrc, edst, cursor, csr);

    for (int l = 0; l < N_GIN; ++l)
        pack_weights<<<8, 256, 0, stream>>>(ginW + (long)l * D * D, D, 32, Gp + (long)l * 32768);

    uint* hA = hbfA;
    uint* hB = hbfB;
    for (int l = 0; l < N_GIN; ++l) {
        gin_fused<<<(NN + 63) / 64, 256, 0, stream>>>(hA, offsets, deg, csr,
                                                      Gp + (long)l * 32768, ginb + (long)l * D, hB);
        uint* tmp = hA; hA = hB; hB = tmp;
    }

    head_kernel<<<NB, 256, 0, stream>>>(hA, root, Wa1, ba1, Wa2, ba2,
                                        Wc1, bc1, Wc2, bc2,
                                        (float*)d_out, (float*)d_out + (long)NB * NTOK);
}

// Round 6
// 1044.578 us; speedup vs baseline: 5.2624x; 1.0932x over previous
//
#include <hip/hip_runtime.h>
#include <math.h>

#define R_ROWS 1048576
#define F_IN   64
#define H1     256
#define D      128
#define NN     100000
#define NE     1600000
#define NB     4096
#define A1     256
#define NTOK   16
#define N_GIN  4
#define FE_ROWS 64

typedef short short8 __attribute__((ext_vector_type(8)));
typedef float f32x4  __attribute__((ext_vector_type(4)));
typedef unsigned int uintx4 __attribute__((ext_vector_type(4)));

__device__ __forceinline__ ushort f2bf(float x) {
    uint u = __builtin_bit_cast(uint, x);
    u += 0x7FFFu + ((u >> 16) & 1u);
    return (ushort)(u >> 16);
}
__device__ __forceinline__ float bf2f(ushort h) {
    uint u = ((uint)h) << 16;
    return __builtin_bit_cast(float, u);
}
// dst.lo16 = bf16(lo), dst.hi16 = bf16(hi)
__device__ __forceinline__ uint cvtpk(float lo, float hi) {
    uint r;
    asm("v_cvt_pk_bf16_f32 %0, %1, %2" : "=v"(r) : "v"(lo), "v"(hi));
    return r;
}
__device__ __forceinline__ float lo16f(uint p) { return __builtin_bit_cast(float, p << 16); }
__device__ __forceinline__ float hi16f(uint p) { return __builtin_bit_cast(float, p & 0xFFFF0000u); }

// packed split: low16 = bf16(x) hi plane, high16 = bf16 residual
__device__ __forceinline__ uint packsplit(float x) {
    uint h;
    asm("v_cvt_pk_bf16_f32 %0, %1, %1" : "=v"(h) : "v"(x));
    const float d = x - lo16f(h);
    uint l;
    asm("v_cvt_pk_bf16_f32 %0, %1, %1" : "=v"(l) : "v"(d));
    return __builtin_amdgcn_perm(l, h, 0x05040100u);
}
__device__ __forceinline__ f32x4 mm(short8 a, short8 b, f32x4 c) {
    return __builtin_amdgcn_mfma_f32_16x16x32_bf16(a, b, c, 0, 0, 0);
}
__device__ __forceinline__ void unpack_pair(const uintx4 q0, const uintx4 q1,
                                            short8& hi, short8& lo) {
    uintx4 H, L;
    H[0] = __builtin_amdgcn_perm(q0[1], q0[0], 0x05040100u);
    H[1] = __builtin_amdgcn_perm(q0[3], q0[2], 0x05040100u);
    H[2] = __builtin_amdgcn_perm(q1[1], q1[0], 0x05040100u);
    H[3] = __builtin_amdgcn_perm(q1[3], q1[2], 0x05040100u);
    L[0] = __builtin_amdgcn_perm(q0[1], q0[0], 0x07060302u);
    L[1] = __builtin_amdgcn_perm(q0[3], q0[2], 0x07060302u);
    L[2] = __builtin_amdgcn_perm(q1[1], q1[0], 0x07060302u);
    L[3] = __builtin_amdgcn_perm(q1[3], q1[2], 0x07060302u);
    hi = __builtin_bit_cast(short8, H);
    lo = __builtin_bit_cast(short8, L);
}
__device__ __forceinline__ void acc_add(f32x4& L, f32x4& H, const uintx4 p) {
    L[0] += lo16f(p[0]); H[0] += hi16f(p[0]);
    L[1] += lo16f(p[1]); H[1] += hi16f(p[1]);
    L[2] += lo16f(p[2]); H[2] += hi16f(p[2]);
    L[3] += lo16f(p[3]); H[3] += hi16f(p[3]);
}

// ---------------------------------------------------------------------------
// Pack [K][N] f32 weight into MFMA fragment order, bf16 hi/lo planes.
// ---------------------------------------------------------------------------
__global__ __launch_bounds__(256) void pack_weights(
    const float* __restrict__ W, int Ndim, int nfrag, ushort* __restrict__ out)
{
    const int id = blockIdx.x * 256 + threadIdx.x;
    const int f = id >> 6, lane = id & 63;
    if (f >= nfrag) return;
    const int NTn = Ndim >> 4;
    const int kt = f / NTn, nt = f - kt * NTn;
    const int k0 = kt * 32 + (lane >> 4) * 8;
    const int n = nt * 16 + (lane & 15);
    uintx4 Hv, Lv;
    #pragma unroll
    for (int jj = 0; jj < 4; ++jj) {
        const float x0 = W[(k0 + 2 * jj) * Ndim + n];
        const float x1 = W[(k0 + 2 * jj + 1) * Ndim + n];
        const ushort h0 = f2bf(x0), l0 = f2bf(x0 - bf2f(h0));
        const ushort h1u = f2bf(x1), l1 = f2bf(x1 - bf2f(h1u));
        Hv[jj] = (uint)h0 | ((uint)h1u << 16);
        Lv[jj] = (uint)l0 | ((uint)l1 << 16);
    }
    *reinterpret_cast<uintx4*>(&out[((f * 2 + 0) * 64 + lane) * 8]) = Hv;
    *reinterpret_cast<uintx4*>(&out[((f * 2 + 1) * 64 + lane) * 8]) = Lv;
}

// ---------------------------------------------------------------------------
// Fused FE + segment sum. 64 rows/block, 4 waves, 4 blocks/CU (40960 B LDS).
// Bulk staged as single bf16 plane (h1 store rounds to bf16 anyway).
// ---------------------------------------------------------------------------
__global__ __launch_bounds__(256, 4) void fe_mfma(
    const float* __restrict__ bulk, const int* __restrict__ seg,
    const ushort* __restrict__ W1p, const float* __restrict__ b1,
    const ushort* __restrict__ W2p, const float* __restrict__ b2,
    float* __restrict__ sums)
{
    __shared__ __align__(16) uint smem_u[10240];      // 40960 B
    char* Ab  = (char*)smem_u;                        // 8 KB: [64][64] bf16, XOR-swz
    char* h1b = Ab + 8192;                            // 32 KB: [64][256] bf16, XOR-swz
    float* h2 = (float*)smem_u;                       // [64][132] f32 overlay (post-L2)

    const int t = threadIdx.x;
    const int lane = t & 63;
    const int w = t >> 6;
    const long r0 = (long)blockIdx.x * FE_ROWS;

    // ---- stage bulk rows, single bf16 plane, 16B XOR swizzle ----
    #pragma unroll
    for (int i = 0; i < 4; ++i) {
        const int gid = t + i * 256;
        const int row = gid >> 4;
        const int c4 = (gid & 15) * 4;
        const float4 v = *reinterpret_cast<const float4*>(&bulk[(r0 + row) * F_IN + c4]);
        uint2 pk; pk.x = cvtpk(v.x, v.y); pk.y = cvtpk(v.z, v.w);
        const int byteoff = row * 128 + ((c4 * 2) ^ ((row & 7) << 4));
        *reinterpret_cast<uint2*>(Ab + byteoff) = pk;
    }
    __syncthreads();

    // ---- L1 (transposed): A = W1 frags (hi+lo), B = bulk bf16 plane ----
    const f32x4 zz = {0.f, 0.f, 0.f, 0.f};
    f32x4 acc1[4][4];
    #pragma unroll
    for (int mtl = 0; mtl < 4; ++mtl)
        #pragma unroll
        for (int ntb = 0; ntb < 4; ++ntb) acc1[mtl][ntb] = zz;

    #pragma unroll
    for (int kt = 0; kt < 2; ++kt) {
        short8 aw[4][2];
        #pragma unroll
        for (int mtl = 0; mtl < 4; ++mtl)
            #pragma unroll
            for (int p = 0; p < 2; ++p) {
                const int f = kt * 16 + (w * 4 + mtl);
                aw[mtl][p] = *reinterpret_cast<const short8*>(&W1p[((f * 2 + p) * 64 + lane) * 8]);
            }
        short8 bh[4];
        #pragma unroll
        for (int ntb = 0; ntb < 4; ++ntb) {
            const int row = ntb * 16 + (lane & 15);
            const int k0 = kt * 32 + (lane >> 4) * 8;
            bh[ntb] = *reinterpret_cast<const short8*>(Ab + (row * 128 + ((k0 * 2) ^ ((row & 7) << 4))));
        }
        #pragma unroll
        for (int mtl = 0; mtl < 4; ++mtl)
            #pragma unroll
            for (int ntb = 0; ntb < 4; ++ntb) {
                acc1[mtl][ntb] = mm(aw[mtl][0], bh[ntb], acc1[mtl][ntb]);
                acc1[mtl][ntb] = mm(aw[mtl][1], bh[ntb], acc1[mtl][ntb]);
            }
    }

    // ---- h1 store: single bf16 plane, row-major, 16B XOR swizzle ----
    #pragma unroll
    for (int mtl = 0; mtl < 4; ++mtl) {
        const int hcb = w * 64 + mtl * 16 + (lane >> 4) * 4;
        const float4 bv = *reinterpret_cast<const float4*>(&b1[hcb]);
        #pragma unroll
        for (int ntb = 0; ntb < 4; ++ntb) {
            const int hr = (lane & 15) + ntb * 16;
            const float v0 = fmaxf(acc1[mtl][ntb][0] + bv.x, 0.f);
            const float v1 = fmaxf(acc1[mtl][ntb][1] + bv.y, 0.f);
            const float v2 = fmaxf(acc1[mtl][ntb][2] + bv.z, 0.f);
            const float v3 = fmaxf(acc1[mtl][ntb][3] + bv.w, 0.f);
            uint2 pk; pk.x = cvtpk(v0, v1); pk.y = cvtpk(v2, v3);
            const int byteoff = (hr * 512 + hcb * 2) ^ ((hr & 7) << 4);
            *reinterpret_cast<uint2*>(h1b + byteoff) = pk;
        }
    }
    __syncthreads();

    // ---- L2: h2 = relu(h1 @ W2 + b2) ----
    float b2v[2];
    #pragma unroll
    for (int ntl = 0; ntl < 2; ++ntl) b2v[ntl] = b2[w * 32 + ntl * 16 + (lane & 15)];
    f32x4 acc2[4][2];
    #pragma unroll
    for (int mt = 0; mt < 4; ++mt) { acc2[mt][0] = zz; acc2[mt][1] = zz; }

    #pragma unroll
    for (int kt = 0; kt < 8; ++kt) {
        short8 bw2[2][2];
        #pragma unroll
        for (int ntl = 0; ntl < 2; ++ntl)
            #pragma unroll
            for (int p = 0; p < 2; ++p) {
                const int f = kt * 8 + (w * 2 + ntl);
                bw2[ntl][p] = *reinterpret_cast<const short8*>(&W2p[((f * 2 + p) * 64 + lane) * 8]);
            }
        short8 ah[4];
        #pragma unroll
        for (int mt = 0; mt < 4; ++mt) {
            const int row = mt * 16 + (lane & 15);
            const int k0 = kt * 32 + (lane >> 4) * 8;
            ah[mt] = *reinterpret_cast<const short8*>(h1b + ((row * 512 + k0 * 2) ^ ((row & 7) << 4)));
        }
        #pragma unroll
        for (int mt = 0; mt < 4; ++mt)
            #pragma unroll
            for (int ntl = 0; ntl < 2; ++ntl) {
                acc2[mt][ntl] = mm(ah[mt], bw2[ntl][0], acc2[mt][ntl]);
                acc2[mt][ntl] = mm(ah[mt], bw2[ntl][1], acc2[mt][ntl]);
            }
    }
    __syncthreads();   // all h1 reads done before h2 overlays LDS

    #pragma unroll
    for (int mt = 0; mt < 4; ++mt)
        #pragma unroll
        for (int ntl = 0; ntl < 2; ++ntl)
            #pragma unroll
            for (int r = 0; r < 4; ++r) {
                const int row = mt * 16 + (lane >> 4) * 4 + r;
                const int col = w * 32 + ntl * 16 + (lane & 15);
                h2[row * 132 + col] = fmaxf(acc2[mt][ntl][r] + b2v[ntl], 0.f);
            }
    __syncthreads();

    // ---- segment sums: 2 half-windows x 128 cols ----
    {
        const int g = t >> 7;
        const int c = t & 127;
        const int base = g * 32;
        const long rb = r0 + base;
        const int prev = (rb == 0) ? -1 : seg[rb - 1];
        const int nxt = (rb + 32 >= R_ROWS) ? -1 : seg[rb + 32];
        int cur = seg[rb];
        float run = 0.f;
        int runstart = 0;
        #pragma unroll 1
        for (int r = 0; r < 32; ++r) {
            const int s = seg[rb + r];
            if (s != cur) {
                if (runstart != 0 || cur != prev) sums[(long)cur * D + c] = run;
                else atomicAdd(&sums[(long)cur * D + c], run);
                cur = s; run = 0.f; runstart = r;
            }
            run += h2[(base + r) * 132 + c];
        }
        if ((runstart != 0 || cur != prev) && cur != nxt) sums[(long)cur * D + c] = run;
        else atomicAdd(&sums[(long)cur * D + c], run);
    }
}

// start[n] = lower_bound(seg, n)
__global__ __launch_bounds__(256) void start_kernel(const int* __restrict__ seg,
                                                    int* __restrict__ start)
{
    const int n = blockIdx.x * 256 + threadIdx.x;
    if (n > NN) return;
    int lo = 0, hi = R_ROWS;
    #pragma unroll 1
    while (lo < hi) {
        const int mid = (lo + hi) >> 1;
        if (seg[mid] < n) lo = mid + 1; else hi = mid;
    }
    start[n] = lo;
}

// node_h (bf16, col-pair packed): uint u of row n holds cols (cA, cA+16),
// cA = (u&15) + (u>>4)*32. lo16 = col cA, hi16 = col cA+16.
__global__ __launch_bounds__(256) void divide_bf(
    const float* __restrict__ sums, const int* __restrict__ start,
    uint* __restrict__ hbf)
{
    const long i = (long)blockIdx.x * 256 + threadIdx.x;
    if (i < (long)NN * 64) {
        const int n = (int)(i >> 6), u = (int)(i & 63);
        const int cA = (u & 15) + (u >> 4) * 32;
        const float inv = 1.f / fmaxf((float)(start[n + 1] - start[n]), 1.f);
        const float vA = sums[(long)n * D + cA] * inv;
        const float vB = sums[(long)n * D + cA + 16] * inv;
        hbf[i] = cvtpk(vA, vB);
    }
}

// ---------------------------------------------------------------------------
// CSR build over edge_dst
// ---------------------------------------------------------------------------
__global__ __launch_bounds__(256) void hist_kernel(const int* __restrict__ edst,
                                                   int* __restrict__ deg)
{
    const int e = blockIdx.x * 256 + threadIdx.x;
    if (e < NE) atomicAdd(&deg[edst[e]], 1);
}

#define SCHUNK 2048
__global__ __launch_bounds__(256) void scan_reduce(const int* __restrict__ deg,
                                                   int* __restrict__ partials, int n)
{
    __shared__ int sdata[256];
    const int b = blockIdx.x, t = threadIdx.x;
    const int base = b * SCHUNK;
    int sum = 0;
    for (int i = t; i < SCHUNK; i += 256) {
        const int idx = base + i;
        sum += (idx < n) ? deg[idx] : 0;
    }
    sdata[t] = sum; __syncthreads();
    for (int s = 128; s > 0; s >>= 1) {
        if (t < s) sdata[t] += sdata[t + s];
        __syncthreads();
    }
    if (t == 0) partials[b] = sdata[0];
}

__global__ void scan_partials(int* partials, int nb)
{
    if (threadIdx.x == 0) {
        int acc = 0;
        for (int i = 0; i < nb; ++i) { const int v = partials[i]; partials[i] = acc; acc += v; }
    }
}

__global__ __launch_bounds__(256) void scan_write(const int* __restrict__ deg,
                                                  const int* __restrict__ partials,
                                                  int* __restrict__ offsets, int n)
{
    __shared__ int sdata[256];
    const int b = blockIdx.x, t = threadIdx.x;
    const int base = b * SCHUNK;
    int loc[8]; int s = 0;
    #pragma unroll
    for (int j = 0; j < 8; ++j) {
        const int idx = base + t * 8 + j;
        const int v = (idx < n) ? deg[idx] : 0;
        loc[j] = s; s += v;
    }
    sdata[t] = s; __syncthreads();
    for (int d = 1; d < 256; d <<= 1) {
        const int v = (t >= d) ? sdata[t - d] : 0;
        __syncthreads();
        sdata[t] += v;
        __syncthreads();
    }
    const int excl = (t == 0) ? 0 : sdata[t - 1];
    const int tbase = partials[b] + excl;
    #pragma unroll
    for (int j = 0; j < 8; ++j) {
        const int idx = base + t * 8 + j;
        if (idx < n) offsets[idx] = tbase + loc[j];
    }
}

__global__ __launch_bounds__(256) void scatter_edges(const int* __restrict__ esrc,
                                                     const int* __restrict__ edst,
                                                     int* __restrict__ cursor,
                                                     int* __restrict__ csr_src)
{
    const int e = blockIdx.x * 256 + threadIdx.x;
    if (e < NE) {
        const int d = edst[e];
        const int p = atomicAdd(&cursor[d], 1);
        csr_src[p] = esrc[e];
    }
}

// ---------------------------------------------------------------------------
// Fused GIN layer, bf16 h, uint4 gather: 16 lanes/row, 4 rows per wave-load.
// Quarter q of each wave processes edges j ≡ q (mod 4); combine via shfl_xor.
// ---------------------------------------------------------------------------
__global__ __launch_bounds__(256, 5) void gin_fused(
    const uint* __restrict__ hbf, const int* __restrict__ offsets,
    const int* __restrict__ deg, const int* __restrict__ csr,
    const ushort* __restrict__ Wp, const float* __restrict__ bvec,
    uint* __restrict__ houtbf)
{
    __shared__ __align__(16) uint ypk[64 * 128];   // 32 KB
    const int t = threadIdx.x, lane = t & 63, w = t >> 6;
    const int q = lane >> 4, m = lane & 15;
    const int r0 = blockIdx.x * 64;

    #pragma unroll 1
    for (int i = 0; i < 16; ++i) {
        const int n = r0 + w * 16 + i;
        const int row = w * 16 + i;
        f32x4 accL = {0.f, 0.f, 0.f, 0.f};
        f32x4 accH = {0.f, 0.f, 0.f, 0.f};
        if (n < NN) {
            const uintx4 sp = *reinterpret_cast<const uintx4*>(&hbf[(long)n * 64 + 4 * m]);
            const float sc = (q == 0) ? 2.1f : 0.f;
            accL[0] = sc * lo16f(sp[0]); accH[0] = sc * hi16f(sp[0]);
            accL[1] = sc * lo16f(sp[1]); accH[1] = sc * hi16f(sp[1]);
            accL[2] = sc * lo16f(sp[2]); accH[2] = sc * hi16f(sp[2]);
            accL[3] = sc * lo16f(sp[3]); accH[3] = sc * hi16f(sp[3]);
            const int off = offsets[n];
            const int dg = deg[n];
            const int dg4 = dg >> 2;
            int jj = 0;
            for (; jj + 4 <= dg4; jj += 4) {
                const int b = off + 4 * jj + q;
                const int s0 = csr[b], s1 = csr[b + 4], s2 = csr[b + 8], s3 = csr[b + 12];
                const uintx4 p0 = *reinterpret_cast<const uintx4*>(&hbf[(long)s0 * 64 + 4 * m]);
                const uintx4 p1 = *reinterpret_cast<const uintx4*>(&hbf[(long)s1 * 64 + 4 * m]);
                const uintx4 p2 = *reinterpret_cast<const uintx4*>(&hbf[(long)s2 * 64 + 4 * m]);
                const uintx4 p3 = *reinterpret_cast<const uintx4*>(&hbf[(long)s3 * 64 + 4 * m]);
                acc_add(accL, accH, p0);
                acc_add(accL, accH, p1);
                acc_add(accL, accH, p2);
                acc_add(accL, accH, p3);
            }
            for (; jj < dg4; ++jj) {
                const int s = csr[off + 4 * jj + q];
                const uintx4 p = *reinterpret_cast<const uintx4*>(&hbf[(long)s * 64 + 4 * m]);
                acc_add(accL, accH, p);
            }
            for (int j = dg4 * 4; j < dg; ++j) {
                if (q == (j & 3)) {
                    const int s = csr[off + j];
                    const uintx4 p = *reinterpret_cast<const uintx4*>(&hbf[(long)s * 64 + 4 * m]);
                    acc_add(accL, accH, p);
                }
            }
        }
        // combine quarters
        #pragma unroll
        for (int e = 0; e < 4; ++e) {
            accL[e] += __shfl_xor(accL[e], 16);
            accH[e] += __shfl_xor(accH[e], 16);
            accL[e] += __shfl_xor(accL[e], 32);
            accH[e] += __shfl_xor(accH[e], 32);
        }
        // lane (q,m) writes uint u = 4m+q (cols cA, cA+16)
        const float vA = (q == 0) ? accL[0] : (q == 1) ? accL[1] : (q == 2) ? accL[2] : accL[3];
        const float vB = (q == 0) ? accH[0] : (q == 1) ? accH[1] : (q == 2) ? accH[2] : accH[3];
        const int u = 4 * m + q;
        const int cA = (u & 15) + (u >> 4) * 32;
        const int cB = cA + 16;
        const int swz = row & 7;
        const int aA = row * 128 + ((((cA >> 2) ^ swz) << 2) | (cA & 3));
        const int aB = row * 128 + ((((cB >> 2) ^ swz) << 2) | (cB & 3));
        ypk[aA] = packsplit(vA);
        ypk[aB] = packsplit(vB);
    }
    __syncthreads();

    const f32x4 zz = {0.f, 0.f, 0.f, 0.f};
    f32x4 acc[4][2];
    #pragma unroll
    for (int mt = 0; mt < 4; ++mt) { acc[mt][0] = zz; acc[mt][1] = zz; }

    #pragma unroll
    for (int kt = 0; kt < 4; ++kt) {
        short8 bw[2][2];
        #pragma unroll
        for (int ntl = 0; ntl < 2; ++ntl)
            #pragma unroll
            for (int p = 0; p < 2; ++p) {
                const int f = kt * 8 + (w * 2 + ntl);
                bw[ntl][p] = *reinterpret_cast<const short8*>(&Wp[((f * 2 + p) * 64 + lane) * 8]);
            }
        #pragma unroll
        for (int mt = 0; mt < 4; ++mt) {
            const int row = mt * 16 + (lane & 15);
            const int g0 = kt * 8 + (lane >> 4) * 2;
            const int swz = lane & 7;
            const uintx4 q0 = *reinterpret_cast<const uintx4*>(&ypk[row * 128 + ((g0 ^ swz) << 2)]);
            const uintx4 q1 = *reinterpret_cast<const uintx4*>(&ypk[row * 128 + (((g0 + 1) ^ swz) << 2)]);
            short8 ah, al;
            unpack_pair(q0, q1, ah, al);
            #pragma unroll
            for (int ntl = 0; ntl < 2; ++ntl) {
                acc[mt][ntl] = mm(ah, bw[ntl][0], acc[mt][ntl]);
                acc[mt][ntl] = mm(ah, bw[ntl][1], acc[mt][ntl]);
                acc[mt][ntl] = mm(al, bw[ntl][0], acc[mt][ntl]);
            }
        }
    }

    const float bv0 = bvec[w * 32 + (lane & 15)];
    const float bv1 = bvec[w * 32 + 16 + (lane & 15)];
    #pragma unroll
    for (int mt = 0; mt < 4; ++mt)
        #pragma unroll
        for (int r = 0; r < 4; ++r) {
            const long grow = r0 + mt * 16 + (lane >> 4) * 4 + r;
            if (grow < NN) {
                const float v0 = fmaxf(acc[mt][0][r] + bv0, 0.f);
                const float v1 = fmaxf(acc[mt][1][r] + bv1, 0.f);
                houtbf[grow * 64 + w * 16 + (lane & 15)] = cvtpk(v0, v1);
            }
        }
}

// ---------------------------------------------------------------------------
// Heads: one block per root (bf16 h input)
// ---------------------------------------------------------------------------
__global__ __launch_bounds__(256) void head_kernel(
    const uint* __restrict__ hbf, const int* __restrict__ root,
    const float* __restrict__ Wa1, const float* __restrict__ ba1,
    const float* __restrict__ Wa2, const float* __restrict__ ba2,
    const float* __restrict__ Wc1, const float* __restrict__ bc1,
    const float* __restrict__ Wc2, const float* __restrict__ bc2,
    float* __restrict__ out_act, float* __restrict__ out_crit)
{
    __shared__ float X[D];
    __shared__ float a1[A1];
    __shared__ float red[256];
    __shared__ float logits[NTOK];
    const int t = threadIdx.x;
    const int bi = blockIdx.x;
    const int n = root[bi];
    if (t < 64) {
        const uint p = hbf[(long)n * 64 + t];
        const int cA = (t & 15) + (t >> 4) * 32;
        X[cA] = lo16f(p);
        X[cA + 16] = hi16f(p);
    }
    __syncthreads();

    float acc = ba1[t];
    #pragma unroll
    for (int k = 0; k < D; k += 4) {
        const float4 xv = *reinterpret_cast<const float4*>(&X[k]);
        acc = fmaf(xv.x, Wa1[(k + 0) * A1 + t], acc);
        acc = fmaf(xv.y, Wa1[(k + 1) * A1 + t], acc);
        acc = fmaf(xv.z, Wa1[(k + 2) * A1 + t], acc);
        acc = fmaf(xv.w, Wa1[(k + 3) * A1 + t], acc);
    }
    a1[t] = fmaxf(acc, 0.f);
    __syncthreads();

    const int j = t & 15, p = t >> 4;
    float pa = 0.f;
    #pragma unroll
    for (int k = 0; k < 16; ++k) {
        const int kk = p * 16 + k;
        pa = fmaf(a1[kk], Wa2[kk * NTOK + j], pa);
    }
    red[j * 16 + p] = pa;
    __syncthreads();
    if (t < NTOK) {
        float s = 0.f;
        #pragma unroll
        for (int p2 = 0; p2 < 16; ++p2) s += red[t * 16 + p2];
        logits[t] = fmaxf(s + ba2[t], 0.f);
    }
    __syncthreads();
    if (t < NTOK) {
        float mx = -1e30f;
        #pragma unroll
        for (int i = 0; i < NTOK; ++i) mx = fmaxf(mx, logits[i]);
        red[t] = expf(logits[t] - mx);
    }
    __syncthreads();
    if (t < NTOK) {
        float s = 0.f;
        #pragma unroll
        for (int i = 0; i < NTOK; ++i) s += red[i];
        out_act[(long)bi * NTOK + t] = red[t] / s;
    }
    __syncthreads();

    float accc = bc1[t];
    #pragma unroll
    for (int k = 0; k < D; k += 4) {
        const float4 xv = *reinterpret_cast<const float4*>(&X[k]);
        accc = fmaf(xv.x, Wc1[(k + 0) * A1 + t], accc);
        accc = fmaf(xv.y, Wc1[(k + 1) * A1 + t], accc);
        accc = fmaf(xv.z, Wc1[(k + 2) * A1 + t], accc);
        accc = fmaf(xv.w, Wc1[(k + 3) * A1 + t], accc);
    }
    red[t] = fmaxf(accc, 0.f) * Wc2[t];
    __syncthreads();
    for (int s = 128; s > 0; s >>= 1) {
        if (t < s) red[t] += red[t + s];
        __syncthreads();
    }
    if (t == 0) out_crit[bi] = red[0] + bc2[0];
}

// ---------------------------------------------------------------------------
extern "C" void kernel_launch(void* const* d_in, const int* in_sizes, int n_in,
                              void* d_out, int out_size, void* d_ws, size_t ws_size,
                              hipStream_t stream)
{
    const float* bulk = (const float*)d_in[0];
    const int*   seg  = (const int*)d_in[1];
    const int*   esrc = (const int*)d_in[2];
    const int*   edst = (const int*)d_in[3];
    const int*   root = (const int*)d_in[4];
    const float* W1   = (const float*)d_in[6];
    const float* b1   = (const float*)d_in[7];
    const float* W2   = (const float*)d_in[8];
    const float* b2   = (const float*)d_in[9];
    const float* ginW = (const float*)d_in[10];
    const float* ginb = (const float*)d_in[11];
    const float* Wa1  = (const float*)d_in[12];
    const float* ba1  = (const float*)d_in[13];
    const float* Wa2  = (const float*)d_in[14];
    const float* ba2  = (const float*)d_in[15];
    const float* Wc1  = (const float*)d_in[16];
    const float* bc1  = (const float*)d_in[17];
    const float* Wc2  = (const float*)d_in[18];
    const float* bc2  = (const float*)d_in[19];

    char* ws = (char*)d_ws;
    ushort* W1p = (ushort*)ws;                     // 64 KB
    ushort* W2p = W1p + 32768;                     // 128 KB
    float* sums    = (float*)(ws + 196608);        // N*D f32
    uint*  hbfA    = (uint*)(sums + (long)NN * D); // N*64 uints (bf16 h)
    uint*  hbfB    = hbfA + (long)NN * 64;         // N*64
    int*   start   = (int*)(hbfB + (long)NN * 64); // N+4
    int*   deg     = start + (NN + 4);             // N
    int*   offsets = deg + NN;                     // N
    int*   cursor  = offsets + NN;                 // N (dead after scatter)
    int*   partials= cursor + NN;                  // 256
    int*   csr     = partials + 256;               // E
    ushort* Gp     = (ushort*)cursor;              // 256 KB, reuses cursor

    pack_weights<<<8, 256, 0, stream>>>(W1, H1, 32, W1p);
    pack_weights<<<16, 256, 0, stream>>>(W2, D, 64, W2p);

    hipMemsetAsync(sums, 0, (long)NN * D * sizeof(float), stream);
    hipMemsetAsync(deg, 0, NN * sizeof(int), stream);

    fe_mfma<<<R_ROWS / FE_ROWS, 256, 0, stream>>>(bulk, seg, W1p, b1, W2p, b2, sums);
    start_kernel<<<(NN + 256) / 256, 256, 0, stream>>>(seg, start);
    divide_bf<<<((long)NN * 64 + 255) / 256, 256, 0, stream>>>(sums, start, hbfA);

    hist_kernel<<<(NE + 255) / 256, 256, 0, stream>>>(edst, deg);
    const int nchunks = (NN + SCHUNK - 1) / SCHUNK;
    scan_reduce<<<nchunks, 256, 0, stream>>>(deg, partials, NN);
    scan_partials<<<1, 64, 0, stream>>>(partials, nchunks);
    scan_write<<<nchunks, 256, 0, stream>>>(deg, partials, offsets, NN);
    hipMemcpyAsync(cursor, offsets, NN * sizeof(int), hipMemcpyDeviceToDevice, stream);
    scatter_edges<<<(NE + 255) / 256, 256, 0, stream>>>(esrc, edst, cursor, csr);

    for (int l = 0; l < N_GIN; ++l)
        pack_weights<<<8, 256, 0, stream>>>(ginW + (long)l * D * D, D, 32, Gp + (long)l * 32768);

    uint* hA = hbfA;
    uint* hB = hbfB;
    for (int l = 0; l < N_GIN; ++l) {
        gin_fused<<<(NN + 63) / 64, 256, 0, stream>>>(hA, offsets, deg, csr,
                                                      Gp + (long)l * 32768, ginb + (long)l * D, hB);
        uint* tmp = hA; hA = hB; hB = tmp;
    }

    head_kernel<<<NB, 256, 0, stream>>>(hA, root, Wa1, ba1, Wa2, ba2,
                                        Wc1, bc1, Wc2, bc2,
                                        (float*)d_out, (float*)d_out + (long)NB * NTOK);
}

// Round 7
// 848.448 us; speedup vs baseline: 6.4789x; 1.2312x over previous
//
#include <hip/hip_runtime.h>
#include <math.h>

#define R_ROWS 1048576
#define F_IN   64
#define H1     256
#define D      128
#define NN     100000
#define NE     1600000
#define NB     4096
#define A1     256
#define NTOK   16
#define N_GIN  4
#define FE_ROWS 64

typedef short short8 __attribute__((ext_vector_type(8)));
typedef float f32x4  __attribute__((ext_vector_type(4)));
typedef unsigned int uintx4 __attribute__((ext_vector_type(4)));

__device__ __forceinline__ ushort f2bf(float x) {
    uint u = __builtin_bit_cast(uint, x);
    u += 0x7FFFu + ((u >> 16) & 1u);
    return (ushort)(u >> 16);
}
__device__ __forceinline__ float bf2f(ushort h) {
    uint u = ((uint)h) << 16;
    return __builtin_bit_cast(float, u);
}
// dst.lo16 = bf16(lo), dst.hi16 = bf16(hi)
__device__ __forceinline__ uint cvtpk(float lo, float hi) {
    uint r;
    asm("v_cvt_pk_bf16_f32 %0, %1, %2" : "=v"(r) : "v"(lo), "v"(hi));
    return r;
}
__device__ __forceinline__ float lo16f(uint p) { return __builtin_bit_cast(float, p << 16); }
__device__ __forceinline__ float hi16f(uint p) { return __builtin_bit_cast(float, p & 0xFFFF0000u); }

__device__ __forceinline__ f32x4 mm(short8 a, short8 b, f32x4 c) {
    return __builtin_amdgcn_mfma_f32_16x16x32_bf16(a, b, c, 0, 0, 0);
}
__device__ __forceinline__ void acc_add(f32x4& L, f32x4& H, const uintx4 p) {
    L[0] += lo16f(p[0]); H[0] += hi16f(p[0]);
    L[1] += lo16f(p[1]); H[1] += hi16f(p[1]);
    L[2] += lo16f(p[2]); H[2] += hi16f(p[2]);
    L[3] += lo16f(p[3]); H[3] += hi16f(p[3]);
}

// ---------------------------------------------------------------------------
// Pack [K][N] f32 weight into MFMA fragment order, bf16 hi/lo planes.
// ---------------------------------------------------------------------------
__device__ __forceinline__ void pack_one(const float* __restrict__ W, int Ndim,
                                         int f, int lane, ushort* __restrict__ out)
{
    const int NTn = Ndim >> 4;
    const int kt = f / NTn, nt = f - kt * NTn;
    const int k0 = kt * 32 + (lane >> 4) * 8;
    const int n = nt * 16 + (lane & 15);
    uintx4 Hv, Lv;
    #pragma unroll
    for (int jj = 0; jj < 4; ++jj) {
        const float x0 = W[(k0 + 2 * jj) * Ndim + n];
        const float x1 = W[(k0 + 2 * jj + 1) * Ndim + n];
        const ushort h0 = f2bf(x0), l0 = f2bf(x0 - bf2f(h0));
        const ushort h1u = f2bf(x1), l1 = f2bf(x1 - bf2f(h1u));
        Hv[jj] = (uint)h0 | ((uint)h1u << 16);
        Lv[jj] = (uint)l0 | ((uint)l1 << 16);
    }
    *reinterpret_cast<uintx4*>(&out[((f * 2 + 0) * 64 + lane) * 8]) = Hv;
    *reinterpret_cast<uintx4*>(&out[((f * 2 + 1) * 64 + lane) * 8]) = Lv;
}

__global__ __launch_bounds__(256) void pack_weights(
    const float* __restrict__ W, int Ndim, int nfrag, ushort* __restrict__ out)
{
    const int id = blockIdx.x * 256 + threadIdx.x;
    const int f = id >> 6, lane = id & 63;
    if (f >= nfrag) return;
    pack_one(W, Ndim, f, lane, out);
}

// all 4 GIN layers in one launch: grid (8, 4)
__global__ __launch_bounds__(256) void pack_gin(
    const float* __restrict__ ginW, ushort* __restrict__ out)
{
    const int l = blockIdx.y;
    const int id = blockIdx.x * 256 + threadIdx.x;
    const int f = id >> 6, lane = id & 63;
    if (f >= 32) return;
    pack_one(ginW + (long)l * D * D, D, f, lane, out + (long)l * 32768);
}

// ---------------------------------------------------------------------------
// Fused FE + segment sum. 64 rows/block, 4 waves, 4 blocks/CU (40960 B LDS).
// ---------------------------------------------------------------------------
__global__ __launch_bounds__(256, 4) void fe_mfma(
    const float* __restrict__ bulk, const int* __restrict__ seg,
    const ushort* __restrict__ W1p, const float* __restrict__ b1,
    const ushort* __restrict__ W2p, const float* __restrict__ b2,
    float* __restrict__ sums)
{
    __shared__ __align__(16) uint smem_u[10240];      // 40960 B
    char* Ab  = (char*)smem_u;                        // 8 KB: [64][64] bf16, XOR-swz
    char* h1b = Ab + 8192;                            // 32 KB: [64][256] bf16, XOR-swz
    float* h2 = (float*)smem_u;                       // [64][132] f32 overlay (post-L2)

    const int t = threadIdx.x;
    const int lane = t & 63;
    const int w = t >> 6;
    const long r0 = (long)blockIdx.x * FE_ROWS;

    // ---- stage bulk rows, single bf16 plane, 16B XOR swizzle ----
    #pragma unroll
    for (int i = 0; i < 4; ++i) {
        const int gid = t + i * 256;
        const int row = gid >> 4;
        const int c4 = (gid & 15) * 4;
        const float4 v = *reinterpret_cast<const float4*>(&bulk[(r0 + row) * F_IN + c4]);
        uint2 pk; pk.x = cvtpk(v.x, v.y); pk.y = cvtpk(v.z, v.w);
        const int byteoff = row * 128 + ((c4 * 2) ^ ((row & 7) << 4));
        *reinterpret_cast<uint2*>(Ab + byteoff) = pk;
    }
    __syncthreads();

    // ---- L1 (transposed): A = W1 frags (hi+lo), B = bulk bf16 plane ----
    const f32x4 zz = {0.f, 0.f, 0.f, 0.f};
    f32x4 acc1[4][4];
    #pragma unroll
    for (int mtl = 0; mtl < 4; ++mtl)
        #pragma unroll
        for (int ntb = 0; ntb < 4; ++ntb) acc1[mtl][ntb] = zz;

    #pragma unroll
    for (int kt = 0; kt < 2; ++kt) {
        short8 aw[4][2];
        #pragma unroll
        for (int mtl = 0; mtl < 4; ++mtl)
            #pragma unroll
            for (int p = 0; p < 2; ++p) {
                const int f = kt * 16 + (w * 4 + mtl);
                aw[mtl][p] = *reinterpret_cast<const short8*>(&W1p[((f * 2 + p) * 64 + lane) * 8]);
            }
        short8 bh[4];
        #pragma unroll
        for (int ntb = 0; ntb < 4; ++ntb) {
            const int row = ntb * 16 + (lane & 15);
            const int k0 = kt * 32 + (lane >> 4) * 8;
            bh[ntb] = *reinterpret_cast<const short8*>(Ab + (row * 128 + ((k0 * 2) ^ ((row & 7) << 4))));
        }
        #pragma unroll
        for (int mtl = 0; mtl < 4; ++mtl)
            #pragma unroll
            for (int ntb = 0; ntb < 4; ++ntb) {
                acc1[mtl][ntb] = mm(aw[mtl][0], bh[ntb], acc1[mtl][ntb]);
                acc1[mtl][ntb] = mm(aw[mtl][1], bh[ntb], acc1[mtl][ntb]);
            }
    }

    // ---- h1 store: single bf16 plane, row-major, 16B XOR swizzle ----
    #pragma unroll
    for (int mtl = 0; mtl < 4; ++mtl) {
        const int hcb = w * 64 + mtl * 16 + (lane >> 4) * 4;
        const float4 bv = *reinterpret_cast<const float4*>(&b1[hcb]);
        #pragma unroll
        for (int ntb = 0; ntb < 4; ++ntb) {
            const int hr = (lane & 15) + ntb * 16;
            const float v0 = fmaxf(acc1[mtl][ntb][0] + bv.x, 0.f);
            const float v1 = fmaxf(acc1[mtl][ntb][1] + bv.y, 0.f);
            const float v2 = fmaxf(acc1[mtl][ntb][2] + bv.z, 0.f);
            const float v3 = fmaxf(acc1[mtl][ntb][3] + bv.w, 0.f);
            uint2 pk; pk.x = cvtpk(v0, v1); pk.y = cvtpk(v2, v3);
            const int byteoff = (hr * 512 + hcb * 2) ^ ((hr & 7) << 4);
            *reinterpret_cast<uint2*>(h1b + byteoff) = pk;
        }
    }
    __syncthreads();

    // ---- L2: h2 = relu(h1 @ W2 + b2) ----
    float b2v[2];
    #pragma unroll
    for (int ntl = 0; ntl < 2; ++ntl) b2v[ntl] = b2[w * 32 + ntl * 16 + (lane & 15)];
    f32x4 acc2[4][2];
    #pragma unroll
    for (int mt = 0; mt < 4; ++mt) { acc2[mt][0] = zz; acc2[mt][1] = zz; }

    #pragma unroll
    for (int kt = 0; kt < 8; ++kt) {
        short8 bw2[2][2];
        #pragma unroll
        for (int ntl = 0; ntl < 2; ++ntl)
            #pragma unroll
            for (int p = 0; p < 2; ++p) {
                const int f = kt * 8 + (w * 2 + ntl);
                bw2[ntl][p] = *reinterpret_cast<const short8*>(&W2p[((f * 2 + p) * 64 + lane) * 8]);
            }
        short8 ah[4];
        #pragma unroll
        for (int mt = 0; mt < 4; ++mt) {
            const int row = mt * 16 + (lane & 15);
            const int k0 = kt * 32 + (lane >> 4) * 8;
            ah[mt] = *reinterpret_cast<const short8*>(h1b + ((row * 512 + k0 * 2) ^ ((row & 7) << 4)));
        }
        #pragma unroll
        for (int mt = 0; mt < 4; ++mt)
            #pragma unroll
            for (int ntl = 0; ntl < 2; ++ntl) {
                acc2[mt][ntl] = mm(ah[mt], bw2[ntl][0], acc2[mt][ntl]);
                acc2[mt][ntl] = mm(ah[mt], bw2[ntl][1], acc2[mt][ntl]);
            }
    }
    __syncthreads();   // all h1 reads done before h2 overlays LDS

    #pragma unroll
    for (int mt = 0; mt < 4; ++mt)
        #pragma unroll
        for (int ntl = 0; ntl < 2; ++ntl)
            #pragma unroll
            for (int r = 0; r < 4; ++r) {
                const int row = mt * 16 + (lane >> 4) * 4 + r;
                const int col = w * 32 + ntl * 16 + (lane & 15);
                h2[row * 132 + col] = fmaxf(acc2[mt][ntl][r] + b2v[ntl], 0.f);
            }
    __syncthreads();

    // ---- segment sums: 2 half-windows x 128 cols ----
    {
        const int g = t >> 7;
        const int c = t & 127;
        const int base = g * 32;
        const long rb = r0 + base;
        const int prev = (rb == 0) ? -1 : seg[rb - 1];
        const int nxt = (rb + 32 >= R_ROWS) ? -1 : seg[rb + 32];
        int cur = seg[rb];
        float run = 0.f;
        int runstart = 0;
        #pragma unroll 1
        for (int r = 0; r < 32; ++r) {
            const int s = seg[rb + r];
            if (s != cur) {
                if (runstart != 0 || cur != prev) sums[(long)cur * D + c] = run;
                else atomicAdd(&sums[(long)cur * D + c], run);
                cur = s; run = 0.f; runstart = r;
            }
            run += h2[(base + r) * 132 + c];
        }
        if ((runstart != 0 || cur != prev) && cur != nxt) sums[(long)cur * D + c] = run;
        else atomicAdd(&sums[(long)cur * D + c], run);
    }
}

// start[n] = lower_bound(seg, n)
__global__ __launch_bounds__(256) void start_kernel(const int* __restrict__ seg,
                                                    int* __restrict__ start)
{
    const int n = blockIdx.x * 256 + threadIdx.x;
    if (n > NN) return;
    int lo = 0, hi = R_ROWS;
    #pragma unroll 1
    while (lo < hi) {
        const int mid = (lo + hi) >> 1;
        if (seg[mid] < n) lo = mid + 1; else hi = mid;
    }
    start[n] = lo;
}

// node_h (bf16, col-pair packed): uint u of row n holds cols (cA, cA+16),
// cA = (u&15) + (u>>4)*32. lo16 = col cA, hi16 = col cA+16.
__global__ __launch_bounds__(256) void divide_bf(
    const float* __restrict__ sums, const int* __restrict__ start,
    uint* __restrict__ hbf)
{
    const long i = (long)blockIdx.x * 256 + threadIdx.x;
    if (i < (long)NN * 64) {
        const int n = (int)(i >> 6), u = (int)(i & 63);
        const int cA = (u & 15) + (u >> 4) * 32;
        const float inv = 1.f / fmaxf((float)(start[n + 1] - start[n]), 1.f);
        const float vA = sums[(long)n * D + cA] * inv;
        const float vB = sums[(long)n * D + cA + 16] * inv;
        hbf[i] = cvtpk(vA, vB);
    }
}

// ---------------------------------------------------------------------------
// CSR build over edge_dst
// ---------------------------------------------------------------------------
__global__ __launch_bounds__(256) void hist_kernel(const int* __restrict__ edst,
                                                   int* __restrict__ deg)
{
    const int e = blockIdx.x * 256 + threadIdx.x;
    if (e < NE) atomicAdd(&deg[edst[e]], 1);
}

#define SCHUNK 2048
__global__ __launch_bounds__(256) void scan_reduce(const int* __restrict__ deg,
                                                   int* __restrict__ partials, int n)
{
    __shared__ int sdata[256];
    const int b = blockIdx.x, t = threadIdx.x;
    const int base = b * SCHUNK;
    int sum = 0;
    for (int i = t; i < SCHUNK; i += 256) {
        const int idx = base + i;
        sum += (idx < n) ? deg[idx] : 0;
    }
    sdata[t] = sum; __syncthreads();
    for (int s = 128; s > 0; s >>= 1) {
        if (t < s) sdata[t] += sdata[t + s];
        __syncthreads();
    }
    if (t == 0) partials[b] = sdata[0];
}

__global__ void scan_partials(int* partials, int nb)
{
    if (threadIdx.x == 0) {
        int acc = 0;
        for (int i = 0; i < nb; ++i) { const int v = partials[i]; partials[i] = acc; acc += v; }
    }
}

__global__ __launch_bounds__(256) void scan_write(const int* __restrict__ deg,
                                                  const int* __restrict__ partials,
                                                  int* __restrict__ offsets, int n)
{
    __shared__ int sdata[256];
    const int b = blockIdx.x, t = threadIdx.x;
    const int base = b * SCHUNK;
    int loc[8]; int s = 0;
    #pragma unroll
    for (int j = 0; j < 8; ++j) {
        const int idx = base + t * 8 + j;
        const int v = (idx < n) ? deg[idx] : 0;
        loc[j] = s; s += v;
    }
    sdata[t] = s; __syncthreads();
    for (int d = 1; d < 256; d <<= 1) {
        const int v = (t >= d) ? sdata[t - d] : 0;
        __syncthreads();
        sdata[t] += v;
        __syncthreads();
    }
    const int excl = (t == 0) ? 0 : sdata[t - 1];
    const int tbase = partials[b] + excl;
    #pragma unroll
    for (int j = 0; j < 8; ++j) {
        const int idx = base + t * 8 + j;
        if (idx < n) offsets[idx] = tbase + loc[j];
    }
}

__global__ __launch_bounds__(256) void scatter_edges(const int* __restrict__ esrc,
                                                     const int* __restrict__ edst,
                                                     int* __restrict__ cursor,
                                                     int* __restrict__ csr_src)
{
    const int e = blockIdx.x * 256 + threadIdx.x;
    if (e < NE) {
        const int d = edst[e];
        const int p = atomicAdd(&cursor[d], 1);
        csr_src[p] = esrc[e];
    }
}

// ---------------------------------------------------------------------------
// Fused GIN layer, bf16 h: quarter-wave uint4 gather -> single bf16 y plane
// in LDS (XOR-swz) -> direct-b128 A-frags, 2-term MFMA. 8 blocks/CU.
// ---------------------------------------------------------------------------
__global__ __launch_bounds__(256, 8) void gin_fused(
    const uint* __restrict__ hbf, const int* __restrict__ offsets,
    const int* __restrict__ deg, const int* __restrict__ csr,
    const ushort* __restrict__ Wp, const float* __restrict__ bvec,
    uint* __restrict__ houtbf)
{
    __shared__ __align__(16) char ylds[64 * 256];   // 16 KB: [64][128] bf16, XOR-swz
    const int t = threadIdx.x, lane = t & 63, w = t >> 6;
    const int q = lane >> 4, m = lane & 15;
    const int r0 = blockIdx.x * 64;

    #pragma unroll 1
    for (int i = 0; i < 16; ++i) {
        const int n = r0 + w * 16 + i;
        const int row = w * 16 + i;
        f32x4 accL = {0.f, 0.f, 0.f, 0.f};
        f32x4 accH = {0.f, 0.f, 0.f, 0.f};
        if (n < NN) {
            const uintx4 sp = *reinterpret_cast<const uintx4*>(&hbf[(long)n * 64 + 4 * m]);
            const float sc = (q == 0) ? 2.1f : 0.f;
            accL[0] = sc * lo16f(sp[0]); accH[0] = sc * hi16f(sp[0]);
            accL[1] = sc * lo16f(sp[1]); accH[1] = sc * hi16f(sp[1]);
            accL[2] = sc * lo16f(sp[2]); accH[2] = sc * hi16f(sp[2]);
            accL[3] = sc * lo16f(sp[3]); accH[3] = sc * hi16f(sp[3]);
            const int off = offsets[n];
            const int dg = deg[n];
            const int dg4 = dg >> 2;
            int jj = 0;
            for (; jj + 4 <= dg4; jj += 4) {
                const int b = off + 4 * jj + q;
                const int s0 = csr[b], s1 = csr[b + 4], s2 = csr[b + 8], s3 = csr[b + 12];
                const uintx4 p0 = *reinterpret_cast<const uintx4*>(&hbf[(long)s0 * 64 + 4 * m]);
                const uintx4 p1 = *reinterpret_cast<const uintx4*>(&hbf[(long)s1 * 64 + 4 * m]);
                const uintx4 p2 = *reinterpret_cast<const uintx4*>(&hbf[(long)s2 * 64 + 4 * m]);
                const uintx4 p3 = *reinterpret_cast<const uintx4*>(&hbf[(long)s3 * 64 + 4 * m]);
                acc_add(accL, accH, p0);
                acc_add(accL, accH, p1);
                acc_add(accL, accH, p2);
                acc_add(accL, accH, p3);
            }
            for (; jj < dg4; ++jj) {
                const int s = csr[off + 4 * jj + q];
                const uintx4 p = *reinterpret_cast<const uintx4*>(&hbf[(long)s * 64 + 4 * m]);
                acc_add(accL, accH, p);
            }
            for (int j = dg4 * 4; j < dg; ++j) {
                if (q == (j & 3)) {
                    const int s = csr[off + j];
                    const uintx4 p = *reinterpret_cast<const uintx4*>(&hbf[(long)s * 64 + 4 * m]);
                    acc_add(accL, accH, p);
                }
            }
        }
        // combine quarters
        #pragma unroll
        for (int e = 0; e < 4; ++e) {
            accL[e] += __shfl_xor(accL[e], 16);
            accH[e] += __shfl_xor(accH[e], 16);
            accL[e] += __shfl_xor(accL[e], 32);
            accH[e] += __shfl_xor(accH[e], 32);
        }
        // lane (q,m) owns uint u = 4m+q -> cols (cA, cA+16); single bf16 plane
        const float vA = (q == 0) ? accL[0] : (q == 1) ? accL[1] : (q == 2) ? accL[2] : accL[3];
        const float vB = (q == 0) ? accH[0] : (q == 1) ? accH[1] : (q == 2) ? accH[2] : accH[3];
        const int u = 4 * m + q;
        const int cA = (u & 15) + (u >> 4) * 32;
        const int swz = (row & 7) << 4;
        const uint pk = cvtpk(vA, vB);
        *reinterpret_cast<ushort*>(ylds + ((row * 256 + cA * 2) ^ swz)) = (ushort)pk;
        *reinterpret_cast<ushort*>(ylds + ((row * 256 + (cA + 16) * 2) ^ swz)) = (ushort)(pk >> 16);
    }

    // hoist kt=0 W-frags above the barrier (global, independent of LDS)
    short8 bw0[2][2];
    #pragma unroll
    for (int ntl = 0; ntl < 2; ++ntl)
        #pragma unroll
        for (int p = 0; p < 2; ++p) {
            const int f = w * 2 + ntl;
            bw0[ntl][p] = *reinterpret_cast<const short8*>(&Wp[((f * 2 + p) * 64 + lane) * 8]);
        }
    __syncthreads();

    const f32x4 zz = {0.f, 0.f, 0.f, 0.f};
    f32x4 acc[4][2];
    #pragma unroll
    for (int mt = 0; mt < 4; ++mt) { acc[mt][0] = zz; acc[mt][1] = zz; }

    #pragma unroll
    for (int kt = 0; kt < 4; ++kt) {
        short8 bw[2][2];
        if (kt == 0) {
            #pragma unroll
            for (int ntl = 0; ntl < 2; ++ntl)
                #pragma unroll
                for (int p = 0; p < 2; ++p) bw[ntl][p] = bw0[ntl][p];
        } else {
            #pragma unroll
            for (int ntl = 0; ntl < 2; ++ntl)
                #pragma unroll
                for (int p = 0; p < 2; ++p) {
                    const int f = kt * 8 + (w * 2 + ntl);
                    bw[ntl][p] = *reinterpret_cast<const short8*>(&Wp[((f * 2 + p) * 64 + lane) * 8]);
                }
        }
        #pragma unroll
        for (int mt = 0; mt < 4; ++mt) {
            const int row = mt * 16 + m;
            const int k0 = kt * 32 + q * 8;
            const short8 ah = *reinterpret_cast<const short8*>(
                ylds + ((row * 256 + k0 * 2) ^ ((row & 7) << 4)));
            acc[mt][0] = mm(ah, bw[0][0], acc[mt][0]);
            acc[mt][0] = mm(ah, bw[0][1], acc[mt][0]);
            acc[mt][1] = mm(ah, bw[1][0], acc[mt][1]);
            acc[mt][1] = mm(ah, bw[1][1], acc[mt][1]);
        }
    }

    const float bv0 = bvec[w * 32 + m];
    const float bv1 = bvec[w * 32 + 16 + m];
    #pragma unroll
    for (int mt = 0; mt < 4; ++mt)
        #pragma unroll
        for (int r = 0; r < 4; ++r) {
            const long grow = r0 + mt * 16 + q * 4 + r;
            if (grow < NN) {
                const float v0 = fmaxf(acc[mt][0][r] + bv0, 0.f);
                const float v1 = fmaxf(acc[mt][1][r] + bv1, 0.f);
                houtbf[grow * 64 + w * 16 + m] = cvtpk(v0, v1);
            }
        }
}

// ---------------------------------------------------------------------------
// Heads: one block per root (bf16 h input)
// ---------------------------------------------------------------------------
__global__ __launch_bounds__(256) void head_kernel(
    const uint* __restrict__ hbf, const int* __restrict__ root,
    const float* __restrict__ Wa1, const float* __restrict__ ba1,
    const float* __restrict__ Wa2, const float* __restrict__ ba2,
    const float* __restrict__ Wc1, const float* __restrict__ bc1,
    const float* __restrict__ Wc2, const float* __restrict__ bc2,
    float* __restrict__ out_act, float* __restrict__ out_crit)
{
    __shared__ float X[D];
    __shared__ float a1[A1];
    __shared__ float red[256];
    __shared__ float logits[NTOK];
    const int t = threadIdx.x;
    const int bi = blockIdx.x;
    const int n = root[bi];
    if (t < 64) {
        const uint p = hbf[(long)n * 64 + t];
        const int cA = (t & 15) + (t >> 4) * 32;
        X[cA] = lo16f(p);
        X[cA + 16] = hi16f(p);
    }
    __syncthreads();

    float acc = ba1[t];
    #pragma unroll
    for (int k = 0; k < D; k += 4) {
        const float4 xv = *reinterpret_cast<const float4*>(&X[k]);
        acc = fmaf(xv.x, Wa1[(k + 0) * A1 + t], acc);
        acc = fmaf(xv.y, Wa1[(k + 1) * A1 + t], acc);
        acc = fmaf(xv.z, Wa1[(k + 2) * A1 + t], acc);
        acc = fmaf(xv.w, Wa1[(k + 3) * A1 + t], acc);
    }
    a1[t] = fmaxf(acc, 0.f);
    __syncthreads();

    const int j = t & 15, p = t >> 4;
    float pa = 0.f;
    #pragma unroll
    for (int k = 0; k < 16; ++k) {
        const int kk = p * 16 + k;
        pa = fmaf(a1[kk], Wa2[kk * NTOK + j], pa);
    }
    red[j * 16 + p] = pa;
    __syncthreads();
    if (t < NTOK) {
        float s = 0.f;
        #pragma unroll
        for (int p2 = 0; p2 < 16; ++p2) s += red[t * 16 + p2];
        logits[t] = fmaxf(s + ba2[t], 0.f);
    }
    __syncthreads();
    if (t < NTOK) {
        float mx = -1e30f;
        #pragma unroll
        for (int i = 0; i < NTOK; ++i) mx = fmaxf(mx, logits[i]);
        red[t] = expf(logits[t] - mx);
    }
    __syncthreads();
    if (t < NTOK) {
        float s = 0.f;
        #pragma unroll
        for (int i = 0; i < NTOK; ++i) s += red[i];
        out_act[(long)bi * NTOK + t] = red[t] / s;
    }
    __syncthreads();

    float accc = bc1[t];
    #pragma unroll
    for (int k = 0; k < D; k += 4) {
        const float4 xv = *reinterpret_cast<const float4*>(&X[k]);
        accc = fmaf(xv.x, Wc1[(k + 0) * A1 + t], accc);
        accc = fmaf(xv.y, Wc1[(k + 1) * A1 + t], accc);
        accc = fmaf(xv.z, Wc1[(k + 2) * A1 + t], accc);
        accc = fmaf(xv.w, Wc1[(k + 3) * A1 + t], accc);
    }
    red[t] = fmaxf(accc, 0.f) * Wc2[t];
    __syncthreads();
    for (int s = 128; s > 0; s >>= 1) {
        if (t < s) red[t] += red[t + s];
        __syncthreads();
    }
    if (t == 0) out_crit[bi] = red[0] + bc2[0];
}

// ---------------------------------------------------------------------------
extern "C" void kernel_launch(void* const* d_in, const int* in_sizes, int n_in,
                              void* d_out, int out_size, void* d_ws, size_t ws_size,
                              hipStream_t stream)
{
    const float* bulk = (const float*)d_in[0];
    const int*   seg  = (const int*)d_in[1];
    const int*   esrc = (const int*)d_in[2];
    const int*   edst = (const int*)d_in[3];
    const int*   root = (const int*)d_in[4];
    const float* W1   = (const float*)d_in[6];
    const float* b1   = (const float*)d_in[7];
    const float* W2   = (const float*)d_in[8];
    const float* b2   = (const float*)d_in[9];
    const float* ginW = (const float*)d_in[10];
    const float* ginb = (const float*)d_in[11];
    const float* Wa1  = (const float*)d_in[12];
    const float* ba1  = (const float*)d_in[13];
    const float* Wa2  = (const float*)d_in[14];
    const float* ba2  = (const float*)d_in[15];
    const float* Wc1  = (const float*)d_in[16];
    const float* bc1  = (const float*)d_in[17];
    const float* Wc2  = (const float*)d_in[18];
    const float* bc2  = (const float*)d_in[19];

    char* ws = (char*)d_ws;
    ushort* W1p = (ushort*)ws;                     // 64 KB
    ushort* W2p = W1p + 32768;                     // 128 KB
    float* sums    = (float*)(ws + 196608);        // N*D f32
    uint*  hbfA    = (uint*)(sums + (long)NN * D); // N*64 uints (bf16 h)
    uint*  hbfB    = hbfA + (long)NN * 64;         // N*64
    int*   start   = (int*)(hbfB + (long)NN * 64); // N+4
    int*   deg     = start + (NN + 4);             // N
    int*   offsets = deg + NN;                     // N
    int*   cursor  = offsets + NN;                 // N (dead after scatter)
    int*   partials= cursor + NN;                  // 256
    int*   csr     = partials + 256;               // E
    ushort* Gp     = (ushort*)cursor;              // 256 KB, reuses cursor

    pack_weights<<<8, 256, 0, stream>>>(W1, H1, 32, W1p);
    pack_weights<<<16, 256, 0, stream>>>(W2, D, 64, W2p);

    hipMemsetAsync(sums, 0, (long)NN * D * sizeof(float), stream);
    hipMemsetAsync(deg, 0, NN * sizeof(int), stream);

    fe_mfma<<<R_ROWS / FE_ROWS, 256, 0, stream>>>(bulk, seg, W1p, b1, W2p, b2, sums);
    start_kernel<<<(NN + 256) / 256, 256, 0, stream>>>(seg, start);
    divide_bf<<<((long)NN * 64 + 255) / 256, 256, 0, stream>>>(sums, start, hbfA);

    hist_kernel<<<(NE + 255) / 256, 256, 0, stream>>>(edst, deg);
    const int nchunks = (NN + SCHUNK - 1) / SCHUNK;
    scan_reduce<<<nchunks, 256, 0, stream>>>(deg, partials, NN);
    scan_partials<<<1, 64, 0, stream>>>(partials, nchunks);
    scan_write<<<nchunks, 256, 0, stream>>>(deg, partials, offsets, NN);
    hipMemcpyAsync(cursor, offsets, NN * sizeof(int), hipMemcpyDeviceToDevice, stream);
    scatter_edges<<<(NE + 255) / 256, 256, 0, stream>>>(esrc, edst, cursor, csr);

    pack_gin<<<dim3(8, 4), 256, 0, stream>>>(ginW, Gp);

    uint* hA = hbfA;
    uint* hB = hbfB;
    for (int l = 0; l < N_GIN; ++l) {
        gin_fused<<<(NN + 63) / 64, 256, 0, stream>>>(hA, offsets, deg, csr,
                                                      Gp + (long)l * 32768, ginb + (long)l * D, hB);
        uint* tmp = hA; hA = hB; hB = tmp;
    }

    head_kernel<<<NB, 256, 0, stream>>>(hA, root, Wa1, ba1, Wa2, ba2,
                                        Wc1, bc1, Wc2, bc2,
                                        (float*)d_out, (float*)d_out + (long)NB * NTOK);
}

// Round 8
// 845.107 us; speedup vs baseline: 6.5045x; 1.0040x over previous
//
#include <hip/hip_runtime.h>
#include <math.h>

#define R_ROWS 1048576
#define F_IN   64
#define H1     256
#define D      128
#define NN     100000
#define NE     1600000
#define NB     4096
#define A1     256
#define NTOK   16
#define N_GIN  4
#define FE_ROWS 64

typedef short short8 __attribute__((ext_vector_type(8)));
typedef float f32x4  __attribute__((ext_vector_type(4)));
typedef unsigned int uintx4 __attribute__((ext_vector_type(4)));

__device__ __forceinline__ ushort f2bf(float x) {
    uint u = __builtin_bit_cast(uint, x);
    u += 0x7FFFu + ((u >> 16) & 1u);
    return (ushort)(u >> 16);
}
__device__ __forceinline__ float bf2f(ushort h) {
    uint u = ((uint)h) << 16;
    return __builtin_bit_cast(float, u);
}
// dst.lo16 = bf16(lo), dst.hi16 = bf16(hi)
__device__ __forceinline__ uint cvtpk(float lo, float hi) {
    uint r;
    asm("v_cvt_pk_bf16_f32 %0, %1, %2" : "=v"(r) : "v"(lo), "v"(hi));
    return r;
}
__device__ __forceinline__ float lo16f(uint p) { return __builtin_bit_cast(float, p << 16); }
__device__ __forceinline__ float hi16f(uint p) { return __builtin_bit_cast(float, p & 0xFFFF0000u); }

__device__ __forceinline__ f32x4 mm(short8 a, short8 b, f32x4 c) {
    return __builtin_amdgcn_mfma_f32_16x16x32_bf16(a, b, c, 0, 0, 0);
}
__device__ __forceinline__ void acc_add(f32x4& L, f32x4& H, const uintx4 p) {
    L[0] += lo16f(p[0]); H[0] += hi16f(p[0]);
    L[1] += lo16f(p[1]); H[1] += hi16f(p[1]);
    L[2] += lo16f(p[2]); H[2] += hi16f(p[2]);
    L[3] += lo16f(p[3]); H[3] += hi16f(p[3]);
}

// ---------------------------------------------------------------------------
// Pack [K][N] f32 weight into MFMA fragment order, bf16 hi/lo planes.
// ---------------------------------------------------------------------------
__device__ __forceinline__ void pack_one(const float* __restrict__ W, int Ndim,
                                         int f, int lane, ushort* __restrict__ out)
{
    const int NTn = Ndim >> 4;
    const int kt = f / NTn, nt = f - kt * NTn;
    const int k0 = kt * 32 + (lane >> 4) * 8;
    const int n = nt * 16 + (lane & 15);
    uintx4 Hv, Lv;
    #pragma unroll
    for (int jj = 0; jj < 4; ++jj) {
        const float x0 = W[(k0 + 2 * jj) * Ndim + n];
        const float x1 = W[(k0 + 2 * jj + 1) * Ndim + n];
        const ushort h0 = f2bf(x0), l0 = f2bf(x0 - bf2f(h0));
        const ushort h1u = f2bf(x1), l1 = f2bf(x1 - bf2f(h1u));
        Hv[jj] = (uint)h0 | ((uint)h1u << 16);
        Lv[jj] = (uint)l0 | ((uint)l1 << 16);
    }
    *reinterpret_cast<uintx4*>(&out[((f * 2 + 0) * 64 + lane) * 8]) = Hv;
    *reinterpret_cast<uintx4*>(&out[((f * 2 + 1) * 64 + lane) * 8]) = Lv;
}

__global__ __launch_bounds__(256) void pack_weights(
    const float* __restrict__ W, int Ndim, int nfrag, ushort* __restrict__ out)
{
    const int id = blockIdx.x * 256 + threadIdx.x;
    const int f = id >> 6, lane = id & 63;
    if (f >= nfrag) return;
    pack_one(W, Ndim, f, lane, out);
}

// all 4 GIN layers in one launch: grid (8, 4)
__global__ __launch_bounds__(256) void pack_gin(
    const float* __restrict__ ginW, ushort* __restrict__ out)
{
    const int l = blockIdx.y;
    const int id = blockIdx.x * 256 + threadIdx.x;
    const int f = id >> 6, lane = id & 63;
    if (f >= 32) return;
    pack_one(ginW + (long)l * D * D, D, f, lane, out + (long)l * 32768);
}

// ---------------------------------------------------------------------------
// Fused FE + segment sum. 64 rows/block, 4 waves, 4 blocks/CU (40960 B LDS).
// ---------------------------------------------------------------------------
__global__ __launch_bounds__(256, 4) void fe_mfma(
    const float* __restrict__ bulk, const int* __restrict__ seg,
    const ushort* __restrict__ W1p, const float* __restrict__ b1,
    const ushort* __restrict__ W2p, const float* __restrict__ b2,
    float* __restrict__ sums)
{
    __shared__ __align__(16) uint smem_u[10240];      // 40960 B
    char* Ab  = (char*)smem_u;                        // 8 KB: [64][64] bf16, XOR-swz
    char* h1b = Ab + 8192;                            // 32 KB: [64][256] bf16, XOR-swz
    float* h2 = (float*)smem_u;                       // [64][132] f32 overlay (post-L2)

    const int t = threadIdx.x;
    const int lane = t & 63;
    const int w = t >> 6;
    const long r0 = (long)blockIdx.x * FE_ROWS;

    // ---- stage bulk rows, single bf16 plane, 16B XOR swizzle ----
    #pragma unroll
    for (int i = 0; i < 4; ++i) {
        const int gid = t + i * 256;
        const int row = gid >> 4;
        const int c4 = (gid & 15) * 4;
        const float4 v = *reinterpret_cast<const float4*>(&bulk[(r0 + row) * F_IN + c4]);
        uint2 pk; pk.x = cvtpk(v.x, v.y); pk.y = cvtpk(v.z, v.w);
        const int byteoff = row * 128 + ((c4 * 2) ^ ((row & 7) << 4));
        *reinterpret_cast<uint2*>(Ab + byteoff) = pk;
    }
    __syncthreads();

    // ---- L1 (transposed): A = W1 frags (hi+lo), B = bulk bf16 plane ----
    const f32x4 zz = {0.f, 0.f, 0.f, 0.f};
    f32x4 acc1[4][4];
    #pragma unroll
    for (int mtl = 0; mtl < 4; ++mtl)
        #pragma unroll
        for (int ntb = 0; ntb < 4; ++ntb) acc1[mtl][ntb] = zz;

    #pragma unroll
    for (int kt = 0; kt < 2; ++kt) {
        short8 aw[4][2];
        #pragma unroll
        for (int mtl = 0; mtl < 4; ++mtl)
            #pragma unroll
            for (int p = 0; p < 2; ++p) {
                const int f = kt * 16 + (w * 4 + mtl);
                aw[mtl][p] = *reinterpret_cast<const short8*>(&W1p[((f * 2 + p) * 64 + lane) * 8]);
            }
        short8 bh[4];
        #pragma unroll
        for (int ntb = 0; ntb < 4; ++ntb) {
            const int row = ntb * 16 + (lane & 15);
            const int k0 = kt * 32 + (lane >> 4) * 8;
            bh[ntb] = *reinterpret_cast<const short8*>(Ab + (row * 128 + ((k0 * 2) ^ ((row & 7) << 4))));
        }
        #pragma unroll
        for (int mtl = 0; mtl < 4; ++mtl)
            #pragma unroll
            for (int ntb = 0; ntb < 4; ++ntb) {
                acc1[mtl][ntb] = mm(aw[mtl][0], bh[ntb], acc1[mtl][ntb]);
                acc1[mtl][ntb] = mm(aw[mtl][1], bh[ntb], acc1[mtl][ntb]);
            }
    }

    // ---- h1 store: single bf16 plane, row-major, 16B XOR swizzle ----
    #pragma unroll
    for (int mtl = 0; mtl < 4; ++mtl) {
        const int hcb = w * 64 + mtl * 16 + (lane >> 4) * 4;
        const float4 bv = *reinterpret_cast<const float4*>(&b1[hcb]);
        #pragma unroll
        for (int ntb = 0; ntb < 4; ++ntb) {
            const int hr = (lane & 15) + ntb * 16;
            const float v0 = fmaxf(acc1[mtl][ntb][0] + bv.x, 0.f);
            const float v1 = fmaxf(acc1[mtl][ntb][1] + bv.y, 0.f);
            const float v2 = fmaxf(acc1[mtl][ntb][2] + bv.z, 0.f);
            const float v3 = fmaxf(acc1[mtl][ntb][3] + bv.w, 0.f);
            uint2 pk; pk.x = cvtpk(v0, v1); pk.y = cvtpk(v2, v3);
            const int byteoff = (hr * 512 + hcb * 2) ^ ((hr & 7) << 4);
            *reinterpret_cast<uint2*>(h1b + byteoff) = pk;
        }
    }
    __syncthreads();

    // ---- L2: h2 = relu(h1 @ W2 + b2) ----
    float b2v[2];
    #pragma unroll
    for (int ntl = 0; ntl < 2; ++ntl) b2v[ntl] = b2[w * 32 + ntl * 16 + (lane & 15)];
    f32x4 acc2[4][2];
    #pragma unroll
    for (int mt = 0; mt < 4; ++mt) { acc2[mt][0] = zz; acc2[mt][1] = zz; }

    #pragma unroll
    for (int kt = 0; kt < 8; ++kt) {
        short8 bw2[2][2];
        #pragma unroll
        for (int ntl = 0; ntl < 2; ++ntl)
            #pragma unroll
            for (int p = 0; p < 2; ++p) {
                const int f = kt * 8 + (w * 2 + ntl);
                bw2[ntl][p] = *reinterpret_cast<const short8*>(&W2p[((f * 2 + p) * 64 + lane) * 8]);
            }
        short8 ah[4];
        #pragma unroll
        for (int mt = 0; mt < 4; ++mt) {
            const int row = mt * 16 + (lane & 15);
            const int k0 = kt * 32 + (lane >> 4) * 8;
            ah[mt] = *reinterpret_cast<const short8*>(h1b + ((row * 512 + k0 * 2) ^ ((row & 7) << 4)));
        }
        #pragma unroll
        for (int mt = 0; mt < 4; ++mt)
            #pragma unroll
            for (int ntl = 0; ntl < 2; ++ntl) {
                acc2[mt][ntl] = mm(ah[mt], bw2[ntl][0], acc2[mt][ntl]);
                acc2[mt][ntl] = mm(ah[mt], bw2[ntl][1], acc2[mt][ntl]);
            }
    }
    __syncthreads();   // all h1 reads done before h2 overlays LDS

    #pragma unroll
    for (int mt = 0; mt < 4; ++mt)
        #pragma unroll
        for (int ntl = 0; ntl < 2; ++ntl)
            #pragma unroll
            for (int r = 0; r < 4; ++r) {
                const int row = mt * 16 + (lane >> 4) * 4 + r;
                const int col = w * 32 + ntl * 16 + (lane & 15);
                h2[row * 132 + col] = fmaxf(acc2[mt][ntl][r] + b2v[ntl], 0.f);
            }
    __syncthreads();

    // ---- segment sums: 2 half-windows x 128 cols ----
    {
        const int g = t >> 7;
        const int c = t & 127;
        const int base = g * 32;
        const long rb = r0 + base;
        const int prev = (rb == 0) ? -1 : seg[rb - 1];
        const int nxt = (rb + 32 >= R_ROWS) ? -1 : seg[rb + 32];
        int cur = seg[rb];
        float run = 0.f;
        int runstart = 0;
        #pragma unroll 1
        for (int r = 0; r < 32; ++r) {
            const int s = seg[rb + r];
            if (s != cur) {
                if (runstart != 0 || cur != prev) sums[(long)cur * D + c] = run;
                else atomicAdd(&sums[(long)cur * D + c], run);
                cur = s; run = 0.f; runstart = r;
            }
            run += h2[(base + r) * 132 + c];
        }
        if ((runstart != 0 || cur != prev) && cur != nxt) sums[(long)cur * D + c] = run;
        else atomicAdd(&sums[(long)cur * D + c], run);
    }
}

// start[n] = lower_bound(seg, n)
__global__ __launch_bounds__(256) void start_kernel(const int* __restrict__ seg,
                                                    int* __restrict__ start)
{
    const int n = blockIdx.x * 256 + threadIdx.x;
    if (n > NN) return;
    int lo = 0, hi = R_ROWS;
    #pragma unroll 1
    while (lo < hi) {
        const int mid = (lo + hi) >> 1;
        if (seg[mid] < n) lo = mid + 1; else hi = mid;
    }
    start[n] = lo;
}

// node_h (bf16, col-pair packed): uint u of row n holds cols (cA, cA+16),
// cA = (u&15) + (u>>4)*32. lo16 = col cA, hi16 = col cA+16.
__global__ __launch_bounds__(256) void divide_bf(
    const float* __restrict__ sums, const int* __restrict__ start,
    uint* __restrict__ hbf)
{
    const long i = (long)blockIdx.x * 256 + threadIdx.x;
    if (i < (long)NN * 64) {
        const int n = (int)(i >> 6), u = (int)(i & 63);
        const int cA = (u & 15) + (u >> 4) * 32;
        const float inv = 1.f / fmaxf((float)(start[n + 1] - start[n]), 1.f);
        const float vA = sums[(long)n * D + cA] * inv;
        const float vB = sums[(long)n * D + cA + 16] * inv;
        hbf[i] = cvtpk(vA, vB);
    }
}

// ---------------------------------------------------------------------------
// CSR build over edge_dst
// ---------------------------------------------------------------------------
__global__ __launch_bounds__(256) void hist_kernel(const int* __restrict__ edst,
                                                   int* __restrict__ deg)
{
    const int e = blockIdx.x * 256 + threadIdx.x;
    if (e < NE) atomicAdd(&deg[edst[e]], 1);
}

#define SCHUNK 2048
__global__ __launch_bounds__(256) void scan_reduce(const int* __restrict__ deg,
                                                   int* __restrict__ partials, int n)
{
    __shared__ int sdata[256];
    const int b = blockIdx.x, t = threadIdx.x;
    const int base = b * SCHUNK;
    int sum = 0;
    for (int i = t; i < SCHUNK; i += 256) {
        const int idx = base + i;
        sum += (idx < n) ? deg[idx] : 0;
    }
    sdata[t] = sum; __syncthreads();
    for (int s = 128; s > 0; s >>= 1) {
        if (t < s) sdata[t] += sdata[t + s];
        __syncthreads();
    }
    if (t == 0) partials[b] = sdata[0];
}

__global__ void scan_partials(int* partials, int nb)
{
    if (threadIdx.x == 0) {
        int acc = 0;
        for (int i = 0; i < nb; ++i) { const int v = partials[i]; partials[i] = acc; acc += v; }
    }
}

__global__ __launch_bounds__(256) void scan_write(const int* __restrict__ deg,
                                                  const int* __restrict__ partials,
                                                  int* __restrict__ offsets, int n)
{
    __shared__ int sdata[256];
    const int b = blockIdx.x, t = threadIdx.x;
    const int base = b * SCHUNK;
    int loc[8]; int s = 0;
    #pragma unroll
    for (int j = 0; j < 8; ++j) {
        const int idx = base + t * 8 + j;
        const int v = (idx < n) ? deg[idx] : 0;
        loc[j] = s; s += v;
    }
    sdata[t] = s; __syncthreads();
    for (int d = 1; d < 256; d <<= 1) {
        const int v = (t >= d) ? sdata[t - d] : 0;
        __syncthreads();
        sdata[t] += v;
        __syncthreads();
    }
    const int excl = (t == 0) ? 0 : sdata[t - 1];
    const int tbase = partials[b] + excl;
    #pragma unroll
    for (int j = 0; j < 8; ++j) {
        const int idx = base + t * 8 + j;
        if (idx < n) offsets[idx] = tbase + loc[j];
    }
}

__global__ __launch_bounds__(256) void scatter_edges(const int* __restrict__ esrc,
                                                     const int* __restrict__ edst,
                                                     int* __restrict__ cursor,
                                                     int* __restrict__ csr_src)
{
    const int e = blockIdx.x * 256 + threadIdx.x;
    if (e < NE) {
        const int d = edst[e];
        const int p = atomicAdd(&cursor[d], 1);
        csr_src[p] = esrc[e];
    }
}

// ---------------------------------------------------------------------------
// Dependency-cone pruning: nodes needed by the last two GIN layers.
// ---------------------------------------------------------------------------
__global__ __launch_bounds__(256) void mark_kernel(
    const int* __restrict__ root, const int* __restrict__ offsets,
    const int* __restrict__ deg, const int* __restrict__ csr,
    int* __restrict__ mark)
{
    const int b = blockIdx.x * 256 + threadIdx.x;
    if (b < NB) {
        const int n = root[b];
        mark[n] = 1;
        const int off = offsets[n], dg = deg[n];
        for (int j = 0; j < dg; ++j) mark[csr[off + j]] = 1;
    }
}

__global__ __launch_bounds__(256) void compact_kernel(
    const int* __restrict__ mark, int* __restrict__ list, int* __restrict__ cnt)
{
    const int n = blockIdx.x * 256 + threadIdx.x;
    if (n < NN && mark[n]) {
        const int p = atomicAdd(cnt, 1);
        list[p] = n;
    }
}

// ---------------------------------------------------------------------------
// Fused GIN layer, bf16 h. MODE 0: all nodes -> hbf; MODE 1: list-driven ->
// hbf; MODE 2: roots -> compact X buffer (row = root slot).
// ---------------------------------------------------------------------------
template<int MODE>
__global__ __launch_bounds__(256, 8) void gin_kernel(
    const uint* __restrict__ hbf, const int* __restrict__ offsets,
    const int* __restrict__ deg, const int* __restrict__ csr,
    const ushort* __restrict__ Wp, const float* __restrict__ bvec,
    uint* __restrict__ outbuf,
    const int* __restrict__ list, const int* __restrict__ cnt,
    const int* __restrict__ root)
{
    __shared__ __align__(16) char ylds[64 * 256];   // 16 KB: [64][128] bf16, XOR-swz
    __shared__ int nid[64];
    const int t = threadIdx.x, lane = t & 63, w = t >> 6;
    const int q = lane >> 4, m = lane & 15;
    const int r0 = blockIdx.x * 64;
    const int CNT = (MODE == 1) ? cnt[0] : 0;
    if (MODE == 1 && r0 >= CNT) return;

    #pragma unroll 1
    for (int i = 0; i < 16; ++i) {
        const int row = w * 16 + i;
        int n = -1;
        if (MODE == 0) {
            const int nn = r0 + row;
            if (nn < NN) n = nn;
        } else if (MODE == 1) {
            const int idx = r0 + row;
            if (idx < CNT) n = list[idx];
        } else {
            n = root[r0 + row];
        }
        if (MODE == 1 && lane == 0) nid[row] = n;
        f32x4 accL = {0.f, 0.f, 0.f, 0.f};
        f32x4 accH = {0.f, 0.f, 0.f, 0.f};
        if (n >= 0) {
            const uintx4 sp = *reinterpret_cast<const uintx4*>(&hbf[(long)n * 64 + 4 * m]);
            const float sc = (q == 0) ? 2.1f : 0.f;
            accL[0] = sc * lo16f(sp[0]); accH[0] = sc * hi16f(sp[0]);
            accL[1] = sc * lo16f(sp[1]); accH[1] = sc * hi16f(sp[1]);
            accL[2] = sc * lo16f(sp[2]); accH[2] = sc * hi16f(sp[2]);
            accL[3] = sc * lo16f(sp[3]); accH[3] = sc * hi16f(sp[3]);
            const int off = offsets[n];
            const int dg = deg[n];
            const int dg4 = dg >> 2;
            int jj = 0;
            for (; jj + 4 <= dg4; jj += 4) {
                const int b = off + 4 * jj + q;
                const int s0 = csr[b], s1 = csr[b + 4], s2 = csr[b + 8], s3 = csr[b + 12];
                const uintx4 p0 = *reinterpret_cast<const uintx4*>(&hbf[(long)s0 * 64 + 4 * m]);
                const uintx4 p1 = *reinterpret_cast<const uintx4*>(&hbf[(long)s1 * 64 + 4 * m]);
                const uintx4 p2 = *reinterpret_cast<const uintx4*>(&hbf[(long)s2 * 64 + 4 * m]);
                const uintx4 p3 = *reinterpret_cast<const uintx4*>(&hbf[(long)s3 * 64 + 4 * m]);
                acc_add(accL, accH, p0);
                acc_add(accL, accH, p1);
                acc_add(accL, accH, p2);
                acc_add(accL, accH, p3);
            }
            for (; jj < dg4; ++jj) {
                const int s = csr[off + 4 * jj + q];
                const uintx4 p = *reinterpret_cast<const uintx4*>(&hbf[(long)s * 64 + 4 * m]);
                acc_add(accL, accH, p);
            }
            for (int j = dg4 * 4; j < dg; ++j) {
                if (q == (j & 3)) {
                    const int s = csr[off + j];
                    const uintx4 p = *reinterpret_cast<const uintx4*>(&hbf[(long)s * 64 + 4 * m]);
                    acc_add(accL, accH, p);
                }
            }
        }
        // combine quarters
        #pragma unroll
        for (int e = 0; e < 4; ++e) {
            accL[e] += __shfl_xor(accL[e], 16);
            accH[e] += __shfl_xor(accH[e], 16);
            accL[e] += __shfl_xor(accL[e], 32);
            accH[e] += __shfl_xor(accH[e], 32);
        }
        // lane (q,m) owns uint u = 4m+q -> cols (cA, cA+16); single bf16 plane
        const float vA = (q == 0) ? accL[0] : (q == 1) ? accL[1] : (q == 2) ? accL[2] : accL[3];
        const float vB = (q == 0) ? accH[0] : (q == 1) ? accH[1] : (q == 2) ? accH[2] : accH[3];
        const int u = 4 * m + q;
        const int cA = (u & 15) + (u >> 4) * 32;
        const int swz = (row & 7) << 4;
        const uint pk = cvtpk(vA, vB);
        *reinterpret_cast<ushort*>(ylds + ((row * 256 + cA * 2) ^ swz)) = (ushort)pk;
        *reinterpret_cast<ushort*>(ylds + ((row * 256 + (cA + 16) * 2) ^ swz)) = (ushort)(pk >> 16);
    }

    // hoist kt=0 W-frags above the barrier
    short8 bw0[2][2];
    #pragma unroll
    for (int ntl = 0; ntl < 2; ++ntl)
        #pragma unroll
        for (int p = 0; p < 2; ++p) {
            const int f = w * 2 + ntl;
            bw0[ntl][p] = *reinterpret_cast<const short8*>(&Wp[((f * 2 + p) * 64 + lane) * 8]);
        }
    __syncthreads();

    const f32x4 zz = {0.f, 0.f, 0.f, 0.f};
    f32x4 acc[4][2];
    #pragma unroll
    for (int mt = 0; mt < 4; ++mt) { acc[mt][0] = zz; acc[mt][1] = zz; }

    #pragma unroll
    for (int kt = 0; kt < 4; ++kt) {
        short8 bw[2][2];
        if (kt == 0) {
            #pragma unroll
            for (int ntl = 0; ntl < 2; ++ntl)
                #pragma unroll
                for (int p = 0; p < 2; ++p) bw[ntl][p] = bw0[ntl][p];
        } else {
            #pragma unroll
            for (int ntl = 0; ntl < 2; ++ntl)
                #pragma unroll
                for (int p = 0; p < 2; ++p) {
                    const int f = kt * 8 + (w * 2 + ntl);
                    bw[ntl][p] = *reinterpret_cast<const short8*>(&Wp[((f * 2 + p) * 64 + lane) * 8]);
                }
        }
        #pragma unroll
        for (int mt = 0; mt < 4; ++mt) {
            const int row = mt * 16 + m;
            const int k0 = kt * 32 + q * 8;
            const short8 ah = *reinterpret_cast<const short8*>(
                ylds + ((row * 256 + k0 * 2) ^ ((row & 7) << 4)));
            acc[mt][0] = mm(ah, bw[0][0], acc[mt][0]);
            acc[mt][0] = mm(ah, bw[0][1], acc[mt][0]);
            acc[mt][1] = mm(ah, bw[1][0], acc[mt][1]);
            acc[mt][1] = mm(ah, bw[1][1], acc[mt][1]);
        }
    }

    const float bv0 = bvec[w * 32 + m];
    const float bv1 = bvec[w * 32 + 16 + m];
    #pragma unroll
    for (int mt = 0; mt < 4; ++mt)
        #pragma unroll
        for (int r = 0; r < 4; ++r) {
            const int grow_row = mt * 16 + q * 4 + r;
            const float v0 = fmaxf(acc[mt][0][r] + bv0, 0.f);
            const float v1 = fmaxf(acc[mt][1][r] + bv1, 0.f);
            const uint pk = cvtpk(v0, v1);
            if (MODE == 0) {
                const long nout = r0 + grow_row;
                if (nout < NN) outbuf[nout * 64 + w * 16 + m] = pk;
            } else if (MODE == 1) {
                if (r0 + grow_row < CNT) {
                    const long nout = nid[grow_row];
                    outbuf[nout * 64 + w * 16 + m] = pk;
                }
            } else {
                outbuf[(long)(r0 + grow_row) * 64 + w * 16 + m] = pk;
            }
        }
}

// ---------------------------------------------------------------------------
// Heads: one block per root, X from compact bf16 buffer (row = root slot)
// ---------------------------------------------------------------------------
__global__ __launch_bounds__(256) void head_kernel(
    const uint* __restrict__ Xbf, const int* __restrict__ root,
    const float* __restrict__ Wa1, const float* __restrict__ ba1,
    const float* __restrict__ Wa2, const float* __restrict__ ba2,
    const float* __restrict__ Wc1, const float* __restrict__ bc1,
    const float* __restrict__ Wc2, const float* __restrict__ bc2,
    float* __restrict__ out_act, float* __restrict__ out_crit)
{
    __shared__ float X[D];
    __shared__ float a1[A1];
    __shared__ float red[256];
    __shared__ float logits[NTOK];
    const int t = threadIdx.x;
    const int bi = blockIdx.x;
    if (t < 64) {
        const uint p = Xbf[(long)bi * 64 + t];
        const int cA = (t & 15) + (t >> 4) * 32;
        X[cA] = lo16f(p);
        X[cA + 16] = hi16f(p);
    }
    __syncthreads();

    float acc = ba1[t];
    #pragma unroll
    for (int k = 0; k < D; k += 4) {
        const float4 xv = *reinterpret_cast<const float4*>(&X[k]);
        acc = fmaf(xv.x, Wa1[(k + 0) * A1 + t], acc);
        acc = fmaf(xv.y, Wa1[(k + 1) * A1 + t], acc);
        acc = fmaf(xv.z, Wa1[(k + 2) * A1 + t], acc);
        acc = fmaf(xv.w, Wa1[(k + 3) * A1 + t], acc);
    }
    a1[t] = fmaxf(acc, 0.f);
    __syncthreads();

    const int j = t & 15, p = t >> 4;
    float pa = 0.f;
    #pragma unroll
    for (int k = 0; k < 16; ++k) {
        const int kk = p * 16 + k;
        pa = fmaf(a1[kk], Wa2[kk * NTOK + j], pa);
    }
    red[j * 16 + p] = pa;
    __syncthreads();
    if (t < NTOK) {
        float s = 0.f;
        #pragma unroll
        for (int p2 = 0; p2 < 16; ++p2) s += red[t * 16 + p2];
        logits[t] = fmaxf(s + ba2[t], 0.f);
    }
    __syncthreads();
    if (t < NTOK) {
        float mx = -1e30f;
        #pragma unroll
        for (int i = 0; i < NTOK; ++i) mx = fmaxf(mx, logits[i]);
        red[t] = expf(logits[t] - mx);
    }
    __syncthreads();
    if (t < NTOK) {
        float s = 0.f;
        #pragma unroll
        for (int i = 0; i < NTOK; ++i) s += red[i];
        out_act[(long)bi * NTOK + t] = red[t] / s;
    }
    __syncthreads();

    float accc = bc1[t];
    #pragma unroll
    for (int k = 0; k < D; k += 4) {
        const float4 xv = *reinterpret_cast<const float4*>(&X[k]);
        accc = fmaf(xv.x, Wc1[(k + 0) * A1 + t], accc);
        accc = fmaf(xv.y, Wc1[(k + 1) * A1 + t], accc);
        accc = fmaf(xv.z, Wc1[(k + 2) * A1 + t], accc);
        accc = fmaf(xv.w, Wc1[(k + 3) * A1 + t], accc);
    }
    red[t] = fmaxf(accc, 0.f) * Wc2[t];
    __syncthreads();
    for (int s = 128; s > 0; s >>= 1) {
        if (t < s) red[t] += red[t + s];
        __syncthreads();
    }
    if (t == 0) out_crit[bi] = red[0] + bc2[0];
}

// ---------------------------------------------------------------------------
extern "C" void kernel_launch(void* const* d_in, const int* in_sizes, int n_in,
                              void* d_out, int out_size, void* d_ws, size_t ws_size,
                              hipStream_t stream)
{
    const float* bulk = (const float*)d_in[0];
    const int*   seg  = (const int*)d_in[1];
    const int*   esrc = (const int*)d_in[2];
    const int*   edst = (const int*)d_in[3];
    const int*   root = (const int*)d_in[4];
    const float* W1   = (const float*)d_in[6];
    const float* b1   = (const float*)d_in[7];
    const float* W2   = (const float*)d_in[8];
    const float* b2   = (const float*)d_in[9];
    const float* ginW = (const float*)d_in[10];
    const float* ginb = (const float*)d_in[11];
    const float* Wa1  = (const float*)d_in[12];
    const float* ba1  = (const float*)d_in[13];
    const float* Wa2  = (const float*)d_in[14];
    const float* ba2  = (const float*)d_in[15];
    const float* Wc1  = (const float*)d_in[16];
    const float* bc1  = (const float*)d_in[17];
    const float* Wc2  = (const float*)d_in[18];
    const float* bc2  = (const float*)d_in[19];

    char* ws = (char*)d_ws;
    ushort* W1p = (ushort*)ws;                     // 64 KB
    ushort* W2p = W1p + 32768;                     // 128 KB
    float* sums    = (float*)(ws + 196608);        // N*D f32
    uint*  hbfA    = (uint*)(sums + (long)NN * D); // N*64 uints (bf16 h)
    uint*  hbfB    = hbfA + (long)NN * 64;         // N*64
    int*   start   = (int*)(hbfB + (long)NN * 64); // N+4
    int*   deg     = start + (NN + 4);             // N
    int*   offsets = deg + NN;                     // N
    int*   cursor  = offsets + NN;                 // N (dead after scatter)
    int*   partials= cursor + NN;                  // 256
    int*   csr     = partials + 256;               // E
    int*   mark    = csr + NE;                     // N
    int*   list    = mark + NN;                    // N
    int*   cnt     = list + NN;                    // 4
    uint*  Xbf     = (uint*)(cnt + 4);             // NB*64
    ushort* Gp     = (ushort*)cursor;              // 256 KB, reuses cursor

    pack_weights<<<8, 256, 0, stream>>>(W1, H1, 32, W1p);
    pack_weights<<<16, 256, 0, stream>>>(W2, D, 64, W2p);

    hipMemsetAsync(sums, 0, (long)NN * D * sizeof(float), stream);
    hipMemsetAsync(deg, 0, NN * sizeof(int), stream);
    hipMemsetAsync(mark, 0, NN * sizeof(int), stream);
    hipMemsetAsync(cnt, 0, sizeof(int), stream);

    fe_mfma<<<R_ROWS / FE_ROWS, 256, 0, stream>>>(bulk, seg, W1p, b1, W2p, b2, sums);
    start_kernel<<<(NN + 256) / 256, 256, 0, stream>>>(seg, start);
    divide_bf<<<((long)NN * 64 + 255) / 256, 256, 0, stream>>>(sums, start, hbfA);

    hist_kernel<<<(NE + 255) / 256, 256, 0, stream>>>(edst, deg);
    const int nchunks = (NN + SCHUNK - 1) / SCHUNK;
    scan_reduce<<<nchunks, 256, 0, stream>>>(deg, partials, NN);
    scan_partials<<<1, 64, 0, stream>>>(partials, nchunks);
    scan_write<<<nchunks, 256, 0, stream>>>(deg, partials, offsets, NN);
    hipMemcpyAsync(cursor, offsets, NN * sizeof(int), hipMemcpyDeviceToDevice, stream);
    scatter_edges<<<(NE + 255) / 256, 256, 0, stream>>>(esrc, edst, cursor, csr);

    mark_kernel<<<(NB + 255) / 256, 256, 0, stream>>>(root, offsets, deg, csr, mark);
    compact_kernel<<<(NN + 255) / 256, 256, 0, stream>>>(mark, list, cnt);

    pack_gin<<<dim3(8, 4), 256, 0, stream>>>(ginW, Gp);

    const int full_grid = (NN + 63) / 64;
    // layer 0, 1: all nodes
    gin_kernel<0><<<full_grid, 256, 0, stream>>>(hbfA, offsets, deg, csr,
        Gp + 0L * 32768, ginb + 0L * D, hbfB, list, cnt, root);
    gin_kernel<0><<<full_grid, 256, 0, stream>>>(hbfB, offsets, deg, csr,
        Gp + 1L * 32768, ginb + 1L * D, hbfA, list, cnt, root);
    // layer 2: only roots + their in-sources (read by layer 3)
    gin_kernel<1><<<full_grid, 256, 0, stream>>>(hbfA, offsets, deg, csr,
        Gp + 2L * 32768, ginb + 2L * D, hbfB, list, cnt, root);
    // layer 3: only the 4096 roots, into compact X
    gin_kernel<2><<<NB / 64, 256, 0, stream>>>(hbfB, offsets, deg, csr,
        Gp + 3L * 32768, ginb + 3L * D, Xbf, list, cnt, root);

    head_kernel<<<NB, 256, 0, stream>>>(Xbf, root, Wa1, ba1, Wa2, ba2,
                                        Wc1, bc1, Wc2, bc2,
                                        (float*)d_out, (float*)d_out + (long)NB * NTOK);
}

// Round 9
// 775.234 us; speedup vs baseline: 7.0907x; 1.0901x over previous
//
#include <hip/hip_runtime.h>
#include <math.h>

#define R_ROWS 1048576
#define F_IN   64
#define H1     256
#define D      128
#define NN     100000
#define NE     1600000
#define NB     4096
#define A1     256
#define NTOK   16
#define N_GIN  4
#define FE_ROWS 64

typedef short short8 __attribute__((ext_vector_type(8)));
typedef float f32x4  __attribute__((ext_vector_type(4)));
typedef unsigned int uintx4 __attribute__((ext_vector_type(4)));

__device__ __forceinline__ ushort f2bf(float x) {
    uint u = __builtin_bit_cast(uint, x);
    u += 0x7FFFu + ((u >> 16) & 1u);
    return (ushort)(u >> 16);
}
__device__ __forceinline__ float bf2f(ushort h) {
    uint u = ((uint)h) << 16;
    return __builtin_bit_cast(float, u);
}
// dst.lo16 = bf16(lo), dst.hi16 = bf16(hi)
__device__ __forceinline__ uint cvtpk(float lo, float hi) {
    uint r;
    asm("v_cvt_pk_bf16_f32 %0, %1, %2" : "=v"(r) : "v"(lo), "v"(hi));
    return r;
}
__device__ __forceinline__ float lo16f(uint p) { return __builtin_bit_cast(float, p << 16); }
__device__ __forceinline__ float hi16f(uint p) { return __builtin_bit_cast(float, p & 0xFFFF0000u); }

__device__ __forceinline__ f32x4 mm(short8 a, short8 b, f32x4 c) {
    return __builtin_amdgcn_mfma_f32_16x16x32_bf16(a, b, c, 0, 0, 0);
}
__device__ __forceinline__ void acc_add(f32x4& L, f32x4& H, const uintx4 p) {
    L[0] += lo16f(p[0]); H[0] += hi16f(p[0]);
    L[1] += lo16f(p[1]); H[1] += hi16f(p[1]);
    L[2] += lo16f(p[2]); H[2] += hi16f(p[2]);
    L[3] += lo16f(p[3]); H[3] += hi16f(p[3]);
}

// ---------------------------------------------------------------------------
// Pack [K][N] f32 weight into MFMA fragment order, bf16 hi/lo planes.
// ---------------------------------------------------------------------------
__device__ __forceinline__ void pack_one(const float* __restrict__ W, int Ndim,
                                         int f, int lane, ushort* __restrict__ out)
{
    const int NTn = Ndim >> 4;
    const int kt = f / NTn, nt = f - kt * NTn;
    const int k0 = kt * 32 + (lane >> 4) * 8;
    const int n = nt * 16 + (lane & 15);
    uintx4 Hv, Lv;
    #pragma unroll
    for (int jj = 0; jj < 4; ++jj) {
        const float x0 = W[(k0 + 2 * jj) * Ndim + n];
        const float x1 = W[(k0 + 2 * jj + 1) * Ndim + n];
        const ushort h0 = f2bf(x0), l0 = f2bf(x0 - bf2f(h0));
        const ushort h1u = f2bf(x1), l1 = f2bf(x1 - bf2f(h1u));
        Hv[jj] = (uint)h0 | ((uint)h1u << 16);
        Lv[jj] = (uint)l0 | ((uint)l1 << 16);
    }
    *reinterpret_cast<uintx4*>(&out[((f * 2 + 0) * 64 + lane) * 8]) = Hv;
    *reinterpret_cast<uintx4*>(&out[((f * 2 + 1) * 64 + lane) * 8]) = Lv;
}

// One launch: pack W1 (frag 0-31), W2 (32-95), gin l (96+32l .. 127+32l),
// plus zero deg/mark/cnt in the remaining blocks.
__global__ __launch_bounds__(256) void pack_all(
    const float* __restrict__ W1, const float* __restrict__ W2,
    const float* __restrict__ ginW,
    ushort* __restrict__ W1p, ushort* __restrict__ W2p, ushort* __restrict__ Gp,
    int* __restrict__ deg, int* __restrict__ mark, int* __restrict__ cnt)
{
    const int bid = blockIdx.x;
    if (bid < 56) {
        const int fid = bid * 4 + (threadIdx.x >> 6);
        const int lane = threadIdx.x & 63;
        if (fid < 32) pack_one(W1, H1, fid, lane, W1p);
        else if (fid < 96) pack_one(W2, D, fid - 32, lane, W2p);
        else {
            const int l = (fid - 96) >> 5;
            pack_one(ginW + (long)l * D * D, D, (fid - 96) & 31, lane, Gp + (long)l * 32768);
        }
    } else {
        const int zb = bid - 56;
        const int idx0 = (zb * 256 + threadIdx.x) * 4;
        #pragma unroll
        for (int k = 0; k < 4; ++k) {
            const int idx = idx0 + k;
            if (idx < NN) deg[idx] = 0;
            else if (idx < 2 * NN) mark[idx - NN] = 0;
        }
        if (bid == 56 && threadIdx.x == 0) cnt[0] = 0;
    }
}

// ---------------------------------------------------------------------------
// Fused FE + segment sum. 64 rows/block, 4 waves, 4 blocks/CU (40960 B LDS).
// ---------------------------------------------------------------------------
__global__ __launch_bounds__(256, 4) void fe_mfma(
    const float* __restrict__ bulk, const int* __restrict__ seg,
    const ushort* __restrict__ W1p, const float* __restrict__ b1,
    const ushort* __restrict__ W2p, const float* __restrict__ b2,
    float* __restrict__ sums)
{
    __shared__ __align__(16) uint smem_u[10240];      // 40960 B
    char* Ab  = (char*)smem_u;                        // 8 KB: [64][64] bf16, XOR-swz
    char* h1b = Ab + 8192;                            // 32 KB: [64][256] bf16, XOR-swz
    float* h2 = (float*)smem_u;                       // [64][132] f32 overlay (post-L2)

    const int t = threadIdx.x;
    const int lane = t & 63;
    const int w = t >> 6;
    const long r0 = (long)blockIdx.x * FE_ROWS;

    // ---- stage bulk rows, single bf16 plane, 16B XOR swizzle ----
    #pragma unroll
    for (int i = 0; i < 4; ++i) {
        const int gid = t + i * 256;
        const int row = gid >> 4;
        const int c4 = (gid & 15) * 4;
        const float4 v = *reinterpret_cast<const float4*>(&bulk[(r0 + row) * F_IN + c4]);
        uint2 pk; pk.x = cvtpk(v.x, v.y); pk.y = cvtpk(v.z, v.w);
        const int byteoff = row * 128 + ((c4 * 2) ^ ((row & 7) << 4));
        *reinterpret_cast<uint2*>(Ab + byteoff) = pk;
    }
    __syncthreads();

    // ---- L1 (transposed): A = W1 frags (hi+lo), B = bulk bf16 plane ----
    const f32x4 zz = {0.f, 0.f, 0.f, 0.f};
    f32x4 acc1[4][4];
    #pragma unroll
    for (int mtl = 0; mtl < 4; ++mtl)
        #pragma unroll
        for (int ntb = 0; ntb < 4; ++ntb) acc1[mtl][ntb] = zz;

    #pragma unroll
    for (int kt = 0; kt < 2; ++kt) {
        short8 aw[4][2];
        #pragma unroll
        for (int mtl = 0; mtl < 4; ++mtl)
            #pragma unroll
            for (int p = 0; p < 2; ++p) {
                const int f = kt * 16 + (w * 4 + mtl);
                aw[mtl][p] = *reinterpret_cast<const short8*>(&W1p[((f * 2 + p) * 64 + lane) * 8]);
            }
        short8 bh[4];
        #pragma unroll
        for (int ntb = 0; ntb < 4; ++ntb) {
            const int row = ntb * 16 + (lane & 15);
            const int k0 = kt * 32 + (lane >> 4) * 8;
            bh[ntb] = *reinterpret_cast<const short8*>(Ab + (row * 128 + ((k0 * 2) ^ ((row & 7) << 4))));
        }
        #pragma unroll
        for (int mtl = 0; mtl < 4; ++mtl)
            #pragma unroll
            for (int ntb = 0; ntb < 4; ++ntb) {
                acc1[mtl][ntb] = mm(aw[mtl][0], bh[ntb], acc1[mtl][ntb]);
                acc1[mtl][ntb] = mm(aw[mtl][1], bh[ntb], acc1[mtl][ntb]);
            }
    }

    // ---- h1 store: single bf16 plane, row-major, 16B XOR swizzle ----
    #pragma unroll
    for (int mtl = 0; mtl < 4; ++mtl) {
        const int hcb = w * 64 + mtl * 16 + (lane >> 4) * 4;
        const float4 bv = *reinterpret_cast<const float4*>(&b1[hcb]);
        #pragma unroll
        for (int ntb = 0; ntb < 4; ++ntb) {
            const int hr = (lane & 15) + ntb * 16;
            const float v0 = fmaxf(acc1[mtl][ntb][0] + bv.x, 0.f);
            const float v1 = fmaxf(acc1[mtl][ntb][1] + bv.y, 0.f);
            const float v2 = fmaxf(acc1[mtl][ntb][2] + bv.z, 0.f);
            const float v3 = fmaxf(acc1[mtl][ntb][3] + bv.w, 0.f);
            uint2 pk; pk.x = cvtpk(v0, v1); pk.y = cvtpk(v2, v3);
            const int byteoff = (hr * 512 + hcb * 2) ^ ((hr & 7) << 4);
            *reinterpret_cast<uint2*>(h1b + byteoff) = pk;
        }
    }
    __syncthreads();

    // ---- L2: h2 = relu(h1 @ W2 + b2) ----
    float b2v[2];
    #pragma unroll
    for (int ntl = 0; ntl < 2; ++ntl) b2v[ntl] = b2[w * 32 + ntl * 16 + (lane & 15)];
    f32x4 acc2[4][2];
    #pragma unroll
    for (int mt = 0; mt < 4; ++mt) { acc2[mt][0] = zz; acc2[mt][1] = zz; }

    #pragma unroll
    for (int kt = 0; kt < 8; ++kt) {
        short8 bw2[2][2];
        #pragma unroll
        for (int ntl = 0; ntl < 2; ++ntl)
            #pragma unroll
            for (int p = 0; p < 2; ++p) {
                const int f = kt * 8 + (w * 2 + ntl);
                bw2[ntl][p] = *reinterpret_cast<const short8*>(&W2p[((f * 2 + p) * 64 + lane) * 8]);
            }
        short8 ah[4];
        #pragma unroll
        for (int mt = 0; mt < 4; ++mt) {
            const int row = mt * 16 + (lane & 15);
            const int k0 = kt * 32 + (lane >> 4) * 8;
            ah[mt] = *reinterpret_cast<const short8*>(h1b + ((row * 512 + k0 * 2) ^ ((row & 7) << 4)));
        }
        #pragma unroll
        for (int mt = 0; mt < 4; ++mt)
            #pragma unroll
            for (int ntl = 0; ntl < 2; ++ntl) {
                acc2[mt][ntl] = mm(ah[mt], bw2[ntl][0], acc2[mt][ntl]);
                acc2[mt][ntl] = mm(ah[mt], bw2[ntl][1], acc2[mt][ntl]);
            }
    }
    __syncthreads();   // all h1 reads done before h2 overlays LDS

    #pragma unroll
    for (int mt = 0; mt < 4; ++mt)
        #pragma unroll
        for (int ntl = 0; ntl < 2; ++ntl)
            #pragma unroll
            for (int r = 0; r < 4; ++r) {
                const int row = mt * 16 + (lane >> 4) * 4 + r;
                const int col = w * 32 + ntl * 16 + (lane & 15);
                h2[row * 132 + col] = fmaxf(acc2[mt][ntl][r] + b2v[ntl], 0.f);
            }
    __syncthreads();

    // ---- segment sums: 2 half-windows x 128 cols ----
    {
        const int g = t >> 7;
        const int c = t & 127;
        const int base = g * 32;
        const long rb = r0 + base;
        const int prev = (rb == 0) ? -1 : seg[rb - 1];
        const int nxt = (rb + 32 >= R_ROWS) ? -1 : seg[rb + 32];
        int cur = seg[rb];
        float run = 0.f;
        int runstart = 0;
        #pragma unroll 1
        for (int r = 0; r < 32; ++r) {
            const int s = seg[rb + r];
            if (s != cur) {
                if (runstart != 0 || cur != prev) sums[(long)cur * D + c] = run;
                else atomicAdd(&sums[(long)cur * D + c], run);
                cur = s; run = 0.f; runstart = r;
            }
            run += h2[(base + r) * 132 + c];
        }
        if ((runstart != 0 || cur != prev) && cur != nxt) sums[(long)cur * D + c] = run;
        else atomicAdd(&sums[(long)cur * D + c], run);
    }
}

// start[n] = lower_bound(seg, n)
__global__ __launch_bounds__(256) void start_kernel(const int* __restrict__ seg,
                                                    int* __restrict__ start)
{
    const int n = blockIdx.x * 256 + threadIdx.x;
    if (n > NN) return;
    int lo = 0, hi = R_ROWS;
    #pragma unroll 1
    while (lo < hi) {
        const int mid = (lo + hi) >> 1;
        if (seg[mid] < n) lo = mid + 1; else hi = mid;
    }
    start[n] = lo;
}

// node_h (bf16, col-pair packed): uint u of row n holds cols (cA, cA+16),
// cA = (u&15) + (u>>4)*32.
__global__ __launch_bounds__(256) void divide_bf(
    const float* __restrict__ sums, const int* __restrict__ start,
    uint* __restrict__ hbf)
{
    const long i = (long)blockIdx.x * 256 + threadIdx.x;
    if (i < (long)NN * 64) {
        const int n = (int)(i >> 6), u = (int)(i & 63);
        const int cA = (u & 15) + (u >> 4) * 32;
        const float inv = 1.f / fmaxf((float)(start[n + 1] - start[n]), 1.f);
        const float vA = sums[(long)n * D + cA] * inv;
        const float vB = sums[(long)n * D + cA + 16] * inv;
        hbf[i] = cvtpk(vA, vB);
    }
}

// ---------------------------------------------------------------------------
// CSR build over edge_dst
// ---------------------------------------------------------------------------
__global__ __launch_bounds__(256) void hist_kernel(const int* __restrict__ edst,
                                                   int* __restrict__ deg)
{
    const int e = blockIdx.x * 256 + threadIdx.x;
    if (e < NE) atomicAdd(&deg[edst[e]], 1);
}

#define SCHUNK 2048
__global__ __launch_bounds__(256) void scan_reduce(const int* __restrict__ deg,
                                                   int* __restrict__ partials, int n)
{
    __shared__ int sdata[256];
    const int b = blockIdx.x, t = threadIdx.x;
    const int base = b * SCHUNK;
    int sum = 0;
    for (int i = t; i < SCHUNK; i += 256) {
        const int idx = base + i;
        sum += (idx < n) ? deg[idx] : 0;
    }
    sdata[t] = sum; __syncthreads();
    for (int s = 128; s > 0; s >>= 1) {
        if (t < s) sdata[t] += sdata[t + s];
        __syncthreads();
    }
    if (t == 0) partials[b] = sdata[0];
}

// scan_write computes its own block-base from partials (<=64 chunks) via
// wave reduce, writes offsets AND cursor (removes scan_partials + memcpy).
__global__ __launch_bounds__(256) void scan_write(const int* __restrict__ deg,
                                                  const int* __restrict__ partials,
                                                  int nchunks,
                                                  int* __restrict__ offsets,
                                                  int* __restrict__ cursor, int n)
{
    __shared__ int sdata[256];
    __shared__ int base_sh;
    const int b = blockIdx.x, t = threadIdx.x;
    if (t < 64) {
        int v = (t < b && t < nchunks) ? partials[t] : 0;
        #pragma unroll
        for (int d2 = 1; d2 < 64; d2 <<= 1) v += __shfl_xor(v, d2);
        if (t == 0) base_sh = v;
    }
    const int base = b * SCHUNK;
    int loc[8]; int s = 0;
    #pragma unroll
    for (int j = 0; j < 8; ++j) {
        const int idx = base + t * 8 + j;
        const int v = (idx < n) ? deg[idx] : 0;
        loc[j] = s; s += v;
    }
    sdata[t] = s; __syncthreads();
    for (int d = 1; d < 256; d <<= 1) {
        const int v = (t >= d) ? sdata[t - d] : 0;
        __syncthreads();
        sdata[t] += v;
        __syncthreads();
    }
    const int excl = (t == 0) ? 0 : sdata[t - 1];
    const int tbase = base_sh + excl;
    #pragma unroll
    for (int j = 0; j < 8; ++j) {
        const int idx = base + t * 8 + j;
        if (idx < n) {
            const int o = tbase + loc[j];
            offsets[idx] = o;
            cursor[idx] = o;
        }
    }
}

__global__ __launch_bounds__(256) void scatter_edges(const int* __restrict__ esrc,
                                                     const int* __restrict__ edst,
                                                     int* __restrict__ cursor,
                                                     int* __restrict__ csr_src)
{
    const int e = blockIdx.x * 256 + threadIdx.x;
    if (e < NE) {
        const int d = edst[e];
        const int p = atomicAdd(&cursor[d], 1);
        csr_src[p] = esrc[e];
    }
}

// ---------------------------------------------------------------------------
// Dependency-cone pruning: nodes needed by the last two GIN layers.
// ---------------------------------------------------------------------------
__global__ __launch_bounds__(256) void mark_kernel(
    const int* __restrict__ root, const int* __restrict__ offsets,
    const int* __restrict__ deg, const int* __restrict__ csr,
    int* __restrict__ mark)
{
    const int b = blockIdx.x * 256 + threadIdx.x;
    if (b < NB) {
        const int n = root[b];
        mark[n] = 1;
        const int off = offsets[n], dg = deg[n];
        for (int j = 0; j < dg; ++j) mark[csr[off + j]] = 1;
    }
}

__global__ __launch_bounds__(256) void compact_kernel(
    const int* __restrict__ mark, int* __restrict__ list, int* __restrict__ cnt)
{
    const int n = blockIdx.x * 256 + threadIdx.x;
    if (n < NN && mark[n]) {
        const int p = atomicAdd(cnt, 1);
        list[p] = n;
    }
}

// ---------------------------------------------------------------------------
// Fused GIN layer, bf16 h. Half-wave per row (2 rows in flight per wave):
// lanes 0-31 own row 2i, 32-63 own row 2i+1; 2-way edge striping per half.
// MODE 0: all nodes; MODE 1: list-driven; MODE 2: roots -> compact X.
// ---------------------------------------------------------------------------
template<int MODE>
__global__ __launch_bounds__(256, 8) void gin_kernel(
    const uint* __restrict__ hbf, const int* __restrict__ offsets,
    const int* __restrict__ deg, const int* __restrict__ csr,
    const ushort* __restrict__ Wp, const float* __restrict__ bvec,
    uint* __restrict__ outbuf,
    const int* __restrict__ list, const int* __restrict__ cnt,
    const int* __restrict__ root)
{
    __shared__ __align__(16) char ylds[64 * 256];   // 16 KB: [64][128] bf16, XOR-swz
    __shared__ int nid[64];
    const int t = threadIdx.x, lane = t & 63, w = t >> 6;
    const int h = lane >> 5;            // half (row parity)
    const int q2 = (lane >> 4) & 1;     // stripe within half
    const int m = lane & 15;
    const int q = lane >> 4;            // MFMA-phase quarter (unchanged)
    const int r0 = blockIdx.x * 64;
    const int CNT = (MODE == 1) ? cnt[0] : 0;
    if (MODE == 1 && r0 >= CNT) return;

    #pragma unroll 1
    for (int i = 0; i < 8; ++i) {
        const int row = w * 16 + i * 2 + h;
        int n = -1;
        if (MODE == 0) {
            const int nn = r0 + row;
            if (nn < NN) n = nn;
        } else if (MODE == 1) {
            const int idx = r0 + row;
            if (idx < CNT) n = list[idx];
        } else {
            n = root[r0 + row];
        }
        if (MODE == 1 && (lane & 31) == 0) nid[row] = n;
        f32x4 accL = {0.f, 0.f, 0.f, 0.f};
        f32x4 accH = {0.f, 0.f, 0.f, 0.f};
        if (n >= 0) {
            const uintx4 sp = *reinterpret_cast<const uintx4*>(&hbf[(long)n * 64 + 4 * m]);
            const float sc = (q2 == 0) ? 2.1f : 0.f;
            accL[0] = sc * lo16f(sp[0]); accH[0] = sc * hi16f(sp[0]);
            accL[1] = sc * lo16f(sp[1]); accH[1] = sc * hi16f(sp[1]);
            accL[2] = sc * lo16f(sp[2]); accH[2] = sc * hi16f(sp[2]);
            accL[3] = sc * lo16f(sp[3]); accH[3] = sc * hi16f(sp[3]);
            const int off = offsets[n];
            const int dg = deg[n];
            const int dg2 = dg >> 1;
            int jj = 0;
            for (; jj + 4 <= dg2; jj += 4) {
                const int b0 = off + 2 * jj + q2;
                const int s0 = csr[b0], s1 = csr[b0 + 2], s2 = csr[b0 + 4], s3 = csr[b0 + 6];
                const uintx4 p0 = *reinterpret_cast<const uintx4*>(&hbf[(long)s0 * 64 + 4 * m]);
                const uintx4 p1 = *reinterpret_cast<const uintx4*>(&hbf[(long)s1 * 64 + 4 * m]);
                const uintx4 p2 = *reinterpret_cast<const uintx4*>(&hbf[(long)s2 * 64 + 4 * m]);
                const uintx4 p3 = *reinterpret_cast<const uintx4*>(&hbf[(long)s3 * 64 + 4 * m]);
                acc_add(accL, accH, p0);
                acc_add(accL, accH, p1);
                acc_add(accL, accH, p2);
                acc_add(accL, accH, p3);
            }
            for (; jj < dg2; ++jj) {
                const int s = csr[off + 2 * jj + q2];
                const uintx4 p = *reinterpret_cast<const uintx4*>(&hbf[(long)s * 64 + 4 * m]);
                acc_add(accL, accH, p);
            }
            if ((dg & 1) && q2 == 0) {
                const int s = csr[off + dg - 1];
                const uintx4 p = *reinterpret_cast<const uintx4*>(&hbf[(long)s * 64 + 4 * m]);
                acc_add(accL, accH, p);
            }
        }
        // combine stripes within the half
        #pragma unroll
        for (int e = 0; e < 4; ++e) {
            accL[e] += __shfl_xor(accL[e], 16);
            accH[e] += __shfl_xor(accH[e], 16);
        }
        // lane (h,q2,m) writes uints u = 4m + 2*q2 + {0,1}
        const int swz = (row & 7) << 4;
        #pragma unroll
        for (int e = 0; e < 2; ++e) {
            const int u = 4 * m + 2 * q2 + e;
            const int cA = (u & 15) + (u >> 4) * 32;
            const uint pk = cvtpk(accL[2 * q2 + e], accH[2 * q2 + e]);
            *reinterpret_cast<ushort*>(ylds + ((row * 256 + cA * 2) ^ swz)) = (ushort)pk;
            *reinterpret_cast<ushort*>(ylds + ((row * 256 + (cA + 16) * 2) ^ swz)) = (ushort)(pk >> 16);
        }
    }

    // hoist kt=0 W-frags above the barrier
    short8 bw0[2][2];
    #pragma unroll
    for (int ntl = 0; ntl < 2; ++ntl)
        #pragma unroll
        for (int p = 0; p < 2; ++p) {
            const int f = w * 2 + ntl;
            bw0[ntl][p] = *reinterpret_cast<const short8*>(&Wp[((f * 2 + p) * 64 + lane) * 8]);
        }
    __syncthreads();

    const f32x4 zz = {0.f, 0.f, 0.f, 0.f};
    f32x4 acc[4][2];
    #pragma unroll
    for (int mt = 0; mt < 4; ++mt) { acc[mt][0] = zz; acc[mt][1] = zz; }

    #pragma unroll
    for (int kt = 0; kt < 4; ++kt) {
        short8 bw[2][2];
        if (kt == 0) {
            #pragma unroll
            for (int ntl = 0; ntl < 2; ++ntl)
                #pragma unroll
                for (int p = 0; p < 2; ++p) bw[ntl][p] = bw0[ntl][p];
        } else {
            #pragma unroll
            for (int ntl = 0; ntl < 2; ++ntl)
                #pragma unroll
                for (int p = 0; p < 2; ++p) {
                    const int f = kt * 8 + (w * 2 + ntl);
                    bw[ntl][p] = *reinterpret_cast<const short8*>(&Wp[((f * 2 + p) * 64 + lane) * 8]);
                }
        }
        #pragma unroll
        for (int mt = 0; mt < 4; ++mt) {
            const int row = mt * 16 + m;
            const int k0 = kt * 32 + q * 8;
            const short8 ah = *reinterpret_cast<const short8*>(
                ylds + ((row * 256 + k0 * 2) ^ ((row & 7) << 4)));
            acc[mt][0] = mm(ah, bw[0][0], acc[mt][0]);
            acc[mt][0] = mm(ah, bw[0][1], acc[mt][0]);
            acc[mt][1] = mm(ah, bw[1][0], acc[mt][1]);
            acc[mt][1] = mm(ah, bw[1][1], acc[mt][1]);
        }
    }

    const float bv0 = bvec[w * 32 + m];
    const float bv1 = bvec[w * 32 + 16 + m];
    #pragma unroll
    for (int mt = 0; mt < 4; ++mt)
        #pragma unroll
        for (int r = 0; r < 4; ++r) {
            const int grow_row = mt * 16 + q * 4 + r;
            const float v0 = fmaxf(acc[mt][0][r] + bv0, 0.f);
            const float v1 = fmaxf(acc[mt][1][r] + bv1, 0.f);
            const uint pk = cvtpk(v0, v1);
            if (MODE == 0) {
                const long nout = r0 + grow_row;
                if (nout < NN) outbuf[nout * 64 + w * 16 + m] = pk;
            } else if (MODE == 1) {
                if (r0 + grow_row < CNT) {
                    const long nout = nid[grow_row];
                    outbuf[nout * 64 + w * 16 + m] = pk;
                }
            } else {
                outbuf[(long)(r0 + grow_row) * 64 + w * 16 + m] = pk;
            }
        }
}

// ---------------------------------------------------------------------------
// Heads: one block per root, X from compact bf16 buffer (row = root slot)
// ---------------------------------------------------------------------------
__global__ __launch_bounds__(256) void head_kernel(
    const uint* __restrict__ Xbf, const int* __restrict__ root,
    const float* __restrict__ Wa1, const float* __restrict__ ba1,
    const float* __restrict__ Wa2, const float* __restrict__ ba2,
    const float* __restrict__ Wc1, const float* __restrict__ bc1,
    const float* __restrict__ Wc2, const float* __restrict__ bc2,
    float* __restrict__ out_act, float* __restrict__ out_crit)
{
    __shared__ float X[D];
    __shared__ float a1[A1];
    __shared__ float red[256];
    __shared__ float logits[NTOK];
    const int t = threadIdx.x;
    const int bi = blockIdx.x;
    if (t < 64) {
        const uint p = Xbf[(long)bi * 64 + t];
        const int cA = (t & 15) + (t >> 4) * 32;
        X[cA] = lo16f(p);
        X[cA + 16] = hi16f(p);
    }
    __syncthreads();

    float acc = ba1[t];
    #pragma unroll
    for (int k = 0; k < D; k += 4) {
        const float4 xv = *reinterpret_cast<const float4*>(&X[k]);
        acc = fmaf(xv.x, Wa1[(k + 0) * A1 + t], acc);
        acc = fmaf(xv.y, Wa1[(k + 1) * A1 + t], acc);
        acc = fmaf(xv.z, Wa1[(k + 2) * A1 + t], acc);
        acc = fmaf(xv.w, Wa1[(k + 3) * A1 + t], acc);
    }
    a1[t] = fmaxf(acc, 0.f);
    __syncthreads();

    const int j = t & 15, p = t >> 4;
    float pa = 0.f;
    #pragma unroll
    for (int k = 0; k < 16; ++k) {
        const int kk = p * 16 + k;
        pa = fmaf(a1[kk], Wa2[kk * NTOK + j], pa);
    }
    red[j * 16 + p] = pa;
    __syncthreads();
    if (t < NTOK) {
        float s = 0.f;
        #pragma unroll
        for (int p2 = 0; p2 < 16; ++p2) s += red[t * 16 + p2];
        logits[t] = fmaxf(s + ba2[t], 0.f);
    }
    __syncthreads();
    if (t < NTOK) {
        float mx = -1e30f;
        #pragma unroll
        for (int i = 0; i < NTOK; ++i) mx = fmaxf(mx, logits[i]);
        red[t] = expf(logits[t] - mx);
    }
    __syncthreads();
    if (t < NTOK) {
        float s = 0.f;
        #pragma unroll
        for (int i = 0; i < NTOK; ++i) s += red[i];
        out_act[(long)bi * NTOK + t] = red[t] / s;
    }
    __syncthreads();

    float accc = bc1[t];
    #pragma unroll
    for (int k = 0; k < D; k += 4) {
        const float4 xv = *reinterpret_cast<const float4*>(&X[k]);
        accc = fmaf(xv.x, Wc1[(k + 0) * A1 + t], accc);
        accc = fmaf(xv.y, Wc1[(k + 1) * A1 + t], accc);
        accc = fmaf(xv.z, Wc1[(k + 2) * A1 + t], accc);
        accc = fmaf(xv.w, Wc1[(k + 3) * A1 + t], accc);
    }
    red[t] = fmaxf(accc, 0.f) * Wc2[t];
    __syncthreads();
    for (int s = 128; s > 0; s >>= 1) {
        if (t < s) red[t] += red[t + s];
        __syncthreads();
    }
    if (t == 0) out_crit[bi] = red[0] + bc2[0];
}

// ---------------------------------------------------------------------------
extern "C" void kernel_launch(void* const* d_in, const int* in_sizes, int n_in,
                              void* d_out, int out_size, void* d_ws, size_t ws_size,
                              hipStream_t stream)
{
    const float* bulk = (const float*)d_in[0];
    const int*   seg  = (const int*)d_in[1];
    const int*   esrc = (const int*)d_in[2];
    const int*   edst = (const int*)d_in[3];
    const int*   root = (const int*)d_in[4];
    const float* W1   = (const float*)d_in[6];
    const float* b1   = (const float*)d_in[7];
    const float* W2   = (const float*)d_in[8];
    const float* b2   = (const float*)d_in[9];
    const float* ginW = (const float*)d_in[10];
    const float* ginb = (const float*)d_in[11];
    const float* Wa1  = (const float*)d_in[12];
    const float* ba1  = (const float*)d_in[13];
    const float* Wa2  = (const float*)d_in[14];
    const float* ba2  = (const float*)d_in[15];
    const float* Wc1  = (const float*)d_in[16];
    const float* bc1  = (const float*)d_in[17];
    const float* Wc2  = (const float*)d_in[18];
    const float* bc2  = (const float*)d_in[19];

    char* ws = (char*)d_ws;
    ushort* W1p = (ushort*)ws;                     // 64 KB
    ushort* W2p = W1p + 32768;                     // 128 KB
    float* sums    = (float*)(ws + 196608);        // N*D f32
    uint*  hbfA    = (uint*)(sums + (long)NN * D); // N*64 uints (bf16 h)
    uint*  hbfB    = hbfA + (long)NN * 64;         // N*64
    int*   start   = (int*)(hbfB + (long)NN * 64); // N+4
    int*   deg     = start + (NN + 4);             // N
    int*   offsets = deg + NN;                     // N
    int*   cursor  = offsets + NN;                 // N
    int*   partials= cursor + NN;                  // 256
    int*   csr     = partials + 256;               // E
    int*   mark    = csr + NE;                     // N
    int*   list    = mark + NN;                    // N
    int*   cnt     = list + NN;                    // 4
    uint*  Xbf     = (uint*)(cnt + 4);             // NB*64
    ushort* Gp     = (ushort*)(Xbf + (long)NB * 64); // 256 KB

    hipMemsetAsync(sums, 0, (long)NN * D * sizeof(float), stream);

    // pack all weights + zero deg/mark/cnt in one launch
    pack_all<<<252, 256, 0, stream>>>(W1, W2, ginW, W1p, W2p, Gp, deg, mark, cnt);

    fe_mfma<<<R_ROWS / FE_ROWS, 256, 0, stream>>>(bulk, seg, W1p, b1, W2p, b2, sums);
    start_kernel<<<(NN + 256) / 256, 256, 0, stream>>>(seg, start);
    divide_bf<<<((long)NN * 64 + 255) / 256, 256, 0, stream>>>(sums, start, hbfA);

    hist_kernel<<<(NE + 255) / 256, 256, 0, stream>>>(edst, deg);
    const int nchunks = (NN + SCHUNK - 1) / SCHUNK;
    scan_reduce<<<nchunks, 256, 0, stream>>>(deg, partials, NN);
    scan_write<<<nchunks, 256, 0, stream>>>(deg, partials, nchunks, offsets, cursor, NN);
    scatter_edges<<<(NE + 255) / 256, 256, 0, stream>>>(esrc, edst, cursor, csr);

    mark_kernel<<<(NB + 255) / 256, 256, 0, stream>>>(root, offsets, deg, csr, mark);
    compact_kernel<<<(NN + 255) / 256, 256, 0, stream>>>(mark, list, cnt);

    const int full_grid = (NN + 63) / 64;
    gin_kernel<0><<<full_grid, 256, 0, stream>>>(hbfA, offsets, deg, csr,
        Gp + 0L * 32768, ginb + 0L * D, hbfB, list, cnt, root);
    gin_kernel<0><<<full_grid, 256, 0, stream>>>(hbfB, offsets, deg, csr,
        Gp + 1L * 32768, ginb + 1L * D, hbfA, list, cnt, root);
    gin_kernel<1><<<full_grid, 256, 0, stream>>>(hbfA, offsets, deg, csr,
        Gp + 2L * 32768, ginb + 2L * D, hbfB, list, cnt, root);
    gin_kernel<2><<<NB / 64, 256, 0, stream>>>(hbfB, offsets, deg, csr,
        Gp + 3L * 32768, ginb + 3L * D, Xbf, list, cnt, root);

    head_kernel<<<NB, 256, 0, stream>>>(Xbf, root, Wa1, ba1, Wa2, ba2,
                                        Wc1, bc1, Wc2, bc2,
                                        (float*)d_out, (float*)d_out + (long)NB * NTOK);
}

// Round 10
// 733.009 us; speedup vs baseline: 7.4992x; 1.0576x over previous
//
#include <hip/hip_runtime.h>
#include <math.h>

#define R_ROWS 1048576
#define F_IN   64
#define H1     256
#define D      128
#define NN     100000
#define NE     1600000
#define NB     4096
#define A1     256
#define NTOK   16
#define N_GIN  4
#define FE_ROWS 64

typedef short short8 __attribute__((ext_vector_type(8)));
typedef float f32x4  __attribute__((ext_vector_type(4)));
typedef unsigned int uintx4 __attribute__((ext_vector_type(4)));

__device__ __forceinline__ ushort f2bf(float x) {
    uint u = __builtin_bit_cast(uint, x);
    u += 0x7FFFu + ((u >> 16) & 1u);
    return (ushort)(u >> 16);
}
__device__ __forceinline__ float bf2f(ushort h) {
    uint u = ((uint)h) << 16;
    return __builtin_bit_cast(float, u);
}
__device__ __forceinline__ uint cvtpk(float lo, float hi) {
    uint r;
    asm("v_cvt_pk_bf16_f32 %0, %1, %2" : "=v"(r) : "v"(lo), "v"(hi));
    return r;
}
__device__ __forceinline__ float lo16f(uint p) { return __builtin_bit_cast(float, p << 16); }
__device__ __forceinline__ float hi16f(uint p) { return __builtin_bit_cast(float, p & 0xFFFF0000u); }

__device__ __forceinline__ f32x4 mm(short8 a, short8 b, f32x4 c) {
    return __builtin_amdgcn_mfma_f32_16x16x32_bf16(a, b, c, 0, 0, 0);
}
__device__ __forceinline__ void acc_add(f32x4& L, f32x4& H, const uintx4 p) {
    L[0] += lo16f(p[0]); H[0] += hi16f(p[0]);
    L[1] += lo16f(p[1]); H[1] += hi16f(p[1]);
    L[2] += lo16f(p[2]); H[2] += hi16f(p[2]);
    L[3] += lo16f(p[3]); H[3] += hi16f(p[3]);
}

// ---------------------------------------------------------------------------
// Pack [K][N] f32 weight into MFMA fragment order, bf16 hi/lo planes.
// ---------------------------------------------------------------------------
__device__ __forceinline__ void pack_one(const float* __restrict__ W, int Ndim,
                                         int f, int lane, ushort* __restrict__ out)
{
    const int NTn = Ndim >> 4;
    const int kt = f / NTn, nt = f - kt * NTn;
    const int k0 = kt * 32 + (lane >> 4) * 8;
    const int n = nt * 16 + (lane & 15);
    uintx4 Hv, Lv;
    #pragma unroll
    for (int jj = 0; jj < 4; ++jj) {
        const float x0 = W[(k0 + 2 * jj) * Ndim + n];
        const float x1 = W[(k0 + 2 * jj + 1) * Ndim + n];
        const ushort h0 = f2bf(x0), l0 = f2bf(x0 - bf2f(h0));
        const ushort h1u = f2bf(x1), l1 = f2bf(x1 - bf2f(h1u));
        Hv[jj] = (uint)h0 | ((uint)h1u << 16);
        Lv[jj] = (uint)l0 | ((uint)l1 << 16);
    }
    *reinterpret_cast<uintx4*>(&out[((f * 2 + 0) * 64 + lane) * 8]) = Hv;
    *reinterpret_cast<uintx4*>(&out[((f * 2 + 1) * 64 + lane) * 8]) = Lv;
}

// Pack W1(0-31), W2(32-95), gin(96-223), Wa1(224-287), Wc1(288-351),
// Wa2(352-359); remaining blocks zero deg/mark/cnt.
__global__ __launch_bounds__(256) void pack_all(
    const float* __restrict__ W1, const float* __restrict__ W2,
    const float* __restrict__ ginW, const float* __restrict__ Wa1,
    const float* __restrict__ Wc1, const float* __restrict__ Wa2,
    ushort* __restrict__ W1p, ushort* __restrict__ W2p, ushort* __restrict__ Gp,
    ushort* __restrict__ Wa1p, ushort* __restrict__ Wc1p, ushort* __restrict__ Wa2p,
    int* __restrict__ deg, int* __restrict__ mark, int* __restrict__ cnt)
{
    const int bid = blockIdx.x;
    if (bid < 90) {
        const int fid = bid * 4 + (threadIdx.x >> 6);
        const int lane = threadIdx.x & 63;
        if (fid < 32) pack_one(W1, H1, fid, lane, W1p);
        else if (fid < 96) pack_one(W2, D, fid - 32, lane, W2p);
        else if (fid < 224) {
            const int l = (fid - 96) >> 5;
            pack_one(ginW + (long)l * D * D, D, (fid - 96) & 31, lane, Gp + (long)l * 32768);
        } else if (fid < 288) pack_one(Wa1, A1, fid - 224, lane, Wa1p);
        else if (fid < 352) pack_one(Wc1, A1, fid - 288, lane, Wc1p);
        else if (fid < 360) pack_one(Wa2, NTOK, fid - 352, lane, Wa2p);
    } else {
        const int zb = bid - 90;
        const int idx0 = (zb * 256 + threadIdx.x) * 4;
        #pragma unroll
        for (int k = 0; k < 4; ++k) {
            const int idx = idx0 + k;
            if (idx < NN) deg[idx] = 0;
            else if (idx < 2 * NN) mark[idx - NN] = 0;
        }
        if (bid == 90 && threadIdx.x == 0) cnt[0] = 0;
    }
}

// ---------------------------------------------------------------------------
// Fused FE + segment sum. 64 rows/block, 4 waves, 4 blocks/CU (40960 B LDS).
// L1 uses W1-hi only (bulk already bf16-rounded).
// ---------------------------------------------------------------------------
__global__ __launch_bounds__(256, 4) void fe_mfma(
    const float* __restrict__ bulk, const int* __restrict__ seg,
    const ushort* __restrict__ W1p, const float* __restrict__ b1,
    const ushort* __restrict__ W2p, const float* __restrict__ b2,
    float* __restrict__ sums)
{
    __shared__ __align__(16) uint smem_u[10240];      // 40960 B
    char* Ab  = (char*)smem_u;                        // 8 KB: [64][64] bf16, XOR-swz
    char* h1b = Ab + 8192;                            // 32 KB: [64][256] bf16, XOR-swz
    float* h2 = (float*)smem_u;                       // [64][132] f32 overlay (post-L2)

    const int t = threadIdx.x;
    const int lane = t & 63;
    const int w = t >> 6;
    const long r0 = (long)blockIdx.x * FE_ROWS;

    #pragma unroll
    for (int i = 0; i < 4; ++i) {
        const int gid = t + i * 256;
        const int row = gid >> 4;
        const int c4 = (gid & 15) * 4;
        const float4 v = *reinterpret_cast<const float4*>(&bulk[(r0 + row) * F_IN + c4]);
        uint2 pk; pk.x = cvtpk(v.x, v.y); pk.y = cvtpk(v.z, v.w);
        const int byteoff = row * 128 + ((c4 * 2) ^ ((row & 7) << 4));
        *reinterpret_cast<uint2*>(Ab + byteoff) = pk;
    }
    __syncthreads();

    const f32x4 zz = {0.f, 0.f, 0.f, 0.f};
    f32x4 acc1[4][4];
    #pragma unroll
    for (int mtl = 0; mtl < 4; ++mtl)
        #pragma unroll
        for (int ntb = 0; ntb < 4; ++ntb) acc1[mtl][ntb] = zz;

    #pragma unroll
    for (int kt = 0; kt < 2; ++kt) {
        short8 aw[4];
        #pragma unroll
        for (int mtl = 0; mtl < 4; ++mtl) {
            const int f = kt * 16 + (w * 4 + mtl);
            aw[mtl] = *reinterpret_cast<const short8*>(&W1p[((f * 2 + 0) * 64 + lane) * 8]);
        }
        short8 bh[4];
        #pragma unroll
        for (int ntb = 0; ntb < 4; ++ntb) {
            const int row = ntb * 16 + (lane & 15);
            const int k0 = kt * 32 + (lane >> 4) * 8;
            bh[ntb] = *reinterpret_cast<const short8*>(Ab + (row * 128 + ((k0 * 2) ^ ((row & 7) << 4))));
        }
        #pragma unroll
        for (int mtl = 0; mtl < 4; ++mtl)
            #pragma unroll
            for (int ntb = 0; ntb < 4; ++ntb)
                acc1[mtl][ntb] = mm(aw[mtl], bh[ntb], acc1[mtl][ntb]);
    }

    #pragma unroll
    for (int mtl = 0; mtl < 4; ++mtl) {
        const int hcb = w * 64 + mtl * 16 + (lane >> 4) * 4;
        const float4 bv = *reinterpret_cast<const float4*>(&b1[hcb]);
        #pragma unroll
        for (int ntb = 0; ntb < 4; ++ntb) {
            const int hr = (lane & 15) + ntb * 16;
            const float v0 = fmaxf(acc1[mtl][ntb][0] + bv.x, 0.f);
            const float v1 = fmaxf(acc1[mtl][ntb][1] + bv.y, 0.f);
            const float v2 = fmaxf(acc1[mtl][ntb][2] + bv.z, 0.f);
            const float v3 = fmaxf(acc1[mtl][ntb][3] + bv.w, 0.f);
            uint2 pk; pk.x = cvtpk(v0, v1); pk.y = cvtpk(v2, v3);
            const int byteoff = (hr * 512 + hcb * 2) ^ ((hr & 7) << 4);
            *reinterpret_cast<uint2*>(h1b + byteoff) = pk;
        }
    }
    __syncthreads();

    float b2v[2];
    #pragma unroll
    for (int ntl = 0; ntl < 2; ++ntl) b2v[ntl] = b2[w * 32 + ntl * 16 + (lane & 15)];
    f32x4 acc2[4][2];
    #pragma unroll
    for (int mt = 0; mt < 4; ++mt) { acc2[mt][0] = zz; acc2[mt][1] = zz; }

    #pragma unroll
    for (int kt = 0; kt < 8; ++kt) {
        short8 bw2[2][2];
        #pragma unroll
        for (int ntl = 0; ntl < 2; ++ntl)
            #pragma unroll
            for (int p = 0; p < 2; ++p) {
                const int f = kt * 8 + (w * 2 + ntl);
                bw2[ntl][p] = *reinterpret_cast<const short8*>(&W2p[((f * 2 + p) * 64 + lane) * 8]);
            }
        short8 ah[4];
        #pragma unroll
        for (int mt = 0; mt < 4; ++mt) {
            const int row = mt * 16 + (lane & 15);
            const int k0 = kt * 32 + (lane >> 4) * 8;
            ah[mt] = *reinterpret_cast<const short8*>(h1b + ((row * 512 + k0 * 2) ^ ((row & 7) << 4)));
        }
        #pragma unroll
        for (int mt = 0; mt < 4; ++mt)
            #pragma unroll
            for (int ntl = 0; ntl < 2; ++ntl) {
                acc2[mt][ntl] = mm(ah[mt], bw2[ntl][0], acc2[mt][ntl]);
                acc2[mt][ntl] = mm(ah[mt], bw2[ntl][1], acc2[mt][ntl]);
            }
    }
    __syncthreads();

    #pragma unroll
    for (int mt = 0; mt < 4; ++mt)
        #pragma unroll
        for (int ntl = 0; ntl < 2; ++ntl)
            #pragma unroll
            for (int r = 0; r < 4; ++r) {
                const int row = mt * 16 + (lane >> 4) * 4 + r;
                const int col = w * 32 + ntl * 16 + (lane & 15);
                h2[row * 132 + col] = fmaxf(acc2[mt][ntl][r] + b2v[ntl], 0.f);
            }
    __syncthreads();

    {
        const int g = t >> 7;
        const int c = t & 127;
        const int base = g * 32;
        const long rb = r0 + base;
        const int prev = (rb == 0) ? -1 : seg[rb - 1];
        const int nxt = (rb + 32 >= R_ROWS) ? -1 : seg[rb + 32];
        int cur = seg[rb];
        float run = 0.f;
        int runstart = 0;
        #pragma unroll 1
        for (int r = 0; r < 32; ++r) {
            const int s = seg[rb + r];
            if (s != cur) {
                if (runstart != 0 || cur != prev) sums[(long)cur * D + c] = run;
                else atomicAdd(&sums[(long)cur * D + c], run);
                cur = s; run = 0.f; runstart = r;
            }
            run += h2[(base + r) * 132 + c];
        }
        if ((runstart != 0 || cur != prev) && cur != nxt) sums[(long)cur * D + c] = run;
        else atomicAdd(&sums[(long)cur * D + c], run);
    }
}

__global__ __launch_bounds__(256) void start_kernel(const int* __restrict__ seg,
                                                    int* __restrict__ start)
{
    const int n = blockIdx.x * 256 + threadIdx.x;
    if (n > NN) return;
    int lo = 0, hi = R_ROWS;
    #pragma unroll 1
    while (lo < hi) {
        const int mid = (lo + hi) >> 1;
        if (seg[mid] < n) lo = mid + 1; else hi = mid;
    }
    start[n] = lo;
}

__global__ __launch_bounds__(256) void divide_bf(
    const float* __restrict__ sums, const int* __restrict__ start,
    uint* __restrict__ hbf)
{
    const long i = (long)blockIdx.x * 256 + threadIdx.x;
    if (i < (long)NN * 64) {
        const int n = (int)(i >> 6), u = (int)(i & 63);
        const int cA = (u & 15) + (u >> 4) * 32;
        const float inv = 1.f / fmaxf((float)(start[n + 1] - start[n]), 1.f);
        const float vA = sums[(long)n * D + cA] * inv;
        const float vB = sums[(long)n * D + cA + 16] * inv;
        hbf[i] = cvtpk(vA, vB);
    }
}

__global__ __launch_bounds__(256) void hist_kernel(const int* __restrict__ edst,
                                                   int* __restrict__ deg)
{
    const int e = blockIdx.x * 256 + threadIdx.x;
    if (e < NE) atomicAdd(&deg[edst[e]], 1);
}

#define SCHUNK 2048
__global__ __launch_bounds__(256) void scan_reduce(const int* __restrict__ deg,
                                                   int* __restrict__ partials, int n)
{
    __shared__ int sdata[256];
    const int b = blockIdx.x, t = threadIdx.x;
    const int base = b * SCHUNK;
    int sum = 0;
    for (int i = t; i < SCHUNK; i += 256) {
        const int idx = base + i;
        sum += (idx < n) ? deg[idx] : 0;
    }
    sdata[t] = sum; __syncthreads();
    for (int s = 128; s > 0; s >>= 1) {
        if (t < s) sdata[t] += sdata[t + s];
        __syncthreads();
    }
    if (t == 0) partials[b] = sdata[0];
}

__global__ __launch_bounds__(256) void scan_write(const int* __restrict__ deg,
                                                  const int* __restrict__ partials,
                                                  int nchunks,
                                                  int* __restrict__ offsets,
                                                  int* __restrict__ cursor, int n)
{
    __shared__ int sdata[256];
    __shared__ int base_sh;
    const int b = blockIdx.x, t = threadIdx.x;
    if (t < 64) {
        int v = (t < b && t < nchunks) ? partials[t] : 0;
        #pragma unroll
        for (int d2 = 1; d2 < 64; d2 <<= 1) v += __shfl_xor(v, d2);
        if (t == 0) base_sh = v;
    }
    const int base = b * SCHUNK;
    int loc[8]; int s = 0;
    #pragma unroll
    for (int j = 0; j < 8; ++j) {
        const int idx = base + t * 8 + j;
        const int v = (idx < n) ? deg[idx] : 0;
        loc[j] = s; s += v;
    }
    sdata[t] = s; __syncthreads();
    for (int d = 1; d < 256; d <<= 1) {
        const int v = (t >= d) ? sdata[t - d] : 0;
        __syncthreads();
        sdata[t] += v;
        __syncthreads();
    }
    const int excl = (t == 0) ? 0 : sdata[t - 1];
    const int tbase = base_sh + excl;
    #pragma unroll
    for (int j = 0; j < 8; ++j) {
        const int idx = base + t * 8 + j;
        if (idx < n) {
            const int o = tbase + loc[j];
            offsets[idx] = o;
            cursor[idx] = o;
        }
    }
}

__global__ __launch_bounds__(256) void scatter_edges(const int* __restrict__ esrc,
                                                     const int* __restrict__ edst,
                                                     int* __restrict__ cursor,
                                                     int* __restrict__ csr_src)
{
    const int e = blockIdx.x * 256 + threadIdx.x;
    if (e < NE) {
        const int d = edst[e];
        const int p = atomicAdd(&cursor[d], 1);
        csr_src[p] = esrc[e];
    }
}

__global__ __launch_bounds__(256) void mark_kernel(
    const int* __restrict__ root, const int* __restrict__ offsets,
    const int* __restrict__ deg, const int* __restrict__ csr,
    int* __restrict__ mark)
{
    const int b = blockIdx.x * 256 + threadIdx.x;
    if (b < NB) {
        const int n = root[b];
        mark[n] = 1;
        const int off = offsets[n], dg = deg[n];
        for (int j = 0; j < dg; ++j) mark[csr[off + j]] = 1;
    }
}

__global__ __launch_bounds__(256) void compact_kernel(
    const int* __restrict__ mark, int* __restrict__ list, int* __restrict__ cnt)
{
    const int n = blockIdx.x * 256 + threadIdx.x;
    if (n < NN && mark[n]) {
        const int p = atomicAdd(cnt, 1);
        list[p] = n;
    }
}

// ---------------------------------------------------------------------------
// Fused GIN layer, bf16 h. Half-wave per row gather; W-hi-only MFMA.
// ---------------------------------------------------------------------------
template<int MODE>
__global__ __launch_bounds__(256, 8) void gin_kernel(
    const uint* __restrict__ hbf, const int* __restrict__ offsets,
    const int* __restrict__ deg, const int* __restrict__ csr,
    const ushort* __restrict__ Wp, const float* __restrict__ bvec,
    uint* __restrict__ outbuf,
    const int* __restrict__ list, const int* __restrict__ cnt,
    const int* __restrict__ root)
{
    __shared__ __align__(16) char ylds[64 * 256];   // 16 KB
    __shared__ int nid[64];
    const int t = threadIdx.x, lane = t & 63, w = t >> 6;
    const int h = lane >> 5;
    const int q2 = (lane >> 4) & 1;
    const int m = lane & 15;
    const int q = lane >> 4;
    const int r0 = blockIdx.x * 64;
    const int CNT = (MODE == 1) ? cnt[0] : 0;
    if (MODE == 1 && r0 >= CNT) return;

    #pragma unroll 1
    for (int i = 0; i < 8; ++i) {
        const int row = w * 16 + i * 2 + h;
        int n = -1;
        if (MODE == 0) {
            const int nn = r0 + row;
            if (nn < NN) n = nn;
        } else if (MODE == 1) {
            const int idx = r0 + row;
            if (idx < CNT) n = list[idx];
        } else {
            n = root[r0 + row];
        }
        if (MODE == 1 && (lane & 31) == 0) nid[row] = n;
        f32x4 accL = {0.f, 0.f, 0.f, 0.f};
        f32x4 accH = {0.f, 0.f, 0.f, 0.f};
        if (n >= 0) {
            const uintx4 sp = *reinterpret_cast<const uintx4*>(&hbf[(long)n * 64 + 4 * m]);
            const float sc = (q2 == 0) ? 2.1f : 0.f;
            accL[0] = sc * lo16f(sp[0]); accH[0] = sc * hi16f(sp[0]);
            accL[1] = sc * lo16f(sp[1]); accH[1] = sc * hi16f(sp[1]);
            accL[2] = sc * lo16f(sp[2]); accH[2] = sc * hi16f(sp[2]);
            accL[3] = sc * lo16f(sp[3]); accH[3] = sc * hi16f(sp[3]);
            const int off = offsets[n];
            const int dg = deg[n];
            const int dg2 = dg >> 1;
            int jj = 0;
            for (; jj + 4 <= dg2; jj += 4) {
                const int b0 = off + 2 * jj + q2;
                const int s0 = csr[b0], s1 = csr[b0 + 2], s2 = csr[b0 + 4], s3 = csr[b0 + 6];
                const uintx4 p0 = *reinterpret_cast<const uintx4*>(&hbf[(long)s0 * 64 + 4 * m]);
                const uintx4 p1 = *reinterpret_cast<const uintx4*>(&hbf[(long)s1 * 64 + 4 * m]);
                const uintx4 p2 = *reinterpret_cast<const uintx4*>(&hbf[(long)s2 * 64 + 4 * m]);
                const uintx4 p3 = *reinterpret_cast<const uintx4*>(&hbf[(long)s3 * 64 + 4 * m]);
                acc_add(accL, accH, p0);
                acc_add(accL, accH, p1);
                acc_add(accL, accH, p2);
                acc_add(accL, accH, p3);
            }
            for (; jj < dg2; ++jj) {
                const int s = csr[off + 2 * jj + q2];
                const uintx4 p = *reinterpret_cast<const uintx4*>(&hbf[(long)s * 64 + 4 * m]);
                acc_add(accL, accH, p);
            }
            if ((dg & 1) && q2 == 0) {
                const int s = csr[off + dg - 1];
                const uintx4 p = *reinterpret_cast<const uintx4*>(&hbf[(long)s * 64 + 4 * m]);
                acc_add(accL, accH, p);
            }
        }
        #pragma unroll
        for (int e = 0; e < 4; ++e) {
            accL[e] += __shfl_xor(accL[e], 16);
            accH[e] += __shfl_xor(accH[e], 16);
        }
        const int swz = (row & 7) << 4;
        #pragma unroll
        for (int e = 0; e < 2; ++e) {
            const int u = 4 * m + 2 * q2 + e;
            const int cA = (u & 15) + (u >> 4) * 32;
            const uint pk = cvtpk(accL[2 * q2 + e], accH[2 * q2 + e]);
            *reinterpret_cast<ushort*>(ylds + ((row * 256 + cA * 2) ^ swz)) = (ushort)pk;
            *reinterpret_cast<ushort*>(ylds + ((row * 256 + (cA + 16) * 2) ^ swz)) = (ushort)(pk >> 16);
        }
    }

    short8 bw0[2];
    #pragma unroll
    for (int ntl = 0; ntl < 2; ++ntl) {
        const int f = w * 2 + ntl;
        bw0[ntl] = *reinterpret_cast<const short8*>(&Wp[((f * 2 + 0) * 64 + lane) * 8]);
    }
    __syncthreads();

    const f32x4 zz = {0.f, 0.f, 0.f, 0.f};
    f32x4 acc[4][2];
    #pragma unroll
    for (int mt = 0; mt < 4; ++mt) { acc[mt][0] = zz; acc[mt][1] = zz; }

    #pragma unroll
    for (int kt = 0; kt < 4; ++kt) {
        short8 bw[2];
        if (kt == 0) { bw[0] = bw0[0]; bw[1] = bw0[1]; }
        else {
            #pragma unroll
            for (int ntl = 0; ntl < 2; ++ntl) {
                const int f = kt * 8 + (w * 2 + ntl);
                bw[ntl] = *reinterpret_cast<const short8*>(&Wp[((f * 2 + 0) * 64 + lane) * 8]);
            }
        }
        #pragma unroll
        for (int mt = 0; mt < 4; ++mt) {
            const int row = mt * 16 + m;
            const int k0 = kt * 32 + q * 8;
            const short8 ah = *reinterpret_cast<const short8*>(
                ylds + ((row * 256 + k0 * 2) ^ ((row & 7) << 4)));
            acc[mt][0] = mm(ah, bw[0], acc[mt][0]);
            acc[mt][1] = mm(ah, bw[1], acc[mt][1]);
        }
    }

    const float bv0 = bvec[w * 32 + m];
    const float bv1 = bvec[w * 32 + 16 + m];
    #pragma unroll
    for (int mt = 0; mt < 4; ++mt)
        #pragma unroll
        for (int r = 0; r < 4; ++r) {
            const int grow_row = mt * 16 + q * 4 + r;
            const float v0 = fmaxf(acc[mt][0][r] + bv0, 0.f);
            const float v1 = fmaxf(acc[mt][1][r] + bv1, 0.f);
            const uint pk = cvtpk(v0, v1);
            if (MODE == 0) {
                const long nout = r0 + grow_row;
                if (nout < NN) outbuf[nout * 64 + w * 16 + m] = pk;
            } else if (MODE == 1) {
                if (r0 + grow_row < CNT) {
                    const long nout = nid[grow_row];
                    outbuf[nout * 64 + w * 16 + m] = pk;
                }
            } else {
                outbuf[(long)(r0 + grow_row) * 64 + w * 16 + m] = pk;
            }
        }
}

// ---------------------------------------------------------------------------
// MFMA batch heads: 64 blocks x 64 roots. Full hi+lo split for head weights.
// ---------------------------------------------------------------------------
__global__ __launch_bounds__(256) void head_mfma(
    const uint* __restrict__ Xbf,
    const ushort* __restrict__ Wa1p, const float* __restrict__ ba1,
    const ushort* __restrict__ Wa2p, const float* __restrict__ ba2,
    const ushort* __restrict__ Wc1p, const float* __restrict__ bc1,
    const float* __restrict__ Wc2, const float* __restrict__ bc2,
    float* __restrict__ out_act, float* __restrict__ out_crit)
{
    __shared__ __align__(16) char Xp[64 * 256];    // 16 KB: [64][128] bf16, XOR-swz
    __shared__ __align__(16) char a1p[64 * 512];   // 32 KB: [64][256] bf16, XOR-swz
    const int t = threadIdx.x, lane = t & 63, w = t >> 6;
    const int r0 = blockIdx.x * 64;
    const f32x4 zz = {0.f, 0.f, 0.f, 0.f};

    // ---- stage X plane ----
    {
        const int row = t >> 2;
        const int ug = (t & 3) * 16;
        const int swz = (row & 7) << 4;
        #pragma unroll
        for (int uu = 0; uu < 16; ++uu) {
            const uint pk = Xbf[(long)(r0 + row) * 64 + ug + uu];
            const int u = ug + uu;
            const int cA = (u & 15) + (u >> 4) * 32;
            *reinterpret_cast<ushort*>(Xp + ((row * 256 + cA * 2) ^ swz)) = (ushort)pk;
            *reinterpret_cast<ushort*>(Xp + ((row * 256 + (cA + 16) * 2) ^ swz)) = (ushort)(pk >> 16);
        }
    }
    __syncthreads();

    // ---- phase 1: a1 = relu(X @ Wa1 + ba1) -> a1p plane ----
    {
        f32x4 acc1[4][4];
        #pragma unroll
        for (int mtl = 0; mtl < 4; ++mtl)
            #pragma unroll
            for (int ntb = 0; ntb < 4; ++ntb) acc1[mtl][ntb] = zz;
        #pragma unroll
        for (int kt = 0; kt < 4; ++kt) {
            short8 aw[4][2];
            #pragma unroll
            for (int mtl = 0; mtl < 4; ++mtl)
                #pragma unroll
                for (int p = 0; p < 2; ++p) {
                    const int f = kt * 16 + (w * 4 + mtl);
                    aw[mtl][p] = *reinterpret_cast<const short8*>(&Wa1p[((f * 2 + p) * 64 + lane) * 8]);
                }
            short8 bh[4];
            #pragma unroll
            for (int ntb = 0; ntb < 4; ++ntb) {
                const int row = ntb * 16 + (lane & 15);
                const int k0 = kt * 32 + (lane >> 4) * 8;
                bh[ntb] = *reinterpret_cast<const short8*>(Xp + ((row * 256 + k0 * 2) ^ ((row & 7) << 4)));
            }
            #pragma unroll
            for (int mtl = 0; mtl < 4; ++mtl)
                #pragma unroll
                for (int ntb = 0; ntb < 4; ++ntb) {
                    acc1[mtl][ntb] = mm(aw[mtl][0], bh[ntb], acc1[mtl][ntb]);
                    acc1[mtl][ntb] = mm(aw[mtl][1], bh[ntb], acc1[mtl][ntb]);
                }
        }
        #pragma unroll
        for (int mtl = 0; mtl < 4; ++mtl) {
            const int hcb = w * 64 + mtl * 16 + (lane >> 4) * 4;
            const float4 bv = *reinterpret_cast<const float4*>(&ba1[hcb]);
            #pragma unroll
            for (int ntb = 0; ntb < 4; ++ntb) {
                const int hr = (lane & 15) + ntb * 16;
                const float v0 = fmaxf(acc1[mtl][ntb][0] + bv.x, 0.f);
                const float v1 = fmaxf(acc1[mtl][ntb][1] + bv.y, 0.f);
                const float v2 = fmaxf(acc1[mtl][ntb][2] + bv.z, 0.f);
                const float v3 = fmaxf(acc1[mtl][ntb][3] + bv.w, 0.f);
                uint2 pk; pk.x = cvtpk(v0, v1); pk.y = cvtpk(v2, v3);
                const int byteoff = (hr * 512 + hcb * 2) ^ ((hr & 7) << 4);
                *reinterpret_cast<uint2*>(a1p + byteoff) = pk;
            }
        }
    }
    __syncthreads();

    // ---- phase 2: logits + softmax ----
    {
        f32x4 accl = zz;
        #pragma unroll
        for (int kt = 0; kt < 8; ++kt) {
            short8 b2h = *reinterpret_cast<const short8*>(&Wa2p[((kt * 2 + 0) * 64 + lane) * 8]);
            short8 b2l = *reinterpret_cast<const short8*>(&Wa2p[((kt * 2 + 1) * 64 + lane) * 8]);
            const int row = w * 16 + (lane & 15);
            const int k0 = kt * 32 + (lane >> 4) * 8;
            const short8 ah = *reinterpret_cast<const short8*>(a1p + ((row * 512 + k0 * 2) ^ ((row & 7) << 4)));
            accl = mm(ah, b2h, accl);
            accl = mm(ah, b2l, accl);
        }
        const int j = lane & 15;
        float lg[4], mx[4], sm[4];
        #pragma unroll
        for (int r = 0; r < 4; ++r) {
            lg[r] = fmaxf(accl[r] + ba2[j], 0.f);
            float m2 = lg[r];
            #pragma unroll
            for (int d2 = 1; d2 < 16; d2 <<= 1) m2 = fmaxf(m2, __shfl_xor(m2, d2));
            mx[r] = m2;
            lg[r] = expf(lg[r] - m2);
            float s2 = lg[r];
            #pragma unroll
            for (int d2 = 1; d2 < 16; d2 <<= 1) s2 += __shfl_xor(s2, d2);
            sm[r] = s2;
        }
        #pragma unroll
        for (int r = 0; r < 4; ++r) {
            const int root_slot = r0 + w * 16 + (lane >> 4) * 4 + r;
            out_act[(long)root_slot * NTOK + j] = lg[r] / sm[r];
        }
    }
    __syncthreads();

    // ---- phase 3: a1c = relu(X @ Wc1 + bc1) -> a1p plane ----
    {
        f32x4 acc1[4][4];
        #pragma unroll
        for (int mtl = 0; mtl < 4; ++mtl)
            #pragma unroll
            for (int ntb = 0; ntb < 4; ++ntb) acc1[mtl][ntb] = zz;
        #pragma unroll
        for (int kt = 0; kt < 4; ++kt) {
            short8 aw[4][2];
            #pragma unroll
            for (int mtl = 0; mtl < 4; ++mtl)
                #pragma unroll
                for (int p = 0; p < 2; ++p) {
                    const int f = kt * 16 + (w * 4 + mtl);
                    aw[mtl][p] = *reinterpret_cast<const short8*>(&Wc1p[((f * 2 + p) * 64 + lane) * 8]);
                }
            short8 bh[4];
            #pragma unroll
            for (int ntb = 0; ntb < 4; ++ntb) {
                const int row = ntb * 16 + (lane & 15);
                const int k0 = kt * 32 + (lane >> 4) * 8;
                bh[ntb] = *reinterpret_cast<const short8*>(Xp + ((row * 256 + k0 * 2) ^ ((row & 7) << 4)));
            }
            #pragma unroll
            for (int mtl = 0; mtl < 4; ++mtl)
                #pragma unroll
                for (int ntb = 0; ntb < 4; ++ntb) {
                    acc1[mtl][ntb] = mm(aw[mtl][0], bh[ntb], acc1[mtl][ntb]);
                    acc1[mtl][ntb] = mm(aw[mtl][1], bh[ntb], acc1[mtl][ntb]);
                }
        }
        #pragma unroll
        for (int mtl = 0; mtl < 4; ++mtl) {
            const int hcb = w * 64 + mtl * 16 + (lane >> 4) * 4;
            const float4 bv = *reinterpret_cast<const float4*>(&bc1[hcb]);
            #pragma unroll
            for (int ntb = 0; ntb < 4; ++ntb) {
                const int hr = (lane & 15) + ntb * 16;
                const float v0 = fmaxf(acc1[mtl][ntb][0] + bv.x, 0.f);
                const float v1 = fmaxf(acc1[mtl][ntb][1] + bv.y, 0.f);
                const float v2 = fmaxf(acc1[mtl][ntb][2] + bv.z, 0.f);
                const float v3 = fmaxf(acc1[mtl][ntb][3] + bv.w, 0.f);
                uint2 pk; pk.x = cvtpk(v0, v1); pk.y = cvtpk(v2, v3);
                const int byteoff = (hr * 512 + hcb * 2) ^ ((hr & 7) << 4);
                *reinterpret_cast<uint2*>(a1p + byteoff) = pk;
            }
        }
    }
    __syncthreads();

    // ---- phase 4: crit = a1c . Wc2 + bc2 ----
    {
        const int row = w * 16 + (lane & 15);
        const int qk = lane >> 4;
        float dot = 0.f;
        #pragma unroll
        for (int g = 0; g < 8; ++g) {
            const int k0 = qk * 64 + g * 8;
            const short8 av = *reinterpret_cast<const short8*>(a1p + ((row * 512 + k0 * 2) ^ ((row & 7) << 4)));
            #pragma unroll
            for (int e = 0; e < 8; ++e)
                dot = fmaf(bf2f((ushort)av[e]), Wc2[k0 + e], dot);
        }
        dot += __shfl_xor(dot, 16);
        dot += __shfl_xor(dot, 32);
        if (lane < 16) out_crit[r0 + w * 16 + lane] = dot + bc2[0];
    }
}

// ---------------------------------------------------------------------------
extern "C" void kernel_launch(void* const* d_in, const int* in_sizes, int n_in,
                              void* d_out, int out_size, void* d_ws, size_t ws_size,
                              hipStream_t stream)
{
    const float* bulk = (const float*)d_in[0];
    const int*   seg  = (const int*)d_in[1];
    const int*   esrc = (const int*)d_in[2];
    const int*   edst = (const int*)d_in[3];
    const int*   root = (const int*)d_in[4];
    const float* W1   = (const float*)d_in[6];
    const float* b1   = (const float*)d_in[7];
    const float* W2   = (const float*)d_in[8];
    const float* b2   = (const float*)d_in[9];
    const float* ginW = (const float*)d_in[10];
    const float* ginb = (const float*)d_in[11];
    const float* Wa1  = (const float*)d_in[12];
    const float* ba1  = (const float*)d_in[13];
    const float* Wa2  = (const float*)d_in[14];
    const float* ba2  = (const float*)d_in[15];
    const float* Wc1  = (const float*)d_in[16];
    const float* bc1  = (const float*)d_in[17];
    const float* Wc2  = (const float*)d_in[18];
    const float* bc2  = (const float*)d_in[19];

    char* ws = (char*)d_ws;
    ushort* W1p = (ushort*)ws;                     // 64 KB
    ushort* W2p = W1p + 32768;                     // 128 KB
    float* sums    = (float*)(ws + 196608);        // N*D f32
    uint*  hbfA    = (uint*)(sums + (long)NN * D); // N*64
    uint*  hbfB    = hbfA + (long)NN * 64;         // N*64
    int*   start   = (int*)(hbfB + (long)NN * 64); // N+4
    int*   deg     = start + (NN + 4);             // N
    int*   offsets = deg + NN;                     // N
    int*   cursor  = offsets + NN;                 // N
    int*   partials= cursor + NN;                  // 256
    int*   csr     = partials + 256;               // E
    int*   mark    = csr + NE;                     // N
    int*   list    = mark + NN;                    // N
    int*   cnt     = list + NN;                    // 4
    uint*  Xbf     = (uint*)(cnt + 4);             // NB*64
    ushort* Gp     = (ushort*)(Xbf + (long)NB * 64); // 256 KB
    ushort* Wa1p   = Gp + 4 * 32768;               // 128 KB
    ushort* Wc1p   = Wa1p + 65536;                 // 128 KB
    ushort* Wa2p   = Wc1p + 65536;                 // 16 KB

    hipMemsetAsync(sums, 0, (long)NN * D * sizeof(float), stream);

    pack_all<<<286, 256, 0, stream>>>(W1, W2, ginW, Wa1, Wc1, Wa2,
                                      W1p, W2p, Gp, Wa1p, Wc1p, Wa2p,
                                      deg, mark, cnt);

    fe_mfma<<<R_ROWS / FE_ROWS, 256, 0, stream>>>(bulk, seg, W1p, b1, W2p, b2, sums);
    start_kernel<<<(NN + 256) / 256, 256, 0, stream>>>(seg, start);
    divide_bf<<<((long)NN * 64 + 255) / 256, 256, 0, stream>>>(sums, start, hbfA);

    hist_kernel<<<(NE + 255) / 256, 256, 0, stream>>>(edst, deg);
    const int nchunks = (NN + SCHUNK - 1) / SCHUNK;
    scan_reduce<<<nchunks, 256, 0, stream>>>(deg, partials, NN);
    scan_write<<<nchunks, 256, 0, stream>>>(deg, partials, nchunks, offsets, cursor, NN);
    scatter_edges<<<(NE + 255) / 256, 256, 0, stream>>>(esrc, edst, cursor, csr);

    mark_kernel<<<(NB + 255) / 256, 256, 0, stream>>>(root, offsets, deg, csr, mark);
    compact_kernel<<<(NN + 255) / 256, 256, 0, stream>>>(mark, list, cnt);

    const int full_grid = (NN + 63) / 64;
    gin_kernel<0><<<full_grid, 256, 0, stream>>>(hbfA, offsets, deg, csr,
        Gp + 0L * 32768, ginb + 0L * D, hbfB, list, cnt, root);
    gin_kernel<0><<<full_grid, 256, 0, stream>>>(hbfB, offsets, deg, csr,
        Gp + 1L * 32768, ginb + 1L * D, hbfA, list, cnt, root);
    gin_kernel<1><<<full_grid, 256, 0, stream>>>(hbfA, offsets, deg, csr,
        Gp + 2L * 32768, ginb + 2L * D, hbfB, list, cnt, root);
    gin_kernel<2><<<NB / 64, 256, 0, stream>>>(hbfB, offsets, deg, csr,
        Gp + 3L * 32768, ginb + 3L * D, Xbf, list, cnt, root);

    head_mfma<<<NB / 64, 256, 0, stream>>>(Xbf, Wa1p, ba1, Wa2p, ba2,
                                           Wc1p, bc1, Wc2, bc2,
                                           (float*)d_out, (float*)d_out + (long)NB * NTOK);
}